// Round 9
// baseline (327.485 us; speedup 1.0000x reference)
//
#include <hip/hip_runtime.h>
#include <hip/hip_fp16.h>
#include <type_traits>

#define NN2 25000
#define NN1 50000
#define NN0 100000
#define EE2 250000
#define EE1 500000
#define EE0 1000000
#define NTOTC 175000
#define ETOTC 1750000
#define NB 171            // ceil(175000/1024) coarse buckets (vg>>10)
#define CHUNK 8192        // edges per count/place block
#define NBLK 214          // ceil(ETOTC/CHUNK)
#define BN_EPS 1e-5f

static inline int cdiv(long a, long b) { return (int)((a + b - 1) / b); }

template <typename T>
__device__ inline float ldf(const T* p) {
    if constexpr (std::is_same<T, __half>::value) return __half2float(*p);
    else return *p;
}

// ---------------- GEMM: out[r] = act(bn?(in[r,:K]) @ W[K,M] + bias) ---------
template <int BM, int K, int M, bool RELU, bool BNIN, typename OT>
__global__ __launch_bounds__(256) void gemm_kernel(
    const float* __restrict__ in, const float* __restrict__ W,
    const float* __restrict__ bias,
    const float* __restrict__ sums, const float* __restrict__ sumsq,
    const float* __restrict__ g, const float* __restrict__ bt,
    OT* __restrict__ out, int n)
{
    constexpr int BK = 32;
    constexpr int COLG = M / 4;
    constexpr int ROWG = 256 / COLG;
    constexpr int TM = BM / ROWG;
    __shared__ float As[BM * (BK + 1)];
    __shared__ float Bs[BK * M];
    const int tid = threadIdx.x;
    const int r0 = blockIdx.x * BM;
    const int tc = tid % COLG, tr = tid / COLG;

    float acc[TM][4];
    #pragma unroll
    for (int i = 0; i < TM; ++i)
        #pragma unroll
        for (int j = 0; j < 4; ++j)
            acc[i][j] = (bias != nullptr) ? bias[tc * 4 + j] : 0.f;

    for (int k0 = 0; k0 < K; k0 += BK) {
        #pragma unroll
        for (int rr = 0; rr < BM; rr += 32) {
            int r = rr + (tid >> 3), kc = (tid & 7) << 2;
            int gr = r0 + r;
            float4 av = make_float4(0.f, 0.f, 0.f, 0.f);
            if (gr < n) av = *(const float4*)(in + (long)gr * K + k0 + kc);
            float a4[4] = {av.x, av.y, av.z, av.w};
            #pragma unroll
            for (int c = 0; c < 4; ++c) {
                if (BNIN) {
                    int ch = k0 + kc + c;
                    float mu = sums[ch] * (1.f / NN2);
                    float rs = rsqrtf(sumsq[ch] * (1.f / NN2) - mu * mu + BN_EPS);
                    a4[c] = g[ch] * rs * (a4[c] - mu) + bt[ch];
                }
                As[r * (BK + 1) + kc + c] = a4[c];
            }
        }
        #pragma unroll
        for (int idx = tid; idx < BK * M / 4; idx += 256) {
            int kk = idx / COLG, cc = (idx % COLG) * 4;
            *(float4*)&Bs[kk * M + cc] = *(const float4*)(W + (long)(k0 + kk) * M + cc);
        }
        __syncthreads();
        #pragma unroll
        for (int kk = 0; kk < BK; ++kk) {
            float4 b = *(const float4*)&Bs[kk * M + tc * 4];
            float a[TM];
            #pragma unroll
            for (int i = 0; i < TM; ++i) a[i] = As[(tr * TM + i) * (BK + 1) + kk];
            #pragma unroll
            for (int i = 0; i < TM; ++i) {
                acc[i][0] = fmaf(a[i], b.x, acc[i][0]);
                acc[i][1] = fmaf(a[i], b.y, acc[i][1]);
                acc[i][2] = fmaf(a[i], b.z, acc[i][2]);
                acc[i][3] = fmaf(a[i], b.w, acc[i][3]);
            }
        }
        __syncthreads();
    }
    #pragma unroll
    for (int i = 0; i < TM; ++i) {
        int r = r0 + tr * TM + i;
        if (r < n) {
            float o0 = RELU ? fmaxf(acc[i][0], 0.f) : acc[i][0];
            float o1 = RELU ? fmaxf(acc[i][1], 0.f) : acc[i][1];
            float o2 = RELU ? fmaxf(acc[i][2], 0.f) : acc[i][2];
            float o3 = RELU ? fmaxf(acc[i][3], 0.f) : acc[i][3];
            if constexpr (std::is_same<OT, __half>::value) {
                __half2 h0 = __floats2half2_rn(o0, o1);
                __half2 h1 = __floats2half2_rn(o2, o3);
                uint2 u = make_uint2(*(unsigned*)&h0, *(unsigned*)&h1);
                *(uint2*)(out + (long)r * M + tc * 4) = u;
            } else {
                *(float4*)(out + (long)r * M + tc * 4) = make_float4(o0, o1, o2, o3);
            }
        }
    }
}

// ---------------- fp32 -> fp16 convert (4 elems/thread) ---------------------
__global__ void tohalf_kernel(const float* __restrict__ in, __half* __restrict__ out, int n4)
{
    int i = blockIdx.x * blockDim.x + threadIdx.x;
    if (i >= n4) return;
    float4 v = ((const float4*)in)[i];
    __half2 a = __floats2half2_rn(v.x, v.y);
    __half2 b = __floats2half2_rn(v.z, v.w);
    ((uint2*)out)[i] = make_uint2(*(unsigned*)&a, *(unsigned*)&b);
}

// ---------------- phase A: per-(bucket,block) counts, LDS histogram ---------
__global__ __launch_bounds__(256) void count_kernel(
    const int* __restrict__ dst2, const int* __restrict__ dst1,
    const int* __restrict__ dst0, int* __restrict__ G)
{
    __shared__ int h[NB];
    int tid = threadIdx.x, blk = blockIdx.x;
    for (int i = tid; i < NB; i += 256) h[i] = 0;
    __syncthreads();
    int e0 = blk * CHUNK, e1 = min(e0 + CHUNK, ETOTC);
    for (int e = e0 + tid; e < e1; e += 256) {
        int vg;
        if (e < EE2) vg = dst2[e];
        else if (e < EE2 + EE1) vg = NN2 + dst1[e - EE2];
        else vg = NN2 + NN1 + dst0[e - EE2 - EE1];
        atomicAdd(&h[vg >> 10], 1);
    }
    __syncthreads();
    for (int i = tid; i < NB; i += 256) G[i * NBLK + blk] = h[i];
}

// in-place exclusive scan, 1024 items / block of 256 threads
__global__ __launch_bounds__(256) void scan_block_kernel(int* data, int* bsum, int n)
{
    __shared__ int sh[256];
    int tid = threadIdx.x;
    int base = blockIdx.x * 1024 + tid * 4;
    int v[4];
    #pragma unroll
    for (int i = 0; i < 4; ++i) v[i] = (base + i < n) ? data[base + i] : 0;
    int tot = v[0] + v[1] + v[2] + v[3];
    sh[tid] = tot;
    __syncthreads();
    for (int d = 1; d < 256; d <<= 1) {
        int add = (tid >= d) ? sh[tid - d] : 0;
        __syncthreads();
        sh[tid] += add;
        __syncthreads();
    }
    int run = sh[tid] - tot;
    #pragma unroll
    for (int i = 0; i < 4; ++i) {
        if (base + i < n) data[base + i] = run;
        run += v[i];
    }
    if (tid == 255) bsum[blockIdx.x] = sh[255];
}

__global__ __launch_bounds__(256) void scan_bsum_kernel(int* bsum, int nb)
{
    __shared__ int sh[256];
    int tid = threadIdx.x;
    int v = (tid < nb) ? bsum[tid] : 0;
    sh[tid] = v;
    __syncthreads();
    for (int d = 1; d < 256; d <<= 1) {
        int add = (tid >= d) ? sh[tid - d] : 0;
        __syncthreads();
        sh[tid] += add;
        __syncthreads();
    }
    if (tid < nb) bsum[tid] = sh[tid] - v;
}

__global__ void scan_add_kernel(int* data, const int* __restrict__ bsum, int n)
{
    int i = blockIdx.x * blockDim.x + threadIdx.x;
    if (i < n) data[i] += bsum[i >> 10];
}

// ---------------- phase C: place edges into bucket-grouped array ------------
__global__ __launch_bounds__(256) void place_kernel(
    const int* __restrict__ src2, const int* __restrict__ dst2,
    const int* __restrict__ src1, const int* __restrict__ dst1,
    const float* __restrict__ ew1,
    const int* __restrict__ src0, const int* __restrict__ dst0,
    const float* __restrict__ ew0,
    const int* __restrict__ G, int2* __restrict__ bedges)
{
    __shared__ int cur[NB];
    int tid = threadIdx.x, blk = blockIdx.x;
    for (int i = tid; i < NB; i += 256) cur[i] = G[i * NBLK + blk];
    __syncthreads();
    int e0 = blk * CHUNK, e1 = min(e0 + CHUNK, ETOTC);
    for (int e = e0 + tid; e < e1; e += 256) {
        int vg, src, ewb;
        if (e < EE2) { vg = dst2[e]; src = src2[e]; ewb = 0; }
        else if (e < EE2 + EE1) {
            int i = e - EE2;
            vg = NN2 + dst1[i]; src = src1[i]; ewb = __float_as_int(ew1[i]);
        } else {
            int i = e - EE2 - EE1;
            vg = NN2 + NN1 + dst0[i]; src = src0[i]; ewb = __float_as_int(ew0[i]);
        }
        int b = vg >> 10, local = vg & 1023;
        int pos = atomicAdd(&cur[b], 1);   // LDS atomic only
        bedges[pos] = make_int2((local << 17) | src, ewb);
    }
}

// ------- phase D: per-bucket LIVE-ONLY CSR + rp/re + dis --------------------
// wdeg over ALL edges (deg semantics); csr keeps only edges with live src,
// storing the COMPACT src index directly.
__global__ __launch_bounds__(256) void bucket_build_kernel(
    const int2* __restrict__ bedges, const int* __restrict__ G,
    const int* __restrict__ inv1, const int* __restrict__ inv0,
    int* __restrict__ rp, int* __restrict__ re,
    int2* __restrict__ csr, float* __restrict__ dis)
{
    __shared__ int cnt[1024];
    __shared__ float wdeg[1024];
    __shared__ int excl[1024];
    __shared__ int tsum[256];
    int b = blockIdx.x, tid = threadIdx.x;
    int s0 = G[b * NBLK];
    int s1 = (b == NB - 1) ? ETOTC : G[(b + 1) * NBLK];
    for (int i = tid; i < 1024; i += 256) { cnt[i] = 0; wdeg[i] = 0.f; }
    __syncthreads();
    for (int i = s0 + tid; i < s1; i += 256) {
        int2 t = bedges[i];
        int local = t.x >> 17;
        int src = t.x & 0x1FFFF;
        atomicAdd(&wdeg[local], __int_as_float(t.y));  // all edges count for deg
        int vg = (b << 10) + local;
        int c = (vg < NN2) ? src : ((vg < NN2 + NN1) ? inv1[src] : inv0[src]);
        if (c >= 0) atomicAdd(&cnt[local], 1);
    }
    __syncthreads();
    int base4 = tid * 4;
    int v0 = cnt[base4], v1 = cnt[base4 + 1], v2 = cnt[base4 + 2], v3 = cnt[base4 + 3];
    int tot = v0 + v1 + v2 + v3;
    tsum[tid] = tot;
    __syncthreads();
    for (int d = 1; d < 256; d <<= 1) {
        int add = (tid >= d) ? tsum[tid - d] : 0;
        __syncthreads();
        tsum[tid] += add;
        __syncthreads();
    }
    int run = tsum[tid] - tot;
    excl[base4] = run;
    excl[base4 + 1] = run + v0;
    excl[base4 + 2] = run + v0 + v1;
    excl[base4 + 3] = run + v0 + v1 + v2;
    __syncthreads();
    for (int i = tid; i < 1024; i += 256) {
        int vg = (b << 10) + i;
        if (vg < NTOTC) {
            int r0_ = s0 + excl[i];
            rp[vg] = r0_;
            re[vg] = r0_ + cnt[i];
            if (vg >= NN2) dis[vg - NN2] = rsqrtf(wdeg[i] + 2.0f);
        }
        cnt[i] = 0;
    }
    __syncthreads();
    for (int i = s0 + tid; i < s1; i += 256) {
        int2 t = bedges[i];
        int local = t.x >> 17;
        int src = t.x & 0x1FFFF;
        int vg = (b << 10) + local;
        int c = (vg < NN2) ? src : ((vg < NN2 + NN1) ? inv1[src] : inv0[src]);
        if (c >= 0) {
            int pos = s0 + excl[local] + atomicAdd(&cnt[local], 1);
            csr[pos] = make_int2(c, t.y);
        }
    }
}

// ---------------- inverse perms ---------------------------------------------
__global__ void inv_kernel(const int* __restrict__ perm1, const int* __restrict__ perm0,
                           int* __restrict__ inv1, int* __restrict__ inv0)
{
    int i = blockIdx.x * blockDim.x + threadIdx.x;
    if (i < NN2) inv1[perm1[i]] = i;
    else if (i < NN2 + NN1) inv0[perm0[i - NN2]] = i - NN2;
}

// ---------------- compact-indexed dis tables --------------------------------
__global__ void disc_kernel(const int* __restrict__ perm1, const int* __restrict__ perm0,
                            const float* __restrict__ dis,
                            float* __restrict__ disc1, float* __restrict__ disc0)
{
    int i = blockIdx.x * blockDim.x + threadIdx.x;
    if (i < NN2) disc1[i] = dis[perm1[i]];
    else if (i < NN2 + NN1) disc0[i - NN2] = dis[NN1 + perm0[i - NN2]];
}

// ---------------- GIN gather: wave per node, D=64, fp16 table, 4x unroll ----
template <bool BN>
__global__ __launch_bounds__(256) void gin_gather_kernel(
    const __half* __restrict__ x, const int* __restrict__ rp, const int* __restrict__ re,
    const int2* __restrict__ csr,
    const float* __restrict__ sums, const float* __restrict__ sumsq,
    const float* __restrict__ g, const float* __restrict__ bt,
    float* __restrict__ out, int n)
{
    int v = (blockIdx.x * 256 + threadIdx.x) >> 6;
    int lane = threadIdx.x & 63;
    if (v >= n) return;
    int p0 = rp[v], pe = re[v];
    float a0 = __half2float(x[(long)v * 64 + lane]);
    float a1 = 0.f, a2 = 0.f, a3 = 0.f;
    for (int base = p0; base < pe; base += 64) {
        int idx = base + lane;
        int s_l = 0; float m_l = 0.f;
        if (idx < pe) { s_l = csr[idx].x; m_l = 1.f; }
        int cnt = min(64, pe - base);
        for (int j = 0; j < cnt; j += 4) {
            int s0 = __shfl(s_l, j),     s1 = __shfl(s_l, j + 1);
            int s2 = __shfl(s_l, j + 2), s3 = __shfl(s_l, j + 3);
            float m0 = __shfl(m_l, j),     m1 = __shfl(m_l, j + 1);
            float m2 = __shfl(m_l, j + 2), m3 = __shfl(m_l, j + 3);
            a0 = fmaf(m0, __half2float(x[(long)s0 * 64 + lane]), a0);
            a1 = fmaf(m1, __half2float(x[(long)s1 * 64 + lane]), a1);
            a2 = fmaf(m2, __half2float(x[(long)s2 * 64 + lane]), a2);
            a3 = fmaf(m3, __half2float(x[(long)s3 * 64 + lane]), a3);
        }
    }
    float acc = (a0 + a1) + (a2 + a3);
    if (BN) {
        int deg = pe - p0;
        float mu = sums[lane] * (1.f / NN2);
        float rs = rsqrtf(sumsq[lane] * (1.f / NN2) - mu * mu + BN_EPS);
        float a = g[lane] * rs;
        acc = a * acc + (float)(deg + 1) * (bt[lane] - a * mu);
    }
    out[(long)v * 64 + lane] = acc;
}

// ---------------- GCN gather: live-only CSR, compact idx, 4x unroll ---------
template <bool RELU>
__global__ __launch_bounds__(256) void gcn_gather128_kernel(
    const __half* __restrict__ cmp, const int* __restrict__ inv,
    const int* __restrict__ rp, const int* __restrict__ re,
    const int2* __restrict__ csr, const float* __restrict__ disc,
    const float* __restrict__ dis, const float* __restrict__ bias,
    float* __restrict__ out, int n)
{
    int v = (blockIdx.x * 256 + threadIdx.x) >> 6;
    int lane = threadIdx.x & 63;
    if (v >= n) return;
    int p0 = rp[v], pe = re[v];
    float ax0 = 0.f, ay0 = 0.f, ax1 = 0.f, ay1 = 0.f;
    float ax2 = 0.f, ay2 = 0.f, ax3 = 0.f, ay3 = 0.f;
    for (int base = p0; base < pe; base += 64) {
        int idx = base + lane;
        int cs_l = 0; float w_l = 0.f;
        if (idx < pe) {
            int2 sl = csr[idx];
            cs_l = sl.x;
            w_l = __int_as_float(sl.y) * disc[sl.x];
        }
        int cnt = min(64, pe - base);
        for (int j = 0; j < cnt; j += 4) {
            int c0 = __shfl(cs_l, j),     c1 = __shfl(cs_l, j + 1);
            int c2 = __shfl(cs_l, j + 2), c3 = __shfl(cs_l, j + 3);
            float w0 = __shfl(w_l, j),     w1 = __shfl(w_l, j + 1);
            float w2 = __shfl(w_l, j + 2), w3 = __shfl(w_l, j + 3);
            float2 h0 = __half22float2(*(const __half2*)(cmp + (long)c0 * 128 + lane * 2));
            float2 h1 = __half22float2(*(const __half2*)(cmp + (long)c1 * 128 + lane * 2));
            float2 h2 = __half22float2(*(const __half2*)(cmp + (long)c2 * 128 + lane * 2));
            float2 h3 = __half22float2(*(const __half2*)(cmp + (long)c3 * 128 + lane * 2));
            ax0 = fmaf(w0, h0.x, ax0); ay0 = fmaf(w0, h0.y, ay0);
            ax1 = fmaf(w1, h1.x, ax1); ay1 = fmaf(w1, h1.y, ay1);
            ax2 = fmaf(w2, h2.x, ax2); ay2 = fmaf(w2, h2.y, ay2);
            ax3 = fmaf(w3, h3.x, ax3); ay3 = fmaf(w3, h3.y, ay3);
        }
    }
    float ax = (ax0 + ax1) + (ax2 + ax3);
    float ay = (ay0 + ay1) + (ay2 + ay3);
    float dv = dis[v];
    int cv = inv[v];
    float sx = 0.f, sy = 0.f;
    if (cv >= 0) {
        float2 hv = __half22float2(*(const __half2*)(cmp + (long)cv * 128 + lane * 2));
        sx = hv.x; sy = hv.y;
    }
    float s2 = 2.f * dv * dv;
    float o0 = fmaf(dv, ax, fmaf(s2, sx, bias[lane * 2]));
    float o1 = fmaf(dv, ay, fmaf(s2, sy, bias[lane * 2 + 1]));
    if (RELU) { o0 = fmaxf(o0, 0.f); o1 = fmaxf(o1, 0.f); }
    *(float2*)(out + (long)v * 128 + lane * 2) = make_float2(o0, o1);
}

template <bool RELU>
__global__ __launch_bounds__(256) void gcn_gather64_kernel(
    const __half* __restrict__ cmp, const int* __restrict__ inv,
    const int* __restrict__ rp, const int* __restrict__ re,
    const int2* __restrict__ csr, const float* __restrict__ disc,
    const float* __restrict__ dis, const float* __restrict__ bias,
    float* __restrict__ out, int n)
{
    int v = (blockIdx.x * 256 + threadIdx.x) >> 6;
    int lane = threadIdx.x & 63;
    if (v >= n) return;
    int p0 = rp[v], pe = re[v];
    float a0 = 0.f, a1 = 0.f, a2 = 0.f, a3 = 0.f;
    for (int base = p0; base < pe; base += 64) {
        int idx = base + lane;
        int cs_l = 0; float w_l = 0.f;
        if (idx < pe) {
            int2 sl = csr[idx];
            cs_l = sl.x;
            w_l = __int_as_float(sl.y) * disc[sl.x];
        }
        int cnt = min(64, pe - base);
        for (int j = 0; j < cnt; j += 4) {
            int c0 = __shfl(cs_l, j),     c1 = __shfl(cs_l, j + 1);
            int c2 = __shfl(cs_l, j + 2), c3 = __shfl(cs_l, j + 3);
            float w0 = __shfl(w_l, j),     w1 = __shfl(w_l, j + 1);
            float w2 = __shfl(w_l, j + 2), w3 = __shfl(w_l, j + 3);
            float h0 = __half2float(cmp[(long)c0 * 64 + lane]);
            float h1 = __half2float(cmp[(long)c1 * 64 + lane]);
            float h2 = __half2float(cmp[(long)c2 * 64 + lane]);
            float h3 = __half2float(cmp[(long)c3 * 64 + lane]);
            a0 = fmaf(w0, h0, a0);
            a1 = fmaf(w1, h1, a1);
            a2 = fmaf(w2, h2, a2);
            a3 = fmaf(w3, h3, a3);
        }
    }
    float acc = (a0 + a1) + (a2 + a3);
    float dv = dis[v];
    int cv = inv[v];
    float sv = (cv >= 0) ? __half2float(cmp[(long)cv * 64 + lane]) : 0.f;
    float o = fmaf(dv, acc, fmaf(2.f * dv * dv, sv, bias[lane]));
    if (RELU) o = fmaxf(o, 0.f);
    out[(long)v * 64 + lane] = o;
}

// ---------------- BatchNorm stats -------------------------------------------
template <int D, typename IT>
__global__ __launch_bounds__(256) void bn_partial_kernel(
    const IT* __restrict__ h, float* __restrict__ sums,
    float* __restrict__ sumsq, int n)
{
    constexpr int R = 256 / D;
    const int c = threadIdx.x % D, lr = threadIdx.x / D;
    float s = 0.f, s2 = 0.f;
    for (int r = blockIdx.x * R + lr; r < n; r += gridDim.x * R) {
        float v = ldf(&h[(long)r * D + c]);
        s += v; s2 += v * v;
    }
    __shared__ float ls[256], ls2[256];
    ls[threadIdx.x] = s; ls2[threadIdx.x] = s2;
    __syncthreads();
    if (lr == 0) {
        #pragma unroll
        for (int j = 1; j < R; ++j) { s += ls[j * D + c]; s2 += ls2[j * D + c]; }
        atomicAdd(&sums[c], s);
        atomicAdd(&sumsq[c], s2);
    }
}

// ---------------- launch ----------------------------------------------------
extern "C" void kernel_launch(void* const* d_in, const int* in_sizes, int n_in,
                              void* d_out, int out_size, void* d_ws, size_t ws_size,
                              hipStream_t stream)
{
    const float* x    = (const float*)d_in[0];
    const int*   ei2  = (const int*)d_in[1];
    const int*   ei0  = (const int*)d_in[4];
    const int*   ei1  = (const int*)d_in[5];
    const float* ew0  = (const float*)d_in[6];
    const float* ew1  = (const float*)d_in[7];
    const int*   perm0= (const int*)d_in[8];
    const int*   perm1= (const int*)d_in[9];
    const float* W1a  = (const float*)d_in[10];
    const float* b1a  = (const float*)d_in[11];
    const float* W1b  = (const float*)d_in[12];
    const float* b1b  = (const float*)d_in[13];
    const float* g1   = (const float*)d_in[14];
    const float* bt1  = (const float*)d_in[15];
    const float* W2a  = (const float*)d_in[16];
    const float* b2a  = (const float*)d_in[17];
    const float* W2b  = (const float*)d_in[18];
    const float* b2b  = (const float*)d_in[19];
    const float* g2   = (const float*)d_in[20];
    const float* bt2  = (const float*)d_in[21];
    const float* Wg0  = (const float*)d_in[22];
    const float* bg0  = (const float*)d_in[23];
    const float* Wg1  = (const float*)d_in[24];
    const float* bg1  = (const float*)d_in[25];
    float* out = (float*)d_out;

    float* ws  = (float*)d_ws;
    int*   wsi = (int*)d_ws;

    // ---- layout (element offsets), max 17.0M floats = 68 MB ----
    int*   rp    = wsi;                     // 175000
    int*   re    = wsi + 175000;            // 175000 -> 350000
    float* dis   = ws  + 350000;            // 150000 (N1|N0) -> 500000
    float* disc1 = ws  + 500000;            // 25000 -> 525000
    float* disc0 = ws  + 525000;            // 50000 -> 575000
    int*   inv1  = wsi + 575000;            // 50000 -> 625000
    int*   inv0  = wsi + 625000;            // 100000 -> 725000
    float* s1    = ws  + 725000;            // 64
    float* q1    = ws  + 725064;
    float* s2    = ws  + 725128;            // 128
    float* q2    = ws  + 725256;            // -> 725384
    int*   bsum  = wsi + 725500;            // 64
    int*   G     = wsi + 726000;            // 36594 -> pad 763000
    int2*  bedges= (int2*)(wsi + 763000);   // 1.75M int2 -> 4,263,000
    int2*  csr   = (int2*)(wsi + 4263000);  // up to 1.75M int2 -> 7,763,000
    __half* xh   = (__half*)(wsi + 763000); // N2*64 half (bedges dead) -> 1,563,000
    __half* t0h  = (__half*)(ws + 7763000); // N2*64 half -> 8,563,000
    float* t1    = ws  + 9000000;           // N2*64 f -> 10,600,000
    float* Ba    = ws  + 10600000;          // N2*128 f -> 13,800,000
    float* Bb    = ws  + 13800000;          // N2*128 f -> 17,000,000
    __half* cmp1 = (__half*)(ws + 7763000); // N2*128 half (t0h,t1 dead) -> 9,363,000
    float* out1  = ws  + 10600000;          // N1*128 f over Ba+Bb (dead)
    __half* cmp0 = (__half*)(ws + 7763000); // N1*64 half (cmp1 dead)
    float* t0f   = ws  + 9000000;           // reuse t1 slot order: gather1 out (before t1 live)

    const int* src2 = ei2, *dst2 = ei2 + EE2;
    const int* src1 = ei1, *dst1 = ei1 + EE1;
    const int* src0 = ei0, *dst0 = ei0 + EE0;

    const int NG = NB * NBLK;  // 36594

    // ---- prep ----
    hipMemsetAsync(s1, 0, 384 * 4, stream);
    hipMemsetAsync(inv1, 0xFF, (NN1 + NN0) * 4, stream);
    inv_kernel<<<cdiv(NN2 + NN1, 256), 256, 0, stream>>>(perm1, perm0, inv1, inv0);
    count_kernel<<<NBLK, 256, 0, stream>>>(dst2, dst1, dst0, G);
    scan_block_kernel<<<cdiv(NG, 1024), 256, 0, stream>>>(G, bsum, NG);
    scan_bsum_kernel<<<1, 256, 0, stream>>>(bsum, cdiv(NG, 1024));
    scan_add_kernel<<<cdiv(NG, 256), 256, 0, stream>>>(G, bsum, NG);
    place_kernel<<<NBLK, 256, 0, stream>>>(
        src2, dst2, src1, dst1, ew1, src0, dst0, ew0, G, bedges);
    bucket_build_kernel<<<NB, 256, 0, stream>>>(
        bedges, G, inv1, inv0, rp, re, csr, dis);
    disc_kernel<<<cdiv(NN2 + NN1, 256), 256, 0, stream>>>(perm1, perm0, dis, disc1, disc0);
    // bedges dead now -> xh into its slot
    tohalf_kernel<<<cdiv(NN2 * 16, 256), 256, 0, stream>>>(x, xh, NN2 * 16);

    // ---- GIN layer 1 ----
    gin_gather_kernel<false><<<cdiv(NN2, 4), 256, 0, stream>>>(
        xh, rp, re, csr, nullptr, nullptr, nullptr, nullptr, t0f, NN2);
    gemm_kernel<64, 64, 64, true, false, float><<<cdiv(NN2, 64), 256, 0, stream>>>(
        t0f, W1a, b1a, nullptr, nullptr, nullptr, nullptr, t1 + 1600000, NN2);  // t1b = ws+10,600,000? no
    // NOTE: t0f occupies [9.0M,10.6M); put intermediate in Ba slot then back
    gemm_kernel<64, 64, 64, true, false, __half><<<cdiv(NN2, 64), 256, 0, stream>>>(
        t1 + 1600000, W1b, b1b, nullptr, nullptr, nullptr, nullptr, t0h, NN2);
    bn_partial_kernel<64, __half><<<256, 256, 0, stream>>>(t0h, s1, q1, NN2);

    // ---- GIN layer 2 (BN1 folded into gather epilogue; fp16 table) ----
    gin_gather_kernel<true><<<cdiv(NN2, 4), 256, 0, stream>>>(
        t0h, rp, re, csr, s1, q1, g1, bt1, t1, NN2);
    gemm_kernel<64, 64, 128, true, false, float><<<cdiv(NN2, 64), 256, 0, stream>>>(
        t1, W2a, b2a, nullptr, nullptr, nullptr, nullptr, Ba, NN2);
    gemm_kernel<64, 128, 128, true, false, float><<<cdiv(NN2, 64), 256, 0, stream>>>(
        Ba, W2b, b2b, nullptr, nullptr, nullptr, nullptr, Bb, NN2);
    bn_partial_kernel<128, float><<<256, 256, 0, stream>>>(Bb, s2, q2, NN2);

    // ---- GCN level 1: cmp1 = BN2(Bb) @ Wg0 (compact fp16), gather -> out1 --
    gemm_kernel<64, 128, 128, false, true, __half><<<cdiv(NN2, 64), 256, 0, stream>>>(
        Bb, Wg0, nullptr, s2, q2, g2, bt2, cmp1, NN2);
    gcn_gather128_kernel<true><<<cdiv(NN1, 4), 256, 0, stream>>>(
        cmp1, inv1, rp + NN2, re + NN2, csr, disc1, dis, bg0, out1, NN1);

    // ---- GCN level 0: cmp0 = out1 @ Wg1 (compact fp16), gather -> d_out ----
    gemm_kernel<64, 128, 64, false, false, __half><<<cdiv(NN1, 64), 256, 0, stream>>>(
        out1, Wg1, nullptr, nullptr, nullptr, nullptr, nullptr, cmp0, NN1);
    gcn_gather64_kernel<false><<<cdiv(NN0, 4), 256, 0, stream>>>(
        cmp0, inv0, rp + NN2 + NN1, re + NN2 + NN1, csr, disc0, dis + NN1, bg1, out, NN0);
}

// Round 10
// 308.536 us; speedup vs baseline: 1.0614x; 1.0614x over previous
//
#include <hip/hip_runtime.h>
#include <hip/hip_fp16.h>
#include <type_traits>

#define NN2 25000
#define NN1 50000
#define NN0 100000
#define EE2 250000
#define EE1 500000
#define EE0 1000000
#define NTOTC 175000
#define ETOTC 1750000
#define NB 684            // ceil(175104/256) coarse buckets of 256 nodes (vg>>8)
#define CHUNK 8192        // edges per count/place block
#define NBLK 214          // ceil(ETOTC/CHUNK)
#define BN_EPS 1e-5f

static inline int cdiv(long a, long b) { return (int)((a + b - 1) / b); }

template <typename T>
__device__ inline float ldf(const T* p) {
    if constexpr (std::is_same<T, __half>::value) return __half2float(*p);
    else return *p;
}

// ---------------- GEMM: out[r] = act(bn?(in[r,:K]) @ W[K,M] + bias) ---------
template <int BM, int K, int M, bool RELU, bool BNIN, typename OT>
__global__ __launch_bounds__(256) void gemm_kernel(
    const float* __restrict__ in, const float* __restrict__ W,
    const float* __restrict__ bias,
    const float* __restrict__ sums, const float* __restrict__ sumsq,
    const float* __restrict__ g, const float* __restrict__ bt,
    OT* __restrict__ out, int n)
{
    constexpr int BK = 32;
    constexpr int COLG = M / 4;
    constexpr int ROWG = 256 / COLG;
    constexpr int TM = BM / ROWG;
    __shared__ float As[BM * (BK + 1)];
    __shared__ float Bs[BK * M];
    const int tid = threadIdx.x;
    const int r0 = blockIdx.x * BM;
    const int tc = tid % COLG, tr = tid / COLG;

    float acc[TM][4];
    #pragma unroll
    for (int i = 0; i < TM; ++i)
        #pragma unroll
        for (int j = 0; j < 4; ++j)
            acc[i][j] = (bias != nullptr) ? bias[tc * 4 + j] : 0.f;

    for (int k0 = 0; k0 < K; k0 += BK) {
        #pragma unroll
        for (int rr = 0; rr < BM; rr += 32) {
            int r = rr + (tid >> 3), kc = (tid & 7) << 2;
            int gr = r0 + r;
            float4 av = make_float4(0.f, 0.f, 0.f, 0.f);
            if (gr < n) av = *(const float4*)(in + (long)gr * K + k0 + kc);
            float a4[4] = {av.x, av.y, av.z, av.w};
            #pragma unroll
            for (int c = 0; c < 4; ++c) {
                if (BNIN) {
                    int ch = k0 + kc + c;
                    float mu = sums[ch] * (1.f / NN2);
                    float rs = rsqrtf(sumsq[ch] * (1.f / NN2) - mu * mu + BN_EPS);
                    a4[c] = g[ch] * rs * (a4[c] - mu) + bt[ch];
                }
                As[r * (BK + 1) + kc + c] = a4[c];
            }
        }
        #pragma unroll
        for (int idx = tid; idx < BK * M / 4; idx += 256) {
            int kk = idx / COLG, cc = (idx % COLG) * 4;
            *(float4*)&Bs[kk * M + cc] = *(const float4*)(W + (long)(k0 + kk) * M + cc);
        }
        __syncthreads();
        #pragma unroll
        for (int kk = 0; kk < BK; ++kk) {
            float4 b = *(const float4*)&Bs[kk * M + tc * 4];
            float a[TM];
            #pragma unroll
            for (int i = 0; i < TM; ++i) a[i] = As[(tr * TM + i) * (BK + 1) + kk];
            #pragma unroll
            for (int i = 0; i < TM; ++i) {
                acc[i][0] = fmaf(a[i], b.x, acc[i][0]);
                acc[i][1] = fmaf(a[i], b.y, acc[i][1]);
                acc[i][2] = fmaf(a[i], b.z, acc[i][2]);
                acc[i][3] = fmaf(a[i], b.w, acc[i][3]);
            }
        }
        __syncthreads();
    }
    #pragma unroll
    for (int i = 0; i < TM; ++i) {
        int r = r0 + tr * TM + i;
        if (r < n) {
            float o0 = RELU ? fmaxf(acc[i][0], 0.f) : acc[i][0];
            float o1 = RELU ? fmaxf(acc[i][1], 0.f) : acc[i][1];
            float o2 = RELU ? fmaxf(acc[i][2], 0.f) : acc[i][2];
            float o3 = RELU ? fmaxf(acc[i][3], 0.f) : acc[i][3];
            if constexpr (std::is_same<OT, __half>::value) {
                __half2 h0 = __floats2half2_rn(o0, o1);
                __half2 h1 = __floats2half2_rn(o2, o3);
                uint2 u = make_uint2(*(unsigned*)&h0, *(unsigned*)&h1);
                *(uint2*)(out + (long)r * M + tc * 4) = u;
            } else {
                *(float4*)(out + (long)r * M + tc * 4) = make_float4(o0, o1, o2, o3);
            }
        }
    }
}

// ---------------- fp32 -> fp16 convert (4 elems/thread) ---------------------
__global__ void tohalf_kernel(const float* __restrict__ in, __half* __restrict__ out, int n4)
{
    int i = blockIdx.x * blockDim.x + threadIdx.x;
    if (i >= n4) return;
    float4 v = ((const float4*)in)[i];
    __half2 a = __floats2half2_rn(v.x, v.y);
    __half2 b = __floats2half2_rn(v.z, v.w);
    ((uint2*)out)[i] = make_uint2(*(unsigned*)&a, *(unsigned*)&b);
}

// ---------------- phase A: per-(bucket,block) counts, LDS histogram ---------
__global__ __launch_bounds__(256) void count_kernel(
    const int* __restrict__ dst2, const int* __restrict__ dst1,
    const int* __restrict__ dst0, int* __restrict__ G)
{
    __shared__ int h[NB];
    int tid = threadIdx.x, blk = blockIdx.x;
    for (int i = tid; i < NB; i += 256) h[i] = 0;
    __syncthreads();
    int e0 = blk * CHUNK, e1 = min(e0 + CHUNK, ETOTC);
    for (int e = e0 + tid; e < e1; e += 256) {
        int vg;
        if (e < EE2) vg = dst2[e];
        else if (e < EE2 + EE1) vg = NN2 + dst1[e - EE2];
        else vg = NN2 + NN1 + dst0[e - EE2 - EE1];
        atomicAdd(&h[vg >> 8], 1);
    }
    __syncthreads();
    for (int i = tid; i < NB; i += 256) G[i * NBLK + blk] = h[i];
}

// in-place exclusive scan, 1024 items / block of 256 threads
__global__ __launch_bounds__(256) void scan_block_kernel(int* data, int* bsum, int n)
{
    __shared__ int sh[256];
    int tid = threadIdx.x;
    int base = blockIdx.x * 1024 + tid * 4;
    int v[4];
    #pragma unroll
    for (int i = 0; i < 4; ++i) v[i] = (base + i < n) ? data[base + i] : 0;
    int tot = v[0] + v[1] + v[2] + v[3];
    sh[tid] = tot;
    __syncthreads();
    for (int d = 1; d < 256; d <<= 1) {
        int add = (tid >= d) ? sh[tid - d] : 0;
        __syncthreads();
        sh[tid] += add;
        __syncthreads();
    }
    int run = sh[tid] - tot;
    #pragma unroll
    for (int i = 0; i < 4; ++i) {
        if (base + i < n) data[base + i] = run;
        run += v[i];
    }
    if (tid == 255) bsum[blockIdx.x] = sh[255];
}

__global__ __launch_bounds__(256) void scan_bsum_kernel(int* bsum, int nb)
{
    __shared__ int sh[256];
    int tid = threadIdx.x;
    int v = (tid < nb) ? bsum[tid] : 0;
    sh[tid] = v;
    __syncthreads();
    for (int d = 1; d < 256; d <<= 1) {
        int add = (tid >= d) ? sh[tid - d] : 0;
        __syncthreads();
        sh[tid] += add;
        __syncthreads();
    }
    if (tid < nb) bsum[tid] = sh[tid] - v;
}

__global__ void scan_add_kernel(int* data, const int* __restrict__ bsum, int n)
{
    int i = blockIdx.x * blockDim.x + threadIdx.x;
    if (i < n) data[i] += bsum[i >> 10];
}

// ------- phase C: place + inv-translate; bedges = ((local<<16)|(c+1), ew) ---
// c = compact live index (or -1 dead). GIN edges: c = src (always live).
__global__ __launch_bounds__(256) void place_kernel(
    const int* __restrict__ src2, const int* __restrict__ dst2,
    const int* __restrict__ src1, const int* __restrict__ dst1,
    const float* __restrict__ ew1,
    const int* __restrict__ src0, const int* __restrict__ dst0,
    const float* __restrict__ ew0,
    const int* __restrict__ inv1, const int* __restrict__ inv0,
    const int* __restrict__ G, int2* __restrict__ bedges)
{
    __shared__ int cur[NB];
    int tid = threadIdx.x, blk = blockIdx.x;
    for (int i = tid; i < NB; i += 256) cur[i] = G[i * NBLK + blk];
    __syncthreads();
    int e0 = blk * CHUNK, e1 = min(e0 + CHUNK, ETOTC);
    for (int e = e0 + tid; e < e1; e += 256) {
        int vg, c, ewb;
        if (e < EE2) {
            vg = dst2[e]; c = src2[e]; ewb = 0;
        } else if (e < EE2 + EE1) {
            int i = e - EE2;
            vg = NN2 + dst1[i]; c = inv1[src1[i]]; ewb = __float_as_int(ew1[i]);
        } else {
            int i = e - EE2 - EE1;
            vg = NN2 + NN1 + dst0[i]; c = inv0[src0[i]]; ewb = __float_as_int(ew0[i]);
        }
        int b = vg >> 8, local = vg & 255;
        int pos = atomicAdd(&cur[b], 1);   // LDS atomic only
        bedges[pos] = make_int2((local << 16) | (c + 1), ewb);
    }
}

// ------- phase D: per-bucket (256 nodes) live-only CSR + rp/re + dis --------
__global__ __launch_bounds__(256) void bucket_build_kernel(
    const int2* __restrict__ bedges, const int* __restrict__ G,
    int* __restrict__ rp, int* __restrict__ re,
    int2* __restrict__ csr, float* __restrict__ dis)
{
    __shared__ int cnt[256];
    __shared__ float wdeg[256];
    __shared__ int excl[256];
    __shared__ int tsum[256];
    int b = blockIdx.x, tid = threadIdx.x;
    int s0 = G[b * NBLK];
    int s1 = (b == NB - 1) ? ETOTC : G[(b + 1) * NBLK];
    cnt[tid] = 0; wdeg[tid] = 0.f;
    __syncthreads();
    for (int i = s0 + tid; i < s1; i += 256) {
        int2 t = bedges[i];
        int local = t.x >> 16;
        atomicAdd(&wdeg[local], __int_as_float(t.y));   // all edges -> deg
        if (t.x & 0xFFFF) atomicAdd(&cnt[local], 1);    // live only
    }
    __syncthreads();
    int v = cnt[tid];
    tsum[tid] = v;
    __syncthreads();
    for (int d = 1; d < 256; d <<= 1) {
        int add = (tid >= d) ? tsum[tid - d] : 0;
        __syncthreads();
        tsum[tid] += add;
        __syncthreads();
    }
    excl[tid] = tsum[tid] - v;
    {
        int vg = (b << 8) + tid;
        if (vg < NTOTC) {
            int r0_ = s0 + excl[tid];
            rp[vg] = r0_;
            re[vg] = r0_ + v;
            if (vg >= NN2) dis[vg - NN2] = rsqrtf(wdeg[tid] + 2.0f);
        }
    }
    cnt[tid] = 0;
    __syncthreads();
    for (int i = s0 + tid; i < s1; i += 256) {
        int2 t = bedges[i];
        int cx = t.x & 0xFFFF;
        if (cx) {
            int local = t.x >> 16;
            int pos = s0 + excl[local] + atomicAdd(&cnt[local], 1);
            csr[pos] = make_int2(cx - 1, t.y);
        }
    }
}

// ---------------- inverse perms ---------------------------------------------
__global__ void inv_kernel(const int* __restrict__ perm1, const int* __restrict__ perm0,
                           int* __restrict__ inv1, int* __restrict__ inv0)
{
    int i = blockIdx.x * blockDim.x + threadIdx.x;
    if (i < NN2) inv1[perm1[i]] = i;
    else if (i < NN2 + NN1) inv0[perm0[i - NN2]] = i - NN2;
}

// ---------------- compact-indexed dis tables --------------------------------
__global__ void disc_kernel(const int* __restrict__ perm1, const int* __restrict__ perm0,
                            const float* __restrict__ dis,
                            float* __restrict__ disc1, float* __restrict__ disc0)
{
    int i = blockIdx.x * blockDim.x + threadIdx.x;
    if (i < NN2) disc1[i] = dis[perm1[i]];
    else if (i < NN2 + NN1) disc0[i - NN2] = dis[NN1 + perm0[i - NN2]];
}

// ---------------- GIN gather: wave per node, D=64, fp16 table, 4x unroll ----
template <bool BN>
__global__ __launch_bounds__(256) void gin_gather_kernel(
    const __half* __restrict__ x, const int* __restrict__ rp, const int* __restrict__ re,
    const int2* __restrict__ csr,
    const float* __restrict__ sums, const float* __restrict__ sumsq,
    const float* __restrict__ g, const float* __restrict__ bt,
    float* __restrict__ out, int n)
{
    int v = (blockIdx.x * 256 + threadIdx.x) >> 6;
    int lane = threadIdx.x & 63;
    if (v >= n) return;
    int p0 = rp[v], pe = re[v];
    float a0 = __half2float(x[(long)v * 64 + lane]);
    float a1 = 0.f, a2 = 0.f, a3 = 0.f;
    for (int base = p0; base < pe; base += 64) {
        int idx = base + lane;
        int s_l = 0; float m_l = 0.f;
        if (idx < pe) { s_l = csr[idx].x; m_l = 1.f; }
        int cnt = min(64, pe - base);
        for (int j = 0; j < cnt; j += 4) {
            int s0 = __shfl(s_l, j),     s1 = __shfl(s_l, j + 1);
            int s2 = __shfl(s_l, j + 2), s3 = __shfl(s_l, j + 3);
            float m0 = __shfl(m_l, j),     m1 = __shfl(m_l, j + 1);
            float m2 = __shfl(m_l, j + 2), m3 = __shfl(m_l, j + 3);
            a0 = fmaf(m0, __half2float(x[(long)s0 * 64 + lane]), a0);
            a1 = fmaf(m1, __half2float(x[(long)s1 * 64 + lane]), a1);
            a2 = fmaf(m2, __half2float(x[(long)s2 * 64 + lane]), a2);
            a3 = fmaf(m3, __half2float(x[(long)s3 * 64 + lane]), a3);
        }
    }
    float acc = (a0 + a1) + (a2 + a3);
    if (BN) {
        int deg = pe - p0;
        float mu = sums[lane] * (1.f / NN2);
        float rs = rsqrtf(sumsq[lane] * (1.f / NN2) - mu * mu + BN_EPS);
        float a = g[lane] * rs;
        acc = a * acc + (float)(deg + 1) * (bt[lane] - a * mu);
    }
    out[(long)v * 64 + lane] = acc;
}

// ---------------- GCN gather: live-only CSR, compact idx, 4x unroll ---------
template <bool RELU>
__global__ __launch_bounds__(256) void gcn_gather128_kernel(
    const __half* __restrict__ cmp, const int* __restrict__ inv,
    const int* __restrict__ rp, const int* __restrict__ re,
    const int2* __restrict__ csr, const float* __restrict__ disc,
    const float* __restrict__ dis, const float* __restrict__ bias,
    float* __restrict__ out, int n)
{
    int v = (blockIdx.x * 256 + threadIdx.x) >> 6;
    int lane = threadIdx.x & 63;
    if (v >= n) return;
    int p0 = rp[v], pe = re[v];
    float ax0 = 0.f, ay0 = 0.f, ax1 = 0.f, ay1 = 0.f;
    float ax2 = 0.f, ay2 = 0.f, ax3 = 0.f, ay3 = 0.f;
    for (int base = p0; base < pe; base += 64) {
        int idx = base + lane;
        int cs_l = 0; float w_l = 0.f;
        if (idx < pe) {
            int2 sl = csr[idx];
            cs_l = sl.x;
            w_l = __int_as_float(sl.y) * disc[sl.x];
        }
        int cnt = min(64, pe - base);
        for (int j = 0; j < cnt; j += 4) {
            int c0 = __shfl(cs_l, j),     c1 = __shfl(cs_l, j + 1);
            int c2 = __shfl(cs_l, j + 2), c3 = __shfl(cs_l, j + 3);
            float w0 = __shfl(w_l, j),     w1 = __shfl(w_l, j + 1);
            float w2 = __shfl(w_l, j + 2), w3 = __shfl(w_l, j + 3);
            float2 h0 = __half22float2(*(const __half2*)(cmp + (long)c0 * 128 + lane * 2));
            float2 h1 = __half22float2(*(const __half2*)(cmp + (long)c1 * 128 + lane * 2));
            float2 h2 = __half22float2(*(const __half2*)(cmp + (long)c2 * 128 + lane * 2));
            float2 h3 = __half22float2(*(const __half2*)(cmp + (long)c3 * 128 + lane * 2));
            ax0 = fmaf(w0, h0.x, ax0); ay0 = fmaf(w0, h0.y, ay0);
            ax1 = fmaf(w1, h1.x, ax1); ay1 = fmaf(w1, h1.y, ay1);
            ax2 = fmaf(w2, h2.x, ax2); ay2 = fmaf(w2, h2.y, ay2);
            ax3 = fmaf(w3, h3.x, ax3); ay3 = fmaf(w3, h3.y, ay3);
        }
    }
    float ax = (ax0 + ax1) + (ax2 + ax3);
    float ay = (ay0 + ay1) + (ay2 + ay3);
    float dv = dis[v];
    int cv = inv[v];
    float sx = 0.f, sy = 0.f;
    if (cv >= 0) {
        float2 hv = __half22float2(*(const __half2*)(cmp + (long)cv * 128 + lane * 2));
        sx = hv.x; sy = hv.y;
    }
    float s2 = 2.f * dv * dv;
    float o0 = fmaf(dv, ax, fmaf(s2, sx, bias[lane * 2]));
    float o1 = fmaf(dv, ay, fmaf(s2, sy, bias[lane * 2 + 1]));
    if (RELU) { o0 = fmaxf(o0, 0.f); o1 = fmaxf(o1, 0.f); }
    *(float2*)(out + (long)v * 128 + lane * 2) = make_float2(o0, o1);
}

template <bool RELU>
__global__ __launch_bounds__(256) void gcn_gather64_kernel(
    const __half* __restrict__ cmp, const int* __restrict__ inv,
    const int* __restrict__ rp, const int* __restrict__ re,
    const int2* __restrict__ csr, const float* __restrict__ disc,
    const float* __restrict__ dis, const float* __restrict__ bias,
    float* __restrict__ out, int n)
{
    int v = (blockIdx.x * 256 + threadIdx.x) >> 6;
    int lane = threadIdx.x & 63;
    if (v >= n) return;
    int p0 = rp[v], pe = re[v];
    float a0 = 0.f, a1 = 0.f, a2 = 0.f, a3 = 0.f;
    for (int base = p0; base < pe; base += 64) {
        int idx = base + lane;
        int cs_l = 0; float w_l = 0.f;
        if (idx < pe) {
            int2 sl = csr[idx];
            cs_l = sl.x;
            w_l = __int_as_float(sl.y) * disc[sl.x];
        }
        int cnt = min(64, pe - base);
        for (int j = 0; j < cnt; j += 4) {
            int c0 = __shfl(cs_l, j),     c1 = __shfl(cs_l, j + 1);
            int c2 = __shfl(cs_l, j + 2), c3 = __shfl(cs_l, j + 3);
            float w0 = __shfl(w_l, j),     w1 = __shfl(w_l, j + 1);
            float w2 = __shfl(w_l, j + 2), w3 = __shfl(w_l, j + 3);
            float h0 = __half2float(cmp[(long)c0 * 64 + lane]);
            float h1 = __half2float(cmp[(long)c1 * 64 + lane]);
            float h2 = __half2float(cmp[(long)c2 * 64 + lane]);
            float h3 = __half2float(cmp[(long)c3 * 64 + lane]);
            a0 = fmaf(w0, h0, a0);
            a1 = fmaf(w1, h1, a1);
            a2 = fmaf(w2, h2, a2);
            a3 = fmaf(w3, h3, a3);
        }
    }
    float acc = (a0 + a1) + (a2 + a3);
    float dv = dis[v];
    int cv = inv[v];
    float sv = (cv >= 0) ? __half2float(cmp[(long)cv * 64 + lane]) : 0.f;
    float o = fmaf(dv, acc, fmaf(2.f * dv * dv, sv, bias[lane]));
    if (RELU) o = fmaxf(o, 0.f);
    out[(long)v * 64 + lane] = o;
}

// ---------------- BatchNorm stats -------------------------------------------
template <int D, typename IT>
__global__ __launch_bounds__(256) void bn_partial_kernel(
    const IT* __restrict__ h, float* __restrict__ sums,
    float* __restrict__ sumsq, int n)
{
    constexpr int R = 256 / D;
    const int c = threadIdx.x % D, lr = threadIdx.x / D;
    float s = 0.f, s2 = 0.f;
    for (int r = blockIdx.x * R + lr; r < n; r += gridDim.x * R) {
        float v = ldf(&h[(long)r * D + c]);
        s += v; s2 += v * v;
    }
    __shared__ float ls[256], ls2[256];
    ls[threadIdx.x] = s; ls2[threadIdx.x] = s2;
    __syncthreads();
    if (lr == 0) {
        #pragma unroll
        for (int j = 1; j < R; ++j) { s += ls[j * D + c]; s2 += ls2[j * D + c]; }
        atomicAdd(&sums[c], s);
        atomicAdd(&sumsq[c], s2);
    }
}

// ---------------- launch ----------------------------------------------------
extern "C" void kernel_launch(void* const* d_in, const int* in_sizes, int n_in,
                              void* d_out, int out_size, void* d_ws, size_t ws_size,
                              hipStream_t stream)
{
    const float* x    = (const float*)d_in[0];
    const int*   ei2  = (const int*)d_in[1];
    const int*   ei0  = (const int*)d_in[4];
    const int*   ei1  = (const int*)d_in[5];
    const float* ew0  = (const float*)d_in[6];
    const float* ew1  = (const float*)d_in[7];
    const int*   perm0= (const int*)d_in[8];
    const int*   perm1= (const int*)d_in[9];
    const float* W1a  = (const float*)d_in[10];
    const float* b1a  = (const float*)d_in[11];
    const float* W1b  = (const float*)d_in[12];
    const float* b1b  = (const float*)d_in[13];
    const float* g1   = (const float*)d_in[14];
    const float* bt1  = (const float*)d_in[15];
    const float* W2a  = (const float*)d_in[16];
    const float* b2a  = (const float*)d_in[17];
    const float* W2b  = (const float*)d_in[18];
    const float* b2b  = (const float*)d_in[19];
    const float* g2   = (const float*)d_in[20];
    const float* bt2  = (const float*)d_in[21];
    const float* Wg0  = (const float*)d_in[22];
    const float* bg0  = (const float*)d_in[23];
    const float* Wg1  = (const float*)d_in[24];
    const float* bg1  = (const float*)d_in[25];
    float* out = (float*)d_out;

    float* ws  = (float*)d_ws;
    int*   wsi = (int*)d_ws;

    // ---- layout (float-element offsets), max 17.0M floats = 68 MB ----
    int*   rp    = wsi;                     // 175104 -> pad 176000
    int*   re    = wsi + 176000;            // 175104 -> 352000
    float* dis   = ws  + 352000;            // 150000 (N1|N0) -> 502000
    float* disc1 = ws  + 502000;            // 25000 -> 527000
    float* disc0 = ws  + 527000;            // 50000 -> 577000
    int*   inv1  = wsi + 577000;            // 50000 -> 627000
    int*   inv0  = wsi + 627000;            // 100000 -> 727000
    float* s1    = ws  + 727000;            // 64
    float* q1    = ws  + 727064;
    float* s2    = ws  + 727128;            // 128
    float* q2    = ws  + 727256;            // -> 727384
    int*   bsum  = wsi + 727500;            // 150
    int*   G     = wsi + 728000;            // NB*NBLK = 146376 -> pad 875000
    int2*  bedges= (int2*)(wsi + 875000);   // 1.75M int2 -> 4,375,000
    int2*  csr   = (int2*)(wsi + 4375000);  // up to 1.75M int2 -> 7,875,000
    __half* xh   = (__half*)(wsi + 875000); // N2*64 half (bedges dead) -> 1,675,000
    __half* t0h  = (__half*)(ws + 7875000); // N2*64 half -> 8,675,000
    float* t0f   = ws  + 9000000;           // N2*64 f -> 10,600,000 (GIN1 gather out)
    float* t1    = ws  + 9000000;           // N2*64 f (reuses t0f slot after dead)
    float* BaF   = ws  + 10600000;          // N2*64 f (GIN1 mid; inside Ba slot)
    float* Ba    = ws  + 10600000;          // N2*128 f -> 13,800,000
    float* Bb    = ws  + 13800000;          // N2*128 f -> 17,000,000
    __half* cmp1 = (__half*)(ws + 7875000); // N2*128 half -> 9,475,000 f (t0h,t1 dead)
    float* out1  = ws  + 10600000;          // N1*128 f over Ba+Bb (dead)
    __half* cmp0 = (__half*)(ws + 7875000); // N1*64 half (cmp1 dead)

    const int* src2 = ei2, *dst2 = ei2 + EE2;
    const int* src1 = ei1, *dst1 = ei1 + EE1;
    const int* src0 = ei0, *dst0 = ei0 + EE0;

    const int NG = NB * NBLK;  // 146376

    // ---- prep ----
    hipMemsetAsync(s1, 0, 384 * 4, stream);
    hipMemsetAsync(inv1, 0xFF, (NN1 + NN0) * 4, stream);
    inv_kernel<<<cdiv(NN2 + NN1, 256), 256, 0, stream>>>(perm1, perm0, inv1, inv0);
    count_kernel<<<NBLK, 256, 0, stream>>>(dst2, dst1, dst0, G);
    scan_block_kernel<<<cdiv(NG, 1024), 256, 0, stream>>>(G, bsum, NG);
    scan_bsum_kernel<<<1, 256, 0, stream>>>(bsum, cdiv(NG, 1024));
    scan_add_kernel<<<cdiv(NG, 256), 256, 0, stream>>>(G, bsum, NG);
    place_kernel<<<NBLK, 256, 0, stream>>>(
        src2, dst2, src1, dst1, ew1, src0, dst0, ew0, inv1, inv0, G, bedges);
    bucket_build_kernel<<<NB, 256, 0, stream>>>(bedges, G, rp, re, csr, dis);
    disc_kernel<<<cdiv(NN2 + NN1, 256), 256, 0, stream>>>(perm1, perm0, dis, disc1, disc0);
    // bedges dead now -> xh into its slot
    tohalf_kernel<<<cdiv(NN2 * 16, 256), 256, 0, stream>>>(x, xh, NN2 * 16);

    // ---- GIN layer 1 ----
    gin_gather_kernel<false><<<cdiv(NN2, 4), 256, 0, stream>>>(
        xh, rp, re, csr, nullptr, nullptr, nullptr, nullptr, t0f, NN2);
    gemm_kernel<64, 64, 64, true, false, float><<<cdiv(NN2, 64), 256, 0, stream>>>(
        t0f, W1a, b1a, nullptr, nullptr, nullptr, nullptr, BaF, NN2);
    gemm_kernel<64, 64, 64, true, false, __half><<<cdiv(NN2, 64), 256, 0, stream>>>(
        BaF, W1b, b1b, nullptr, nullptr, nullptr, nullptr, t0h, NN2);
    bn_partial_kernel<64, __half><<<256, 256, 0, stream>>>(t0h, s1, q1, NN2);

    // ---- GIN layer 2 (BN1 folded into gather epilogue; fp16 table) ----
    gin_gather_kernel<true><<<cdiv(NN2, 4), 256, 0, stream>>>(
        t0h, rp, re, csr, s1, q1, g1, bt1, t1, NN2);
    gemm_kernel<64, 64, 128, true, false, float><<<cdiv(NN2, 64), 256, 0, stream>>>(
        t1, W2a, b2a, nullptr, nullptr, nullptr, nullptr, Ba, NN2);
    gemm_kernel<64, 128, 128, true, false, float><<<cdiv(NN2, 64), 256, 0, stream>>>(
        Ba, W2b, b2b, nullptr, nullptr, nullptr, nullptr, Bb, NN2);
    bn_partial_kernel<128, float><<<256, 256, 0, stream>>>(Bb, s2, q2, NN2);

    // ---- GCN level 1: cmp1 = BN2(Bb) @ Wg0 (compact fp16), gather -> out1 --
    gemm_kernel<64, 128, 128, false, true, __half><<<cdiv(NN2, 64), 256, 0, stream>>>(
        Bb, Wg0, nullptr, s2, q2, g2, bt2, cmp1, NN2);
    gcn_gather128_kernel<true><<<cdiv(NN1, 4), 256, 0, stream>>>(
        cmp1, inv1, rp + NN2, re + NN2, csr, disc1, dis, bg0, out1, NN1);

    // ---- GCN level 0: cmp0 = out1 @ Wg1 (compact fp16), gather -> d_out ----
    gemm_kernel<64, 128, 64, false, false, __half><<<cdiv(NN1, 64), 256, 0, stream>>>(
        out1, Wg1, nullptr, nullptr, nullptr, nullptr, nullptr, cmp0, NN1);
    gcn_gather64_kernel<false><<<cdiv(NN0, 4), 256, 0, stream>>>(
        cmp0, inv0, rp + NN2 + NN1, re + NN2 + NN1, csr, disc0, dis + NN1, bg1, out, NN0);
}

// Round 11
// 306.839 us; speedup vs baseline: 1.0673x; 1.0055x over previous
//
#include <hip/hip_runtime.h>
#include <hip/hip_fp16.h>
#include <type_traits>

#define NN2 25000
#define NN1 50000
#define NN0 100000
#define EE2 250000
#define EE1 500000
#define EE0 1000000
#define NTOTC 175000
#define ETOTC 1750000
#define NB 684            // ceil(175104/256) coarse buckets of 256 nodes (vg>>8)
#define CHUNK 4096        // edges per count/place block
#define NBLK 428          // ceil(ETOTC/CHUNK)
#define BN_EPS 1e-5f

static inline int cdiv(long a, long b) { return (int)((a + b - 1) / b); }

template <typename T>
__device__ inline float ldf(const T* p) {
    if constexpr (std::is_same<T, __half>::value) return __half2float(*p);
    else return *p;
}

// ---------------- GEMM: out[r] = act(bn?(in[r,:K]) @ W[K,M] + bias) ---------
template <int BM, int K, int M, bool RELU, bool BNIN, typename OT>
__global__ __launch_bounds__(256) void gemm_kernel(
    const float* __restrict__ in, const float* __restrict__ W,
    const float* __restrict__ bias,
    const float* __restrict__ sums, const float* __restrict__ sumsq,
    const float* __restrict__ g, const float* __restrict__ bt,
    OT* __restrict__ out, int n)
{
    constexpr int BK = 32;
    constexpr int COLG = M / 4;
    constexpr int ROWG = 256 / COLG;
    constexpr int TM = BM / ROWG;
    __shared__ float As[BM * (BK + 1)];
    __shared__ float Bs[BK * M];
    const int tid = threadIdx.x;
    const int r0 = blockIdx.x * BM;
    const int tc = tid % COLG, tr = tid / COLG;

    float acc[TM][4];
    #pragma unroll
    for (int i = 0; i < TM; ++i)
        #pragma unroll
        for (int j = 0; j < 4; ++j)
            acc[i][j] = (bias != nullptr) ? bias[tc * 4 + j] : 0.f;

    for (int k0 = 0; k0 < K; k0 += BK) {
        #pragma unroll
        for (int rr = 0; rr < BM; rr += 32) {
            int r = rr + (tid >> 3), kc = (tid & 7) << 2;
            int gr = r0 + r;
            float4 av = make_float4(0.f, 0.f, 0.f, 0.f);
            if (gr < n) av = *(const float4*)(in + (long)gr * K + k0 + kc);
            float a4[4] = {av.x, av.y, av.z, av.w};
            #pragma unroll
            for (int c = 0; c < 4; ++c) {
                if (BNIN) {
                    int ch = k0 + kc + c;
                    float mu = sums[ch] * (1.f / NN2);
                    float rs = rsqrtf(sumsq[ch] * (1.f / NN2) - mu * mu + BN_EPS);
                    a4[c] = g[ch] * rs * (a4[c] - mu) + bt[ch];
                }
                As[r * (BK + 1) + kc + c] = a4[c];
            }
        }
        #pragma unroll
        for (int idx = tid; idx < BK * M / 4; idx += 256) {
            int kk = idx / COLG, cc = (idx % COLG) * 4;
            *(float4*)&Bs[kk * M + cc] = *(const float4*)(W + (long)(k0 + kk) * M + cc);
        }
        __syncthreads();
        #pragma unroll
        for (int kk = 0; kk < BK; ++kk) {
            float4 b = *(const float4*)&Bs[kk * M + tc * 4];
            float a[TM];
            #pragma unroll
            for (int i = 0; i < TM; ++i) a[i] = As[(tr * TM + i) * (BK + 1) + kk];
            #pragma unroll
            for (int i = 0; i < TM; ++i) {
                acc[i][0] = fmaf(a[i], b.x, acc[i][0]);
                acc[i][1] = fmaf(a[i], b.y, acc[i][1]);
                acc[i][2] = fmaf(a[i], b.z, acc[i][2]);
                acc[i][3] = fmaf(a[i], b.w, acc[i][3]);
            }
        }
        __syncthreads();
    }
    #pragma unroll
    for (int i = 0; i < TM; ++i) {
        int r = r0 + tr * TM + i;
        if (r < n) {
            float o0 = RELU ? fmaxf(acc[i][0], 0.f) : acc[i][0];
            float o1 = RELU ? fmaxf(acc[i][1], 0.f) : acc[i][1];
            float o2 = RELU ? fmaxf(acc[i][2], 0.f) : acc[i][2];
            float o3 = RELU ? fmaxf(acc[i][3], 0.f) : acc[i][3];
            if constexpr (std::is_same<OT, __half>::value) {
                __half2 h0 = __floats2half2_rn(o0, o1);
                __half2 h1 = __floats2half2_rn(o2, o3);
                uint2 u = make_uint2(*(unsigned*)&h0, *(unsigned*)&h1);
                *(uint2*)(out + (long)r * M + tc * 4) = u;
            } else {
                *(float4*)(out + (long)r * M + tc * 4) = make_float4(o0, o1, o2, o3);
            }
        }
    }
}

// ---------------- fp32 -> fp16 convert (4 elems/thread) ---------------------
__global__ void tohalf_kernel(const float* __restrict__ in, __half* __restrict__ out, int n4)
{
    int i = blockIdx.x * blockDim.x + threadIdx.x;
    if (i >= n4) return;
    float4 v = ((const float4*)in)[i];
    __half2 a = __floats2half2_rn(v.x, v.y);
    __half2 b = __floats2half2_rn(v.z, v.w);
    ((uint2*)out)[i] = make_uint2(*(unsigned*)&a, *(unsigned*)&b);
}

// ------- translate: random inv lookups at HIGH occupancy (grid-stride) ------
__global__ void translate_kernel(const int* __restrict__ src1, const int* __restrict__ src0,
                                 const int* __restrict__ inv1, const int* __restrict__ inv0,
                                 int* __restrict__ tcg)
{
    int e = blockIdx.x * blockDim.x + threadIdx.x;
    if (e < EE1) tcg[e] = inv1[src1[e]];
    else if (e < EE1 + EE0) tcg[e] = inv0[src0[e - EE1]];
}

// ---------------- phase A: per-(bucket,block) counts, LDS histogram ---------
__global__ __launch_bounds__(256) void count_kernel(
    const int* __restrict__ dst2, const int* __restrict__ dst1,
    const int* __restrict__ dst0, int* __restrict__ G)
{
    __shared__ int h[NB];
    int tid = threadIdx.x, blk = blockIdx.x;
    for (int i = tid; i < NB; i += 256) h[i] = 0;
    __syncthreads();
    int e0 = blk * CHUNK, e1 = min(e0 + CHUNK, ETOTC);
    for (int e = e0 + tid; e < e1; e += 256) {
        int vg;
        if (e < EE2) vg = dst2[e];
        else if (e < EE2 + EE1) vg = NN2 + dst1[e - EE2];
        else vg = NN2 + NN1 + dst0[e - EE2 - EE1];
        atomicAdd(&h[vg >> 8], 1);
    }
    __syncthreads();
    for (int i = tid; i < NB; i += 256) G[i * NBLK + blk] = h[i];
}

// in-place exclusive scan, 1024 items / block of 256 threads
__global__ __launch_bounds__(256) void scan_block_kernel(int* data, int* bsum, int n)
{
    __shared__ int sh[256];
    int tid = threadIdx.x;
    int base = blockIdx.x * 1024 + tid * 4;
    int v[4];
    #pragma unroll
    for (int i = 0; i < 4; ++i) v[i] = (base + i < n) ? data[base + i] : 0;
    int tot = v[0] + v[1] + v[2] + v[3];
    sh[tid] = tot;
    __syncthreads();
    for (int d = 1; d < 256; d <<= 1) {
        int add = (tid >= d) ? sh[tid - d] : 0;
        __syncthreads();
        sh[tid] += add;
        __syncthreads();
    }
    int run = sh[tid] - tot;
    #pragma unroll
    for (int i = 0; i < 4; ++i) {
        if (base + i < n) data[base + i] = run;
        run += v[i];
    }
    if (tid == 255) bsum[blockIdx.x] = sh[255];
}

__global__ __launch_bounds__(512) void scan_bsum_kernel(int* bsum, int nb)
{
    __shared__ int sh[512];
    int tid = threadIdx.x;
    int v = (tid < nb) ? bsum[tid] : 0;
    sh[tid] = v;
    __syncthreads();
    for (int d = 1; d < 512; d <<= 1) {
        int add = (tid >= d) ? sh[tid - d] : 0;
        __syncthreads();
        sh[tid] += add;
        __syncthreads();
    }
    if (tid < nb) bsum[tid] = sh[tid] - v;
}

__global__ void scan_add_kernel(int* data, const int* __restrict__ bsum, int n)
{
    int i = blockIdx.x * blockDim.x + threadIdx.x;
    if (i < n) data[i] += bsum[i >> 10];
}

// ------- phase C: place (streaming only); bedges = ((local<<16)|(c+1), ew) --
__global__ __launch_bounds__(256) void place_kernel(
    const int* __restrict__ src2, const int* __restrict__ dst2,
    const int* __restrict__ dst1, const float* __restrict__ ew1,
    const int* __restrict__ dst0, const float* __restrict__ ew0,
    const int* __restrict__ tcg,
    const int* __restrict__ G, int2* __restrict__ bedges)
{
    __shared__ int cur[NB];
    int tid = threadIdx.x, blk = blockIdx.x;
    for (int i = tid; i < NB; i += 256) cur[i] = G[i * NBLK + blk];
    __syncthreads();
    int e0 = blk * CHUNK, e1 = min(e0 + CHUNK, ETOTC);
    for (int e = e0 + tid; e < e1; e += 256) {
        int vg, c, ewb;
        if (e < EE2) {
            vg = dst2[e]; c = src2[e]; ewb = 0;
        } else if (e < EE2 + EE1) {
            int i = e - EE2;
            vg = NN2 + dst1[i]; c = tcg[i]; ewb = __float_as_int(ew1[i]);
        } else {
            int i = e - EE2 - EE1;
            vg = NN2 + NN1 + dst0[i]; c = tcg[EE1 + i]; ewb = __float_as_int(ew0[i]);
        }
        int b = vg >> 8, local = vg & 255;
        int pos = atomicAdd(&cur[b], 1);   // LDS atomic only
        bedges[pos] = make_int2((local << 16) | (c + 1), ewb);
    }
}

// ------- phase D: per-bucket (256 nodes) live-only CSR + rp/re + dis --------
__global__ __launch_bounds__(256) void bucket_build_kernel(
    const int2* __restrict__ bedges, const int* __restrict__ G,
    int* __restrict__ rp, int* __restrict__ re,
    int2* __restrict__ csr, float* __restrict__ dis)
{
    __shared__ int cnt[256];
    __shared__ float wdeg[256];
    __shared__ int excl[256];
    __shared__ int tsum[256];
    int b = blockIdx.x, tid = threadIdx.x;
    int s0 = G[b * NBLK];
    int s1 = (b == NB - 1) ? ETOTC : G[(b + 1) * NBLK];
    cnt[tid] = 0; wdeg[tid] = 0.f;
    __syncthreads();
    for (int i = s0 + tid; i < s1; i += 256) {
        int2 t = bedges[i];
        int local = t.x >> 16;
        atomicAdd(&wdeg[local], __int_as_float(t.y));   // all edges -> deg
        if (t.x & 0xFFFF) atomicAdd(&cnt[local], 1);    // live only
    }
    __syncthreads();
    int v = cnt[tid];
    tsum[tid] = v;
    __syncthreads();
    for (int d = 1; d < 256; d <<= 1) {
        int add = (tid >= d) ? tsum[tid - d] : 0;
        __syncthreads();
        tsum[tid] += add;
        __syncthreads();
    }
    excl[tid] = tsum[tid] - v;
    {
        int vg = (b << 8) + tid;
        if (vg < NTOTC) {
            int r0_ = s0 + excl[tid];
            rp[vg] = r0_;
            re[vg] = r0_ + v;
            if (vg >= NN2) dis[vg - NN2] = rsqrtf(wdeg[tid] + 2.0f);
        }
    }
    cnt[tid] = 0;
    __syncthreads();
    for (int i = s0 + tid; i < s1; i += 256) {
        int2 t = bedges[i];
        int cx = t.x & 0xFFFF;
        if (cx) {
            int local = t.x >> 16;
            int pos = s0 + excl[local] + atomicAdd(&cnt[local], 1);
            csr[pos] = make_int2(cx - 1, t.y);
        }
    }
}

// ---------------- inverse perms ---------------------------------------------
__global__ void inv_kernel(const int* __restrict__ perm1, const int* __restrict__ perm0,
                           int* __restrict__ inv1, int* __restrict__ inv0)
{
    int i = blockIdx.x * blockDim.x + threadIdx.x;
    if (i < NN2) inv1[perm1[i]] = i;
    else if (i < NN2 + NN1) inv0[perm0[i - NN2]] = i - NN2;
}

// ---------------- compact-indexed dis tables --------------------------------
__global__ void disc_kernel(const int* __restrict__ perm1, const int* __restrict__ perm0,
                            const float* __restrict__ dis,
                            float* __restrict__ disc1, float* __restrict__ disc0)
{
    int i = blockIdx.x * blockDim.x + threadIdx.x;
    if (i < NN2) disc1[i] = dis[perm1[i]];
    else if (i < NN2 + NN1) disc0[i - NN2] = dis[NN1 + perm0[i - NN2]];
}

// ---------------- GIN gather: wave per node, D=64, fp16 table, 4x unroll ----
template <bool BN>
__global__ __launch_bounds__(256) void gin_gather_kernel(
    const __half* __restrict__ x, const int* __restrict__ rp, const int* __restrict__ re,
    const int2* __restrict__ csr,
    const float* __restrict__ sums, const float* __restrict__ sumsq,
    const float* __restrict__ g, const float* __restrict__ bt,
    float* __restrict__ out, int n)
{
    int v = (blockIdx.x * 256 + threadIdx.x) >> 6;
    int lane = threadIdx.x & 63;
    if (v >= n) return;
    int p0 = rp[v], pe = re[v];
    float a0 = __half2float(x[(long)v * 64 + lane]);
    float a1 = 0.f, a2 = 0.f, a3 = 0.f;
    for (int base = p0; base < pe; base += 64) {
        int idx = base + lane;
        int s_l = 0; float m_l = 0.f;
        if (idx < pe) { s_l = csr[idx].x; m_l = 1.f; }
        int cnt = min(64, pe - base);
        for (int j = 0; j < cnt; j += 4) {
            int s0 = __shfl(s_l, j),     s1 = __shfl(s_l, j + 1);
            int s2 = __shfl(s_l, j + 2), s3 = __shfl(s_l, j + 3);
            float m0 = __shfl(m_l, j),     m1 = __shfl(m_l, j + 1);
            float m2 = __shfl(m_l, j + 2), m3 = __shfl(m_l, j + 3);
            a0 = fmaf(m0, __half2float(x[(long)s0 * 64 + lane]), a0);
            a1 = fmaf(m1, __half2float(x[(long)s1 * 64 + lane]), a1);
            a2 = fmaf(m2, __half2float(x[(long)s2 * 64 + lane]), a2);
            a3 = fmaf(m3, __half2float(x[(long)s3 * 64 + lane]), a3);
        }
    }
    float acc = (a0 + a1) + (a2 + a3);
    if (BN) {
        int deg = pe - p0;
        float mu = sums[lane] * (1.f / NN2);
        float rs = rsqrtf(sumsq[lane] * (1.f / NN2) - mu * mu + BN_EPS);
        float a = g[lane] * rs;
        acc = a * acc + (float)(deg + 1) * (bt[lane] - a * mu);
    }
    out[(long)v * 64 + lane] = acc;
}

// ---------------- GCN gather: live-only CSR, compact idx, 4x unroll ---------
template <bool RELU>
__global__ __launch_bounds__(256) void gcn_gather128_kernel(
    const __half* __restrict__ cmp, const int* __restrict__ inv,
    const int* __restrict__ rp, const int* __restrict__ re,
    const int2* __restrict__ csr, const float* __restrict__ disc,
    const float* __restrict__ dis, const float* __restrict__ bias,
    float* __restrict__ out, int n)
{
    int v = (blockIdx.x * 256 + threadIdx.x) >> 6;
    int lane = threadIdx.x & 63;
    if (v >= n) return;
    int p0 = rp[v], pe = re[v];
    float ax0 = 0.f, ay0 = 0.f, ax1 = 0.f, ay1 = 0.f;
    float ax2 = 0.f, ay2 = 0.f, ax3 = 0.f, ay3 = 0.f;
    for (int base = p0; base < pe; base += 64) {
        int idx = base + lane;
        int cs_l = 0; float w_l = 0.f;
        if (idx < pe) {
            int2 sl = csr[idx];
            cs_l = sl.x;
            w_l = __int_as_float(sl.y) * disc[sl.x];
        }
        int cnt = min(64, pe - base);
        for (int j = 0; j < cnt; j += 4) {
            int c0 = __shfl(cs_l, j),     c1 = __shfl(cs_l, j + 1);
            int c2 = __shfl(cs_l, j + 2), c3 = __shfl(cs_l, j + 3);
            float w0 = __shfl(w_l, j),     w1 = __shfl(w_l, j + 1);
            float w2 = __shfl(w_l, j + 2), w3 = __shfl(w_l, j + 3);
            float2 h0 = __half22float2(*(const __half2*)(cmp + (long)c0 * 128 + lane * 2));
            float2 h1 = __half22float2(*(const __half2*)(cmp + (long)c1 * 128 + lane * 2));
            float2 h2 = __half22float2(*(const __half2*)(cmp + (long)c2 * 128 + lane * 2));
            float2 h3 = __half22float2(*(const __half2*)(cmp + (long)c3 * 128 + lane * 2));
            ax0 = fmaf(w0, h0.x, ax0); ay0 = fmaf(w0, h0.y, ay0);
            ax1 = fmaf(w1, h1.x, ax1); ay1 = fmaf(w1, h1.y, ay1);
            ax2 = fmaf(w2, h2.x, ax2); ay2 = fmaf(w2, h2.y, ay2);
            ax3 = fmaf(w3, h3.x, ax3); ay3 = fmaf(w3, h3.y, ay3);
        }
    }
    float ax = (ax0 + ax1) + (ax2 + ax3);
    float ay = (ay0 + ay1) + (ay2 + ay3);
    float dv = dis[v];
    int cv = inv[v];
    float sx = 0.f, sy = 0.f;
    if (cv >= 0) {
        float2 hv = __half22float2(*(const __half2*)(cmp + (long)cv * 128 + lane * 2));
        sx = hv.x; sy = hv.y;
    }
    float s2 = 2.f * dv * dv;
    float o0 = fmaf(dv, ax, fmaf(s2, sx, bias[lane * 2]));
    float o1 = fmaf(dv, ay, fmaf(s2, sy, bias[lane * 2 + 1]));
    if (RELU) { o0 = fmaxf(o0, 0.f); o1 = fmaxf(o1, 0.f); }
    *(float2*)(out + (long)v * 128 + lane * 2) = make_float2(o0, o1);
}

template <bool RELU>
__global__ __launch_bounds__(256) void gcn_gather64_kernel(
    const __half* __restrict__ cmp, const int* __restrict__ inv,
    const int* __restrict__ rp, const int* __restrict__ re,
    const int2* __restrict__ csr, const float* __restrict__ disc,
    const float* __restrict__ dis, const float* __restrict__ bias,
    float* __restrict__ out, int n)
{
    int v = (blockIdx.x * 256 + threadIdx.x) >> 6;
    int lane = threadIdx.x & 63;
    if (v >= n) return;
    int p0 = rp[v], pe = re[v];
    float a0 = 0.f, a1 = 0.f, a2 = 0.f, a3 = 0.f;
    for (int base = p0; base < pe; base += 64) {
        int idx = base + lane;
        int cs_l = 0; float w_l = 0.f;
        if (idx < pe) {
            int2 sl = csr[idx];
            cs_l = sl.x;
            w_l = __int_as_float(sl.y) * disc[sl.x];
        }
        int cnt = min(64, pe - base);
        for (int j = 0; j < cnt; j += 4) {
            int c0 = __shfl(cs_l, j),     c1 = __shfl(cs_l, j + 1);
            int c2 = __shfl(cs_l, j + 2), c3 = __shfl(cs_l, j + 3);
            float w0 = __shfl(w_l, j),     w1 = __shfl(w_l, j + 1);
            float w2 = __shfl(w_l, j + 2), w3 = __shfl(w_l, j + 3);
            float h0 = __half2float(cmp[(long)c0 * 64 + lane]);
            float h1 = __half2float(cmp[(long)c1 * 64 + lane]);
            float h2 = __half2float(cmp[(long)c2 * 64 + lane]);
            float h3 = __half2float(cmp[(long)c3 * 64 + lane]);
            a0 = fmaf(w0, h0, a0);
            a1 = fmaf(w1, h1, a1);
            a2 = fmaf(w2, h2, a2);
            a3 = fmaf(w3, h3, a3);
        }
    }
    float acc = (a0 + a1) + (a2 + a3);
    float dv = dis[v];
    int cv = inv[v];
    float sv = (cv >= 0) ? __half2float(cmp[(long)cv * 64 + lane]) : 0.f;
    float o = fmaf(dv, acc, fmaf(2.f * dv * dv, sv, bias[lane]));
    if (RELU) o = fmaxf(o, 0.f);
    out[(long)v * 64 + lane] = o;
}

// ---------------- BatchNorm stats -------------------------------------------
template <int D, typename IT>
__global__ __launch_bounds__(256) void bn_partial_kernel(
    const IT* __restrict__ h, float* __restrict__ sums,
    float* __restrict__ sumsq, int n)
{
    constexpr int R = 256 / D;
    const int c = threadIdx.x % D, lr = threadIdx.x / D;
    float s = 0.f, s2 = 0.f;
    for (int r = blockIdx.x * R + lr; r < n; r += gridDim.x * R) {
        float v = ldf(&h[(long)r * D + c]);
        s += v; s2 += v * v;
    }
    __shared__ float ls[256], ls2[256];
    ls[threadIdx.x] = s; ls2[threadIdx.x] = s2;
    __syncthreads();
    if (lr == 0) {
        #pragma unroll
        for (int j = 1; j < R; ++j) { s += ls[j * D + c]; s2 += ls2[j * D + c]; }
        atomicAdd(&sums[c], s);
        atomicAdd(&sumsq[c], s2);
    }
}

// ---------------- launch ----------------------------------------------------
extern "C" void kernel_launch(void* const* d_in, const int* in_sizes, int n_in,
                              void* d_out, int out_size, void* d_ws, size_t ws_size,
                              hipStream_t stream)
{
    const float* x    = (const float*)d_in[0];
    const int*   ei2  = (const int*)d_in[1];
    const int*   ei0  = (const int*)d_in[4];
    const int*   ei1  = (const int*)d_in[5];
    const float* ew0  = (const float*)d_in[6];
    const float* ew1  = (const float*)d_in[7];
    const int*   perm0= (const int*)d_in[8];
    const int*   perm1= (const int*)d_in[9];
    const float* W1a  = (const float*)d_in[10];
    const float* b1a  = (const float*)d_in[11];
    const float* W1b  = (const float*)d_in[12];
    const float* b1b  = (const float*)d_in[13];
    const float* g1   = (const float*)d_in[14];
    const float* bt1  = (const float*)d_in[15];
    const float* W2a  = (const float*)d_in[16];
    const float* b2a  = (const float*)d_in[17];
    const float* W2b  = (const float*)d_in[18];
    const float* b2b  = (const float*)d_in[19];
    const float* g2   = (const float*)d_in[20];
    const float* bt2  = (const float*)d_in[21];
    const float* Wg0  = (const float*)d_in[22];
    const float* bg0  = (const float*)d_in[23];
    const float* Wg1  = (const float*)d_in[24];
    const float* bg1  = (const float*)d_in[25];
    float* out = (float*)d_out;

    float* ws  = (float*)d_ws;
    int*   wsi = (int*)d_ws;

    // ---- layout (float-element offsets), max ~19.2M floats = 77 MB ----
    int*   rp    = wsi;                     // 175104 -> pad 176000
    int*   re    = wsi + 176000;            // 175104 -> 352000
    float* dis   = ws  + 352000;            // 150000 (N1|N0) -> 502000
    float* disc1 = ws  + 502000;            // 25000 -> 527000
    float* disc0 = ws  + 527000;            // 50000 -> 577000
    int*   inv1  = wsi + 577000;            // 50000 -> 627000
    int*   inv0  = wsi + 627000;            // 100000 -> 727000
    float* s1    = ws  + 727000;            // 64
    float* q1    = ws  + 727064;
    float* s2    = ws  + 727128;            // 128
    float* q2    = ws  + 727256;            // -> 727384
    int*   bsum  = wsi + 727500;            // 300
    int*   G     = wsi + 728000;            // NB*NBLK = 292752 -> pad 1,021,000
    int2*  bedges= (int2*)(wsi + 1025000);  // 1.75M int2 -> 4,525,000
    int2*  csr   = (int2*)(wsi + 4525000);  // up to 1.75M int2 -> 8,025,000
    __half* xh   = (__half*)(wsi + 1025000);// N2*64 half (bedges dead) -> 1,825,000
    __half* t0h  = (__half*)(ws + 8025000); // N2*64 half -> 8,825,000
    __half* cmp1 = (__half*)(ws + 8025000); // N2*128 half -> 9,625,000 (t0h dead)
    __half* cmp0 = (__half*)(ws + 8025000); // N1*64 half (cmp1 dead)
    float* t0f   = ws  + 9700000;           // N2*64 f -> 11,300,000 (GIN1 gather out)
    float* t1    = ws  + 9700000;           // N2*64 f (reuses t0f slot after dead)
    float* BaF   = ws  + 11300000;          // N2*64 f (GIN1 mid; inside Ba slot)
    float* Ba    = ws  + 11300000;          // N2*128 f -> 14,500,000
    float* Bb    = ws  + 14500000;          // N2*128 f -> 17,700,000
    float* out1  = ws  + 11300000;          // N1*128 f over Ba+Bb (dead)
    int*   tcg   = wsi + 17700000;          // 1.5M -> 19,200,000

    const int* src2 = ei2, *dst2 = ei2 + EE2;
    const int* src1 = ei1, *dst1 = ei1 + EE1;
    const int* src0 = ei0, *dst0 = ei0 + EE0;

    const int NG = NB * NBLK;  // 292752

    // ---- prep ----
    hipMemsetAsync(s1, 0, 384 * 4, stream);
    hipMemsetAsync(inv1, 0xFF, (NN1 + NN0) * 4, stream);
    inv_kernel<<<cdiv(NN2 + NN1, 256), 256, 0, stream>>>(perm1, perm0, inv1, inv0);
    translate_kernel<<<cdiv(EE1 + EE0, 256), 256, 0, stream>>>(src1, src0, inv1, inv0, tcg);
    count_kernel<<<NBLK, 256, 0, stream>>>(dst2, dst1, dst0, G);
    scan_block_kernel<<<cdiv(NG, 1024), 256, 0, stream>>>(G, bsum, NG);
    scan_bsum_kernel<<<1, 512, 0, stream>>>(bsum, cdiv(NG, 1024));
    scan_add_kernel<<<cdiv(NG, 256), 256, 0, stream>>>(G, bsum, NG);
    place_kernel<<<NBLK, 256, 0, stream>>>(
        src2, dst2, dst1, ew1, dst0, ew0, tcg, G, bedges);
    bucket_build_kernel<<<NB, 256, 0, stream>>>(bedges, G, rp, re, csr, dis);
    disc_kernel<<<cdiv(NN2 + NN1, 256), 256, 0, stream>>>(perm1, perm0, dis, disc1, disc0);
    // bedges dead now -> xh into its slot
    tohalf_kernel<<<cdiv(NN2 * 16, 256), 256, 0, stream>>>(x, xh, NN2 * 16);

    // ---- GIN layer 1 ----
    gin_gather_kernel<false><<<cdiv(NN2, 4), 256, 0, stream>>>(
        xh, rp, re, csr, nullptr, nullptr, nullptr, nullptr, t0f, NN2);
    gemm_kernel<64, 64, 64, true, false, float><<<cdiv(NN2, 64), 256, 0, stream>>>(
        t0f, W1a, b1a, nullptr, nullptr, nullptr, nullptr, BaF, NN2);
    gemm_kernel<64, 64, 64, true, false, __half><<<cdiv(NN2, 64), 256, 0, stream>>>(
        BaF, W1b, b1b, nullptr, nullptr, nullptr, nullptr, t0h, NN2);
    bn_partial_kernel<64, __half><<<256, 256, 0, stream>>>(t0h, s1, q1, NN2);

    // ---- GIN layer 2 (BN1 folded into gather epilogue; fp16 table) ----
    gin_gather_kernel<true><<<cdiv(NN2, 4), 256, 0, stream>>>(
        t0h, rp, re, csr, s1, q1, g1, bt1, t1, NN2);
    gemm_kernel<64, 64, 128, true, false, float><<<cdiv(NN2, 64), 256, 0, stream>>>(
        t1, W2a, b2a, nullptr, nullptr, nullptr, nullptr, Ba, NN2);
    gemm_kernel<64, 128, 128, true, false, float><<<cdiv(NN2, 64), 256, 0, stream>>>(
        Ba, W2b, b2b, nullptr, nullptr, nullptr, nullptr, Bb, NN2);
    bn_partial_kernel<128, float><<<256, 256, 0, stream>>>(Bb, s2, q2, NN2);

    // ---- GCN level 1: cmp1 = BN2(Bb) @ Wg0 (compact fp16), gather -> out1 --
    gemm_kernel<64, 128, 128, false, true, __half><<<cdiv(NN2, 64), 256, 0, stream>>>(
        Bb, Wg0, nullptr, s2, q2, g2, bt2, cmp1, NN2);
    gcn_gather128_kernel<true><<<cdiv(NN1, 4), 256, 0, stream>>>(
        cmp1, inv1, rp + NN2, re + NN2, csr, disc1, dis, bg0, out1, NN1);

    // ---- GCN level 0: cmp0 = out1 @ Wg1 (compact fp16), gather -> d_out ----
    gemm_kernel<64, 128, 64, false, false, __half><<<cdiv(NN1, 64), 256, 0, stream>>>(
        out1, Wg1, nullptr, nullptr, nullptr, nullptr, nullptr, cmp0, NN1);
    gcn_gather64_kernel<false><<<cdiv(NN0, 4), 256, 0, stream>>>(
        cmp0, inv0, rp + NN2 + NN1, re + NN2 + NN1, csr, disc0, dis + NN1, bg1, out, NN0);
}

// Round 12
// 299.402 us; speedup vs baseline: 1.0938x; 1.0248x over previous
//
#include <hip/hip_runtime.h>
#include <hip/hip_fp16.h>
#include <type_traits>

#define NN2 25000
#define NN1 50000
#define NN0 100000
#define EE2 250000
#define EE1 500000
#define EE0 1000000
#define NTOTC 175000
#define ETOTC 1750000
#define NB 684            // ceil(175104/256) coarse buckets of 256 nodes (vg>>8)
#define CHUNK 4096        // edges per count/place block
#define NBLK 428          // ceil(ETOTC/CHUNK)
#define BN_EPS 1e-5f

static inline int cdiv(long a, long b) { return (int)((a + b - 1) / b); }

typedef _Float16 half8 __attribute__((ext_vector_type(8)));
typedef float f32x4 __attribute__((ext_vector_type(4)));

template <typename T>
__device__ inline float ldf(const T* p) {
    if constexpr (std::is_same<T, __half>::value) return __half2float(*p);
    else return *p;
}

// ------------- MFMA GEMM: out[r] = act(bn?(in[r,:K]) @ W[K,M] + bias) -------
// fp16 inputs, fp32 accumulate. BM=64 rows/block, 4 waves x 16 rows.
// A frag: row=lane&15, k=(lane>>4)*8+j ; B via W^T in LDS: col=lane&15, same k
// D frag: col=lane&15, row=(lane>>4)*4+reg   [verified layout]
template <int K, int M, bool RELU, bool BNIN, typename OT>
__global__ __launch_bounds__(256) void mfma_gemm_kernel(
    const __half* __restrict__ in, const float* __restrict__ W,
    const float* __restrict__ bias,
    const float* __restrict__ sums, const float* __restrict__ sumsq,
    const float* __restrict__ g, const float* __restrict__ bt,
    OT* __restrict__ out, int n)
{
    constexpr int BM = 64;
    constexpr int LDA = K + 8;   // halfs; keeps 16B alignment, spreads banks
    constexpr int NC = M / 16;
    __shared__ __align__(16) _Float16 Ah[BM * LDA];
    __shared__ __align__(16) _Float16 Wt[M * LDA];
    const int tid = threadIdx.x;
    const int r0 = blockIdx.x * BM;

    // stage W^T (global K x M row-major -> LDS M x K)
    for (int idx = tid; idx < K * M; idx += 256) {
        int k = idx / M, m = idx % M;            // coalesced global read
        Wt[m * LDA + k] = (_Float16)W[idx];
    }
    // stage A rows (fp16 -> optional BN affine -> fp16)
    for (int idx = tid; idx < BM * K; idx += 256) {
        int r = idx / K, k = idx % K;            // coalesced global read
        int gr = r0 + r;
        float v = (gr < n) ? __half2float(in[(long)gr * K + k]) : 0.f;
        if (BNIN) {
            float mu = sums[k] * (1.f / NN2);
            float rs = rsqrtf(sumsq[k] * (1.f / NN2) - mu * mu + BN_EPS);
            v = g[k] * rs * (v - mu) + bt[k];
        }
        Ah[r * LDA + k] = (_Float16)v;
    }
    __syncthreads();

    const int wid = tid >> 6, lane = tid & 63;
    const int rw = wid * 16;
    const int arow = rw + (lane & 15);
    const int koff = (lane >> 4) * 8;

    f32x4 acc[NC];
    #pragma unroll
    for (int c = 0; c < NC; ++c) acc[c] = f32x4{0.f, 0.f, 0.f, 0.f};

    #pragma unroll
    for (int k0 = 0; k0 < K; k0 += 32) {
        half8 a = *(const half8*)&Ah[arow * LDA + k0 + koff];
        #pragma unroll
        for (int c = 0; c < NC; ++c) {
            half8 b = *(const half8*)&Wt[(c * 16 + (lane & 15)) * LDA + k0 + koff];
            acc[c] = __builtin_amdgcn_mfma_f32_16x16x32_f16(a, b, acc[c], 0, 0, 0);
        }
    }

    const int drow = r0 + rw + 4 * (lane >> 4);
    #pragma unroll
    for (int c = 0; c < NC; ++c) {
        int col = c * 16 + (lane & 15);
        float bv = (bias != nullptr) ? bias[col] : 0.f;
        #pragma unroll
        for (int j = 0; j < 4; ++j) {
            int r = drow + j;
            if (r < n) {
                float v = acc[c][j] + bv;
                if (RELU) v = fmaxf(v, 0.f);
                if constexpr (std::is_same<OT, __half>::value)
                    out[(long)r * M + col] = __float2half(v);
                else
                    out[(long)r * M + col] = v;
            }
        }
    }
}

// ---------------- fp32 -> fp16 convert (4 elems/thread) ---------------------
__global__ void tohalf_kernel(const float* __restrict__ in, __half* __restrict__ out, int n4)
{
    int i = blockIdx.x * blockDim.x + threadIdx.x;
    if (i >= n4) return;
    float4 v = ((const float4*)in)[i];
    __half2 a = __floats2half2_rn(v.x, v.y);
    __half2 b = __floats2half2_rn(v.z, v.w);
    ((uint2*)out)[i] = make_uint2(*(unsigned*)&a, *(unsigned*)&b);
}

// ------- translate: random inv lookups at HIGH occupancy (grid-stride) ------
__global__ void translate_kernel(const int* __restrict__ src1, const int* __restrict__ src0,
                                 const int* __restrict__ inv1, const int* __restrict__ inv0,
                                 int* __restrict__ tcg)
{
    int e = blockIdx.x * blockDim.x + threadIdx.x;
    if (e < EE1) tcg[e] = inv1[src1[e]];
    else if (e < EE1 + EE0) tcg[e] = inv0[src0[e - EE1]];
}

// ---------------- phase A: per-(bucket,block) counts, LDS histogram ---------
__global__ __launch_bounds__(256) void count_kernel(
    const int* __restrict__ dst2, const int* __restrict__ dst1,
    const int* __restrict__ dst0, int* __restrict__ G)
{
    __shared__ int h[NB];
    int tid = threadIdx.x, blk = blockIdx.x;
    for (int i = tid; i < NB; i += 256) h[i] = 0;
    __syncthreads();
    int e0 = blk * CHUNK, e1 = min(e0 + CHUNK, ETOTC);
    for (int e = e0 + tid; e < e1; e += 256) {
        int vg;
        if (e < EE2) vg = dst2[e];
        else if (e < EE2 + EE1) vg = NN2 + dst1[e - EE2];
        else vg = NN2 + NN1 + dst0[e - EE2 - EE1];
        atomicAdd(&h[vg >> 8], 1);
    }
    __syncthreads();
    for (int i = tid; i < NB; i += 256) G[i * NBLK + blk] = h[i];
}

// in-place exclusive scan, 1024 items / block of 256 threads
__global__ __launch_bounds__(256) void scan_block_kernel(int* data, int* bsum, int n)
{
    __shared__ int sh[256];
    int tid = threadIdx.x;
    int base = blockIdx.x * 1024 + tid * 4;
    int v[4];
    #pragma unroll
    for (int i = 0; i < 4; ++i) v[i] = (base + i < n) ? data[base + i] : 0;
    int tot = v[0] + v[1] + v[2] + v[3];
    sh[tid] = tot;
    __syncthreads();
    for (int d = 1; d < 256; d <<= 1) {
        int add = (tid >= d) ? sh[tid - d] : 0;
        __syncthreads();
        sh[tid] += add;
        __syncthreads();
    }
    int run = sh[tid] - tot;
    #pragma unroll
    for (int i = 0; i < 4; ++i) {
        if (base + i < n) data[base + i] = run;
        run += v[i];
    }
    if (tid == 255) bsum[blockIdx.x] = sh[255];
}

__global__ __launch_bounds__(512) void scan_bsum_kernel(int* bsum, int nb)
{
    __shared__ int sh[512];
    int tid = threadIdx.x;
    int v = (tid < nb) ? bsum[tid] : 0;
    sh[tid] = v;
    __syncthreads();
    for (int d = 1; d < 512; d <<= 1) {
        int add = (tid >= d) ? sh[tid - d] : 0;
        __syncthreads();
        sh[tid] += add;
        __syncthreads();
    }
    if (tid < nb) bsum[tid] = sh[tid] - v;
}

__global__ void scan_add_kernel(int* data, const int* __restrict__ bsum, int n)
{
    int i = blockIdx.x * blockDim.x + threadIdx.x;
    if (i < n) data[i] += bsum[i >> 10];
}

// ------- phase C: place (streaming only); bedges = ((local<<16)|(c+1), ew) --
__global__ __launch_bounds__(256) void place_kernel(
    const int* __restrict__ src2, const int* __restrict__ dst2,
    const int* __restrict__ dst1, const float* __restrict__ ew1,
    const int* __restrict__ dst0, const float* __restrict__ ew0,
    const int* __restrict__ tcg,
    const int* __restrict__ G, int2* __restrict__ bedges)
{
    __shared__ int cur[NB];
    int tid = threadIdx.x, blk = blockIdx.x;
    for (int i = tid; i < NB; i += 256) cur[i] = G[i * NBLK + blk];
    __syncthreads();
    int e0 = blk * CHUNK, e1 = min(e0 + CHUNK, ETOTC);
    for (int e = e0 + tid; e < e1; e += 256) {
        int vg, c, ewb;
        if (e < EE2) {
            vg = dst2[e]; c = src2[e]; ewb = 0;
        } else if (e < EE2 + EE1) {
            int i = e - EE2;
            vg = NN2 + dst1[i]; c = tcg[i]; ewb = __float_as_int(ew1[i]);
        } else {
            int i = e - EE2 - EE1;
            vg = NN2 + NN1 + dst0[i]; c = tcg[EE1 + i]; ewb = __float_as_int(ew0[i]);
        }
        int b = vg >> 8, local = vg & 255;
        int pos = atomicAdd(&cur[b], 1);   // LDS atomic only
        bedges[pos] = make_int2((local << 16) | (c + 1), ewb);
    }
}

// ------- phase D: per-bucket (256 nodes) live-only CSR + rp/re + dis --------
__global__ __launch_bounds__(256) void bucket_build_kernel(
    const int2* __restrict__ bedges, const int* __restrict__ G,
    int* __restrict__ rp, int* __restrict__ re,
    int2* __restrict__ csr, float* __restrict__ dis)
{
    __shared__ int cnt[256];
    __shared__ float wdeg[256];
    __shared__ int excl[256];
    __shared__ int tsum[256];
    int b = blockIdx.x, tid = threadIdx.x;
    int s0 = G[b * NBLK];
    int s1 = (b == NB - 1) ? ETOTC : G[(b + 1) * NBLK];
    cnt[tid] = 0; wdeg[tid] = 0.f;
    __syncthreads();
    for (int i = s0 + tid; i < s1; i += 256) {
        int2 t = bedges[i];
        int local = t.x >> 16;
        atomicAdd(&wdeg[local], __int_as_float(t.y));   // all edges -> deg
        if (t.x & 0xFFFF) atomicAdd(&cnt[local], 1);    // live only
    }
    __syncthreads();
    int v = cnt[tid];
    tsum[tid] = v;
    __syncthreads();
    for (int d = 1; d < 256; d <<= 1) {
        int add = (tid >= d) ? tsum[tid - d] : 0;
        __syncthreads();
        tsum[tid] += add;
        __syncthreads();
    }
    excl[tid] = tsum[tid] - v;
    {
        int vg = (b << 8) + tid;
        if (vg < NTOTC) {
            int r0_ = s0 + excl[tid];
            rp[vg] = r0_;
            re[vg] = r0_ + v;
            if (vg >= NN2) dis[vg - NN2] = rsqrtf(wdeg[tid] + 2.0f);
        }
    }
    cnt[tid] = 0;
    __syncthreads();
    for (int i = s0 + tid; i < s1; i += 256) {
        int2 t = bedges[i];
        int cx = t.x & 0xFFFF;
        if (cx) {
            int local = t.x >> 16;
            int pos = s0 + excl[local] + atomicAdd(&cnt[local], 1);
            csr[pos] = make_int2(cx - 1, t.y);
        }
    }
}

// ---------------- inverse perms ---------------------------------------------
__global__ void inv_kernel(const int* __restrict__ perm1, const int* __restrict__ perm0,
                           int* __restrict__ inv1, int* __restrict__ inv0)
{
    int i = blockIdx.x * blockDim.x + threadIdx.x;
    if (i < NN2) inv1[perm1[i]] = i;
    else if (i < NN2 + NN1) inv0[perm0[i - NN2]] = i - NN2;
}

// ---------------- compact-indexed dis tables --------------------------------
__global__ void disc_kernel(const int* __restrict__ perm1, const int* __restrict__ perm0,
                            const float* __restrict__ dis,
                            float* __restrict__ disc1, float* __restrict__ disc0)
{
    int i = blockIdx.x * blockDim.x + threadIdx.x;
    if (i < NN2) disc1[i] = dis[perm1[i]];
    else if (i < NN2 + NN1) disc0[i - NN2] = dis[NN1 + perm0[i - NN2]];
}

// ---------------- GIN gather: wave per node, D=64, fp16 in/out, 4x unroll ---
template <bool BN>
__global__ __launch_bounds__(256) void gin_gather_kernel(
    const __half* __restrict__ x, const int* __restrict__ rp, const int* __restrict__ re,
    const int2* __restrict__ csr,
    const float* __restrict__ sums, const float* __restrict__ sumsq,
    const float* __restrict__ g, const float* __restrict__ bt,
    __half* __restrict__ out, int n)
{
    int v = (blockIdx.x * 256 + threadIdx.x) >> 6;
    int lane = threadIdx.x & 63;
    if (v >= n) return;
    int p0 = rp[v], pe = re[v];
    float a0 = __half2float(x[(long)v * 64 + lane]);
    float a1 = 0.f, a2 = 0.f, a3 = 0.f;
    for (int base = p0; base < pe; base += 64) {
        int idx = base + lane;
        int s_l = 0; float m_l = 0.f;
        if (idx < pe) { s_l = csr[idx].x; m_l = 1.f; }
        int cnt = min(64, pe - base);
        for (int j = 0; j < cnt; j += 4) {
            int s0 = __shfl(s_l, j),     s1 = __shfl(s_l, j + 1);
            int s2 = __shfl(s_l, j + 2), s3 = __shfl(s_l, j + 3);
            float m0 = __shfl(m_l, j),     m1 = __shfl(m_l, j + 1);
            float m2 = __shfl(m_l, j + 2), m3 = __shfl(m_l, j + 3);
            a0 = fmaf(m0, __half2float(x[(long)s0 * 64 + lane]), a0);
            a1 = fmaf(m1, __half2float(x[(long)s1 * 64 + lane]), a1);
            a2 = fmaf(m2, __half2float(x[(long)s2 * 64 + lane]), a2);
            a3 = fmaf(m3, __half2float(x[(long)s3 * 64 + lane]), a3);
        }
    }
    float acc = (a0 + a1) + (a2 + a3);
    if (BN) {
        int deg = pe - p0;
        float mu = sums[lane] * (1.f / NN2);
        float rs = rsqrtf(sumsq[lane] * (1.f / NN2) - mu * mu + BN_EPS);
        float a = g[lane] * rs;
        acc = a * acc + (float)(deg + 1) * (bt[lane] - a * mu);
    }
    out[(long)v * 64 + lane] = __float2half(acc);
}

// ---------------- GCN gather: live-only CSR, compact idx, 4x unroll ---------
template <bool RELU>
__global__ __launch_bounds__(256) void gcn_gather128_kernel(
    const __half* __restrict__ cmp, const int* __restrict__ inv,
    const int* __restrict__ rp, const int* __restrict__ re,
    const int2* __restrict__ csr, const float* __restrict__ disc,
    const float* __restrict__ dis, const float* __restrict__ bias,
    __half* __restrict__ out, int n)
{
    int v = (blockIdx.x * 256 + threadIdx.x) >> 6;
    int lane = threadIdx.x & 63;
    if (v >= n) return;
    int p0 = rp[v], pe = re[v];
    float ax0 = 0.f, ay0 = 0.f, ax1 = 0.f, ay1 = 0.f;
    float ax2 = 0.f, ay2 = 0.f, ax3 = 0.f, ay3 = 0.f;
    for (int base = p0; base < pe; base += 64) {
        int idx = base + lane;
        int cs_l = 0; float w_l = 0.f;
        if (idx < pe) {
            int2 sl = csr[idx];
            cs_l = sl.x;
            w_l = __int_as_float(sl.y) * disc[sl.x];
        }
        int cnt = min(64, pe - base);
        for (int j = 0; j < cnt; j += 4) {
            int c0 = __shfl(cs_l, j),     c1 = __shfl(cs_l, j + 1);
            int c2 = __shfl(cs_l, j + 2), c3 = __shfl(cs_l, j + 3);
            float w0 = __shfl(w_l, j),     w1 = __shfl(w_l, j + 1);
            float w2 = __shfl(w_l, j + 2), w3 = __shfl(w_l, j + 3);
            float2 h0 = __half22float2(*(const __half2*)(cmp + (long)c0 * 128 + lane * 2));
            float2 h1 = __half22float2(*(const __half2*)(cmp + (long)c1 * 128 + lane * 2));
            float2 h2 = __half22float2(*(const __half2*)(cmp + (long)c2 * 128 + lane * 2));
            float2 h3 = __half22float2(*(const __half2*)(cmp + (long)c3 * 128 + lane * 2));
            ax0 = fmaf(w0, h0.x, ax0); ay0 = fmaf(w0, h0.y, ay0);
            ax1 = fmaf(w1, h1.x, ax1); ay1 = fmaf(w1, h1.y, ay1);
            ax2 = fmaf(w2, h2.x, ax2); ay2 = fmaf(w2, h2.y, ay2);
            ax3 = fmaf(w3, h3.x, ax3); ay3 = fmaf(w3, h3.y, ay3);
        }
    }
    float ax = (ax0 + ax1) + (ax2 + ax3);
    float ay = (ay0 + ay1) + (ay2 + ay3);
    float dv = dis[v];
    int cv = inv[v];
    float sx = 0.f, sy = 0.f;
    if (cv >= 0) {
        float2 hv = __half22float2(*(const __half2*)(cmp + (long)cv * 128 + lane * 2));
        sx = hv.x; sy = hv.y;
    }
    float s2 = 2.f * dv * dv;
    float o0 = fmaf(dv, ax, fmaf(s2, sx, bias[lane * 2]));
    float o1 = fmaf(dv, ay, fmaf(s2, sy, bias[lane * 2 + 1]));
    if (RELU) { o0 = fmaxf(o0, 0.f); o1 = fmaxf(o1, 0.f); }
    *(__half2*)(out + (long)v * 128 + lane * 2) = __floats2half2_rn(o0, o1);
}

template <bool RELU>
__global__ __launch_bounds__(256) void gcn_gather64_kernel(
    const __half* __restrict__ cmp, const int* __restrict__ inv,
    const int* __restrict__ rp, const int* __restrict__ re,
    const int2* __restrict__ csr, const float* __restrict__ disc,
    const float* __restrict__ dis, const float* __restrict__ bias,
    float* __restrict__ out, int n)
{
    int v = (blockIdx.x * 256 + threadIdx.x) >> 6;
    int lane = threadIdx.x & 63;
    if (v >= n) return;
    int p0 = rp[v], pe = re[v];
    float a0 = 0.f, a1 = 0.f, a2 = 0.f, a3 = 0.f;
    for (int base = p0; base < pe; base += 64) {
        int idx = base + lane;
        int cs_l = 0; float w_l = 0.f;
        if (idx < pe) {
            int2 sl = csr[idx];
            cs_l = sl.x;
            w_l = __int_as_float(sl.y) * disc[sl.x];
        }
        int cnt = min(64, pe - base);
        for (int j = 0; j < cnt; j += 4) {
            int c0 = __shfl(cs_l, j),     c1 = __shfl(cs_l, j + 1);
            int c2 = __shfl(cs_l, j + 2), c3 = __shfl(cs_l, j + 3);
            float w0 = __shfl(w_l, j),     w1 = __shfl(w_l, j + 1);
            float w2 = __shfl(w_l, j + 2), w3 = __shfl(w_l, j + 3);
            float h0 = __half2float(cmp[(long)c0 * 64 + lane]);
            float h1 = __half2float(cmp[(long)c1 * 64 + lane]);
            float h2 = __half2float(cmp[(long)c2 * 64 + lane]);
            float h3 = __half2float(cmp[(long)c3 * 64 + lane]);
            a0 = fmaf(w0, h0, a0);
            a1 = fmaf(w1, h1, a1);
            a2 = fmaf(w2, h2, a2);
            a3 = fmaf(w3, h3, a3);
        }
    }
    float acc = (a0 + a1) + (a2 + a3);
    float dv = dis[v];
    int cv = inv[v];
    float sv = (cv >= 0) ? __half2float(cmp[(long)cv * 64 + lane]) : 0.f;
    float o = fmaf(dv, acc, fmaf(2.f * dv * dv, sv, bias[lane]));
    if (RELU) o = fmaxf(o, 0.f);
    out[(long)v * 64 + lane] = o;
}

// ---------------- BatchNorm stats -------------------------------------------
template <int D, typename IT>
__global__ __launch_bounds__(256) void bn_partial_kernel(
    const IT* __restrict__ h, float* __restrict__ sums,
    float* __restrict__ sumsq, int n)
{
    constexpr int R = 256 / D;
    const int c = threadIdx.x % D, lr = threadIdx.x / D;
    float s = 0.f, s2 = 0.f;
    for (int r = blockIdx.x * R + lr; r < n; r += gridDim.x * R) {
        float v = ldf(&h[(long)r * D + c]);
        s += v; s2 += v * v;
    }
    __shared__ float ls[256], ls2[256];
    ls[threadIdx.x] = s; ls2[threadIdx.x] = s2;
    __syncthreads();
    if (lr == 0) {
        #pragma unroll
        for (int j = 1; j < R; ++j) { s += ls[j * D + c]; s2 += ls2[j * D + c]; }
        atomicAdd(&sums[c], s);
        atomicAdd(&sumsq[c], s2);
    }
}

// ---------------- launch ----------------------------------------------------
extern "C" void kernel_launch(void* const* d_in, const int* in_sizes, int n_in,
                              void* d_out, int out_size, void* d_ws, size_t ws_size,
                              hipStream_t stream)
{
    const float* x    = (const float*)d_in[0];
    const int*   ei2  = (const int*)d_in[1];
    const int*   ei0  = (const int*)d_in[4];
    const int*   ei1  = (const int*)d_in[5];
    const float* ew0  = (const float*)d_in[6];
    const float* ew1  = (const float*)d_in[7];
    const int*   perm0= (const int*)d_in[8];
    const int*   perm1= (const int*)d_in[9];
    const float* W1a  = (const float*)d_in[10];
    const float* b1a  = (const float*)d_in[11];
    const float* W1b  = (const float*)d_in[12];
    const float* b1b  = (const float*)d_in[13];
    const float* g1   = (const float*)d_in[14];
    const float* bt1  = (const float*)d_in[15];
    const float* W2a  = (const float*)d_in[16];
    const float* b2a  = (const float*)d_in[17];
    const float* W2b  = (const float*)d_in[18];
    const float* b2b  = (const float*)d_in[19];
    const float* g2   = (const float*)d_in[20];
    const float* bt2  = (const float*)d_in[21];
    const float* Wg0  = (const float*)d_in[22];
    const float* bg0  = (const float*)d_in[23];
    const float* Wg1  = (const float*)d_in[24];
    const float* bg1  = (const float*)d_in[25];
    float* out = (float*)d_out;

    float* ws  = (float*)d_ws;
    int*   wsi = (int*)d_ws;

    // ---- layout (float-element offsets), total 22,325,000 f = 89.3 MB ----
    int*   rp    = wsi;                     // 175104 -> pad 176000
    int*   re    = wsi + 176000;            // -> 352000
    float* dis   = ws  + 352000;            // 150000 -> 502000
    float* disc1 = ws  + 502000;            // -> 527000
    float* disc0 = ws  + 527000;            // -> 577000
    int*   inv1  = wsi + 577000;            // -> 627000
    int*   inv0  = wsi + 627000;            // -> 727000
    float* s1    = ws  + 727000;            // 64
    float* q1    = ws  + 727064;
    float* s2    = ws  + 727128;            // 128
    float* q2    = ws  + 727256;            // -> 727384
    int*   bsum  = wsi + 727500;            // 300
    int*   G     = wsi + 728000;            // 292752 -> pad 1,025,000
    int2*  bedges= (int2*)(wsi + 1025000);  // 1.75M int2 -> 4,525,000
    int2*  csr   = (int2*)(wsi + 4525000);  // -> 8,025,000
    __half* xh   = (__half*)(wsi + 1025000);// aliases bedges (dead) -> 1,825,000
    __half* t0f  = (__half*)(ws + 8025000); // N2*64 h -> 8,825,000
    __half* BaF  = (__half*)(ws + 8825000); // N2*64 h -> 9,625,000
    __half* t0h  = (__half*)(ws + 9625000); // N2*64 h -> 10,425,000
    __half* t1   = (__half*)(ws + 10425000);// N2*64 h -> 11,225,000
    __half* Ba   = (__half*)(ws + 11225000);// N2*128 h -> 12,825,000
    __half* Bb   = (__half*)(ws + 12825000);// N2*128 h -> 14,425,000
    __half* cmp1 = (__half*)(ws + 14425000);// N2*128 h -> 16,025,000
    __half* out1 = (__half*)(ws + 16025000);// N1*128 h -> 19,225,000
    __half* cmp0 = (__half*)(ws + 19225000);// N1*64 h -> 20,825,000
    int*   tcg   = wsi + 20825000;          // 1.5M -> 22,325,000

    const int* src2 = ei2, *dst2 = ei2 + EE2;
    const int* src1 = ei1, *dst1 = ei1 + EE1;
    const int* src0 = ei0, *dst0 = ei0 + EE0;

    const int NG = NB * NBLK;  // 292752

    // ---- prep ----
    hipMemsetAsync(s1, 0, 384 * 4, stream);
    hipMemsetAsync(inv1, 0xFF, (NN1 + NN0) * 4, stream);
    inv_kernel<<<cdiv(NN2 + NN1, 256), 256, 0, stream>>>(perm1, perm0, inv1, inv0);
    translate_kernel<<<cdiv(EE1 + EE0, 256), 256, 0, stream>>>(src1, src0, inv1, inv0, tcg);
    count_kernel<<<NBLK, 256, 0, stream>>>(dst2, dst1, dst0, G);
    scan_block_kernel<<<cdiv(NG, 1024), 256, 0, stream>>>(G, bsum, NG);
    scan_bsum_kernel<<<1, 512, 0, stream>>>(bsum, cdiv(NG, 1024));
    scan_add_kernel<<<cdiv(NG, 256), 256, 0, stream>>>(G, bsum, NG);
    place_kernel<<<NBLK, 256, 0, stream>>>(
        src2, dst2, dst1, ew1, dst0, ew0, tcg, G, bedges);
    bucket_build_kernel<<<NB, 256, 0, stream>>>(bedges, G, rp, re, csr, dis);
    disc_kernel<<<cdiv(NN2 + NN1, 256), 256, 0, stream>>>(perm1, perm0, dis, disc1, disc0);
    // bedges dead now -> xh into its slot
    tohalf_kernel<<<cdiv(NN2 * 16, 256), 256, 0, stream>>>(x, xh, NN2 * 16);

    // ---- GIN layer 1 ----
    gin_gather_kernel<false><<<cdiv(NN2, 4), 256, 0, stream>>>(
        xh, rp, re, csr, nullptr, nullptr, nullptr, nullptr, t0f, NN2);
    mfma_gemm_kernel<64, 64, true, false, __half><<<cdiv(NN2, 64), 256, 0, stream>>>(
        t0f, W1a, b1a, nullptr, nullptr, nullptr, nullptr, BaF, NN2);
    mfma_gemm_kernel<64, 64, true, false, __half><<<cdiv(NN2, 64), 256, 0, stream>>>(
        BaF, W1b, b1b, nullptr, nullptr, nullptr, nullptr, t0h, NN2);
    bn_partial_kernel<64, __half><<<256, 256, 0, stream>>>(t0h, s1, q1, NN2);

    // ---- GIN layer 2 (BN1 folded into gather epilogue) ----
    gin_gather_kernel<true><<<cdiv(NN2, 4), 256, 0, stream>>>(
        t0h, rp, re, csr, s1, q1, g1, bt1, t1, NN2);
    mfma_gemm_kernel<64, 128, true, false, __half><<<cdiv(NN2, 64), 256, 0, stream>>>(
        t1, W2a, b2a, nullptr, nullptr, nullptr, nullptr, Ba, NN2);
    mfma_gemm_kernel<128, 128, true, false, __half><<<cdiv(NN2, 64), 256, 0, stream>>>(
        Ba, W2b, b2b, nullptr, nullptr, nullptr, nullptr, Bb, NN2);
    bn_partial_kernel<128, __half><<<256, 256, 0, stream>>>(Bb, s2, q2, NN2);

    // ---- GCN level 1: cmp1 = BN2(Bb) @ Wg0 (fp16 MFMA), gather -> out1 -----
    mfma_gemm_kernel<128, 128, false, true, __half><<<cdiv(NN2, 64), 256, 0, stream>>>(
        Bb, Wg0, nullptr, s2, q2, g2, bt2, cmp1, NN2);
    gcn_gather128_kernel<true><<<cdiv(NN1, 4), 256, 0, stream>>>(
        cmp1, inv1, rp + NN2, re + NN2, csr, disc1, dis, bg0, out1, NN1);

    // ---- GCN level 0: cmp0 = out1 @ Wg1 (fp16 MFMA), gather -> d_out -------
    mfma_gemm_kernel<128, 64, false, false, __half><<<cdiv(NN1, 64), 256, 0, stream>>>(
        out1, Wg1, nullptr, nullptr, nullptr, nullptr, nullptr, cmp0, NN1);
    gcn_gather64_kernel<false><<<cdiv(NN0, 4), 256, 0, stream>>>(
        cmp0, inv0, rp + NN2 + NN1, re + NN2 + NN1, csr, disc0, dis + NN1, bg1, out, NN0);
}

// Round 13
// 265.557 us; speedup vs baseline: 1.2332x; 1.1274x over previous
//
#include <hip/hip_runtime.h>
#include <hip/hip_fp16.h>
#include <type_traits>

#define NN2 25000
#define NN1 50000
#define NN0 100000
#define EE2 250000
#define EE1 500000
#define EE0 1000000
#define NTOTC 175000
#define ETOTC 1750000
#define NB 684            // ceil(175104/256) coarse buckets of 256 nodes (vg>>8)
#define CHUNK 4096        // edges per count/place block
#define NBLK 428          // ceil(ETOTC/CHUNK)
#define BN_EPS 1e-5f

static inline int cdiv(long a, long b) { return (int)((a + b - 1) / b); }

typedef _Float16 half8 __attribute__((ext_vector_type(8)));
typedef float f32x4 __attribute__((ext_vector_type(4)));

// ------------- MFMA GEMM: out[r] = act(bn?(in[r,:K]) @ W[K,M] + bias) -------
// fp16 in, fp32 accum. BM=64 rows/block, 4 waves x 16 rows.
// BNOUT: fold BatchNorm statistics (sum, sumsq of post-act output) via LDS
// reduce + one global atomic per column per block.
template <int K, int M, bool RELU, bool BNIN, bool BNOUT, typename OT>
__global__ __launch_bounds__(256) void mfma_gemm_kernel(
    const __half* __restrict__ in, const float* __restrict__ W,
    const float* __restrict__ bias,
    const float* __restrict__ sums, const float* __restrict__ sumsq,
    const float* __restrict__ g, const float* __restrict__ bt,
    float* __restrict__ osum, float* __restrict__ osq,
    OT* __restrict__ out, int n)
{
    constexpr int BM = 64;
    constexpr int LDA = K + 8;
    constexpr int NC = M / 16;
    __shared__ __align__(16) _Float16 Ah[BM * LDA];
    __shared__ __align__(16) _Float16 Wt[M * LDA];
    const int tid = threadIdx.x;
    const int r0 = blockIdx.x * BM;

    for (int idx = tid; idx < K * M; idx += 256) {
        int k = idx / M, m = idx % M;
        Wt[m * LDA + k] = (_Float16)W[idx];
    }
    for (int idx = tid; idx < BM * K; idx += 256) {
        int r = idx / K, k = idx % K;
        int gr = r0 + r;
        float v = (gr < n) ? __half2float(in[(long)gr * K + k]) : 0.f;
        if (BNIN) {
            float mu = sums[k] * (1.f / NN2);
            float rs = rsqrtf(sumsq[k] * (1.f / NN2) - mu * mu + BN_EPS);
            v = g[k] * rs * (v - mu) + bt[k];
        }
        Ah[r * LDA + k] = (_Float16)v;
    }
    __syncthreads();

    const int wid = tid >> 6, lane = tid & 63;
    const int rw = wid * 16;
    const int arow = rw + (lane & 15);
    const int koff = (lane >> 4) * 8;

    f32x4 acc[NC];
    #pragma unroll
    for (int c = 0; c < NC; ++c) acc[c] = f32x4{0.f, 0.f, 0.f, 0.f};

    #pragma unroll
    for (int k0 = 0; k0 < K; k0 += 32) {
        half8 a = *(const half8*)&Ah[arow * LDA + k0 + koff];
        #pragma unroll
        for (int c = 0; c < NC; ++c) {
            half8 b = *(const half8*)&Wt[(c * 16 + (lane & 15)) * LDA + k0 + koff];
            acc[c] = __builtin_amdgcn_mfma_f32_16x16x32_f16(a, b, acc[c], 0, 0, 0);
        }
    }

    float* bs = (float*)Ah;   // LDS reuse for BNOUT (2*M floats <= Ah size)
    if (BNOUT) {
        __syncthreads();
        if (tid < 2 * M) bs[tid] = 0.f;
        __syncthreads();
    }

    const int drow = r0 + rw + 4 * (lane >> 4);
    #pragma unroll
    for (int c = 0; c < NC; ++c) {
        int col = c * 16 + (lane & 15);
        float bv = (bias != nullptr) ? bias[col] : 0.f;
        float sc = 0.f, qc = 0.f;
        #pragma unroll
        for (int j = 0; j < 4; ++j) {
            int r = drow + j;
            if (r < n) {
                float v = acc[c][j] + bv;
                if (RELU) v = fmaxf(v, 0.f);
                if constexpr (std::is_same<OT, __half>::value)
                    out[(long)r * M + col] = __float2half(v);
                else
                    out[(long)r * M + col] = v;
                if (BNOUT) { sc += v; qc += v * v; }
            }
        }
        if (BNOUT) {
            atomicAdd(&bs[col], sc);
            atomicAdd(&bs[M + col], qc);
        }
    }
    if (BNOUT) {
        __syncthreads();
        if (tid < M) {
            atomicAdd(&osum[tid], bs[tid]);
            atomicAdd(&osq[tid], bs[M + tid]);
        }
    }
}

// ---------------- fp32 -> fp16 convert (4 elems/thread) ---------------------
__global__ void tohalf_kernel(const float* __restrict__ in, __half* __restrict__ out, int n4)
{
    int i = blockIdx.x * blockDim.x + threadIdx.x;
    if (i >= n4) return;
    float4 v = ((const float4*)in)[i];
    __half2 a = __floats2half2_rn(v.x, v.y);
    __half2 b = __floats2half2_rn(v.z, v.w);
    ((uint2*)out)[i] = make_uint2(*(unsigned*)&a, *(unsigned*)&b);
}

// ------- translate: random inv lookups at HIGH occupancy (grid-stride) ------
__global__ void translate_kernel(const int* __restrict__ src1, const int* __restrict__ src0,
                                 const int* __restrict__ inv1, const int* __restrict__ inv0,
                                 int* __restrict__ tcg)
{
    int e = blockIdx.x * blockDim.x + threadIdx.x;
    if (e < EE1) tcg[e] = inv1[src1[e]];
    else if (e < EE1 + EE0) tcg[e] = inv0[src0[e - EE1]];
}

// ---------------- phase A: per-(bucket,block) counts, LDS histogram ---------
__global__ __launch_bounds__(256) void count_kernel(
    const int* __restrict__ dst2, const int* __restrict__ dst1,
    const int* __restrict__ dst0, int* __restrict__ G)
{
    __shared__ int h[NB];
    int tid = threadIdx.x, blk = blockIdx.x;
    for (int i = tid; i < NB; i += 256) h[i] = 0;
    __syncthreads();
    int e0 = blk * CHUNK, e1 = min(e0 + CHUNK, ETOTC);
    for (int e = e0 + tid; e < e1; e += 256) {
        int vg;
        if (e < EE2) vg = dst2[e];
        else if (e < EE2 + EE1) vg = NN2 + dst1[e - EE2];
        else vg = NN2 + NN1 + dst0[e - EE2 - EE1];
        atomicAdd(&h[vg >> 8], 1);
    }
    __syncthreads();
    for (int i = tid; i < NB; i += 256) G[i * NBLK + blk] = h[i];
}

// in-place exclusive scan, 1024 items / block of 256 threads
__global__ __launch_bounds__(256) void scan_block_kernel(int* data, int* bsum, int n)
{
    __shared__ int sh[256];
    int tid = threadIdx.x;
    int base = blockIdx.x * 1024 + tid * 4;
    int v[4];
    #pragma unroll
    for (int i = 0; i < 4; ++i) v[i] = (base + i < n) ? data[base + i] : 0;
    int tot = v[0] + v[1] + v[2] + v[3];
    sh[tid] = tot;
    __syncthreads();
    for (int d = 1; d < 256; d <<= 1) {
        int add = (tid >= d) ? sh[tid - d] : 0;
        __syncthreads();
        sh[tid] += add;
        __syncthreads();
    }
    int run = sh[tid] - tot;
    #pragma unroll
    for (int i = 0; i < 4; ++i) {
        if (base + i < n) data[base + i] = run;
        run += v[i];
    }
    if (tid == 255) bsum[blockIdx.x] = sh[255];
}

__global__ __launch_bounds__(512) void scan_bsum_kernel(int* bsum, int nb)
{
    __shared__ int sh[512];
    int tid = threadIdx.x;
    int v = (tid < nb) ? bsum[tid] : 0;
    sh[tid] = v;
    __syncthreads();
    for (int d = 1; d < 512; d <<= 1) {
        int add = (tid >= d) ? sh[tid - d] : 0;
        __syncthreads();
        sh[tid] += add;
        __syncthreads();
    }
    if (tid < nb) bsum[tid] = sh[tid] - v;
}

__global__ void scan_add_kernel(int* data, const int* __restrict__ bsum, int n)
{
    int i = blockIdx.x * blockDim.x + threadIdx.x;
    if (i < n) data[i] += bsum[i >> 10];
}

// ------- phase C: place (streaming only); bedges = ((local<<16)|(c+1), ew) --
__global__ __launch_bounds__(256) void place_kernel(
    const int* __restrict__ src2, const int* __restrict__ dst2,
    const int* __restrict__ dst1, const float* __restrict__ ew1,
    const int* __restrict__ dst0, const float* __restrict__ ew0,
    const int* __restrict__ tcg,
    const int* __restrict__ G, int2* __restrict__ bedges)
{
    __shared__ int cur[NB];
    int tid = threadIdx.x, blk = blockIdx.x;
    for (int i = tid; i < NB; i += 256) cur[i] = G[i * NBLK + blk];
    __syncthreads();
    int e0 = blk * CHUNK, e1 = min(e0 + CHUNK, ETOTC);
    for (int e = e0 + tid; e < e1; e += 256) {
        int vg, c, ewb;
        if (e < EE2) {
            vg = dst2[e]; c = src2[e]; ewb = 0;
        } else if (e < EE2 + EE1) {
            int i = e - EE2;
            vg = NN2 + dst1[i]; c = tcg[i]; ewb = __float_as_int(ew1[i]);
        } else {
            int i = e - EE2 - EE1;
            vg = NN2 + NN1 + dst0[i]; c = tcg[EE1 + i]; ewb = __float_as_int(ew0[i]);
        }
        int b = vg >> 8, local = vg & 255;
        int pos = atomicAdd(&cur[b], 1);   // LDS atomic only
        bedges[pos] = make_int2((local << 16) | (c + 1), ewb);
    }
}

// ------- phase D: per-bucket (256 nodes) live-only CSR + rp/re + dis --------
__global__ __launch_bounds__(256) void bucket_build_kernel(
    const int2* __restrict__ bedges, const int* __restrict__ G,
    int* __restrict__ rp, int* __restrict__ re,
    int2* __restrict__ csr, float* __restrict__ dis)
{
    __shared__ int cnt[256];
    __shared__ float wdeg[256];
    __shared__ int excl[256];
    __shared__ int tsum[256];
    int b = blockIdx.x, tid = threadIdx.x;
    int s0 = G[b * NBLK];
    int s1 = (b == NB - 1) ? ETOTC : G[(b + 1) * NBLK];
    cnt[tid] = 0; wdeg[tid] = 0.f;
    __syncthreads();
    for (int i = s0 + tid; i < s1; i += 256) {
        int2 t = bedges[i];
        int local = t.x >> 16;
        atomicAdd(&wdeg[local], __int_as_float(t.y));   // all edges -> deg
        if (t.x & 0xFFFF) atomicAdd(&cnt[local], 1);    // live only
    }
    __syncthreads();
    int v = cnt[tid];
    tsum[tid] = v;
    __syncthreads();
    for (int d = 1; d < 256; d <<= 1) {
        int add = (tid >= d) ? tsum[tid - d] : 0;
        __syncthreads();
        tsum[tid] += add;
        __syncthreads();
    }
    excl[tid] = tsum[tid] - v;
    {
        int vg = (b << 8) + tid;
        if (vg < NTOTC) {
            int r0_ = s0 + excl[tid];
            rp[vg] = r0_;
            re[vg] = r0_ + v;
            if (vg >= NN2) dis[vg - NN2] = rsqrtf(wdeg[tid] + 2.0f);
        }
    }
    cnt[tid] = 0;
    __syncthreads();
    for (int i = s0 + tid; i < s1; i += 256) {
        int2 t = bedges[i];
        int cx = t.x & 0xFFFF;
        if (cx) {
            int local = t.x >> 16;
            int pos = s0 + excl[local] + atomicAdd(&cnt[local], 1);
            csr[pos] = make_int2(cx - 1, t.y);
        }
    }
}

// ---------------- inverse perms ---------------------------------------------
__global__ void inv_kernel(const int* __restrict__ perm1, const int* __restrict__ perm0,
                           int* __restrict__ inv1, int* __restrict__ inv0)
{
    int i = blockIdx.x * blockDim.x + threadIdx.x;
    if (i < NN2) inv1[perm1[i]] = i;
    else if (i < NN2 + NN1) inv0[perm0[i - NN2]] = i - NN2;
}

// ---------------- compact-indexed dis tables --------------------------------
__global__ void disc_kernel(const int* __restrict__ perm1, const int* __restrict__ perm0,
                            const float* __restrict__ dis,
                            float* __restrict__ disc1, float* __restrict__ disc0)
{
    int i = blockIdx.x * blockDim.x + threadIdx.x;
    if (i < NN2) disc1[i] = dis[perm1[i]];
    else if (i < NN2 + NN1) disc0[i - NN2] = dis[NN1 + perm0[i - NN2]];
}

// --------- GIN gather: 32-lane group per node (2 nodes/wave), fp16 ----------
template <bool BN>
__global__ __launch_bounds__(256) void gin_gather_kernel(
    const __half* __restrict__ x, const int* __restrict__ rp, const int* __restrict__ re,
    const int2* __restrict__ csr,
    const float* __restrict__ sums, const float* __restrict__ sumsq,
    const float* __restrict__ g, const float* __restrict__ bt,
    __half* __restrict__ out, int n)
{
    int v = (blockIdx.x * 256 + threadIdx.x) >> 5;
    int lane = threadIdx.x & 31;
    if (v >= n) return;
    int p0 = rp[v], pe = re[v];
    float2 sv = __half22float2(*(const __half2*)(x + (long)v * 64 + lane * 2));
    float ax0 = sv.x, ay0 = sv.y;
    float ax1 = 0.f, ay1 = 0.f, ax2 = 0.f, ay2 = 0.f, ax3 = 0.f, ay3 = 0.f;
    for (int base = p0; base < pe; base += 32) {
        int idx = base + lane;
        int s_l = 0; float m_l = 0.f;
        if (idx < pe) { s_l = csr[idx].x; m_l = 1.f; }
        int cnt = min(32, pe - base);
        for (int j = 0; j < cnt; j += 4) {
            int s0 = __shfl(s_l, j, 32),     s1 = __shfl(s_l, j + 1, 32);
            int s2 = __shfl(s_l, j + 2, 32), s3 = __shfl(s_l, j + 3, 32);
            float m0 = __shfl(m_l, j, 32),     m1 = __shfl(m_l, j + 1, 32);
            float m2 = __shfl(m_l, j + 2, 32), m3 = __shfl(m_l, j + 3, 32);
            float2 h0 = __half22float2(*(const __half2*)(x + (long)s0 * 64 + lane * 2));
            float2 h1 = __half22float2(*(const __half2*)(x + (long)s1 * 64 + lane * 2));
            float2 h2 = __half22float2(*(const __half2*)(x + (long)s2 * 64 + lane * 2));
            float2 h3 = __half22float2(*(const __half2*)(x + (long)s3 * 64 + lane * 2));
            ax0 = fmaf(m0, h0.x, ax0); ay0 = fmaf(m0, h0.y, ay0);
            ax1 = fmaf(m1, h1.x, ax1); ay1 = fmaf(m1, h1.y, ay1);
            ax2 = fmaf(m2, h2.x, ax2); ay2 = fmaf(m2, h2.y, ay2);
            ax3 = fmaf(m3, h3.x, ax3); ay3 = fmaf(m3, h3.y, ay3);
        }
    }
    float accx = (ax0 + ax1) + (ax2 + ax3);
    float accy = (ay0 + ay1) + (ay2 + ay3);
    if (BN) {
        int deg = pe - p0;
        int c0 = lane * 2, c1 = lane * 2 + 1;
        float mu0 = sums[c0] * (1.f / NN2), mu1 = sums[c1] * (1.f / NN2);
        float rs0 = rsqrtf(sumsq[c0] * (1.f / NN2) - mu0 * mu0 + BN_EPS);
        float rs1 = rsqrtf(sumsq[c1] * (1.f / NN2) - mu1 * mu1 + BN_EPS);
        float a0 = g[c0] * rs0, a1 = g[c1] * rs1;
        accx = a0 * accx + (float)(deg + 1) * (bt[c0] - a0 * mu0);
        accy = a1 * accy + (float)(deg + 1) * (bt[c1] - a1 * mu1);
    }
    *(__half2*)(out + (long)v * 64 + lane * 2) = __floats2half2_rn(accx, accy);
}

// ------ GCN gather 128ch: 32-lane group per node, 4 ch/lane, live CSR -------
template <bool RELU>
__global__ __launch_bounds__(256) void gcn_gather128_kernel(
    const __half* __restrict__ cmp, const int* __restrict__ inv,
    const int* __restrict__ rp, const int* __restrict__ re,
    const int2* __restrict__ csr, const float* __restrict__ disc,
    const float* __restrict__ dis, const float* __restrict__ bias,
    __half* __restrict__ out, int n)
{
    int v = (blockIdx.x * 256 + threadIdx.x) >> 5;
    int lane = threadIdx.x & 31;
    if (v >= n) return;
    int p0 = rp[v], pe = re[v];
    f32x4 a0 = {0,0,0,0}, a1 = {0,0,0,0}, a2 = {0,0,0,0}, a3 = {0,0,0,0};
    for (int base = p0; base < pe; base += 32) {
        int idx = base + lane;
        int cs_l = 0; float w_l = 0.f;
        if (idx < pe) {
            int2 sl = csr[idx];
            cs_l = sl.x;
            w_l = __int_as_float(sl.y) * disc[sl.x];
        }
        int cnt = min(32, pe - base);
        for (int j = 0; j < cnt; j += 4) {
            int c0 = __shfl(cs_l, j, 32),     c1 = __shfl(cs_l, j + 1, 32);
            int c2 = __shfl(cs_l, j + 2, 32), c3 = __shfl(cs_l, j + 3, 32);
            float w0 = __shfl(w_l, j, 32),     w1 = __shfl(w_l, j + 1, 32);
            float w2 = __shfl(w_l, j + 2, 32), w3 = __shfl(w_l, j + 3, 32);
            uint2 u0 = *(const uint2*)(cmp + (long)c0 * 128 + lane * 4);
            uint2 u1 = *(const uint2*)(cmp + (long)c1 * 128 + lane * 4);
            uint2 u2 = *(const uint2*)(cmp + (long)c2 * 128 + lane * 4);
            uint2 u3 = *(const uint2*)(cmp + (long)c3 * 128 + lane * 4);
            float2 p0a = __half22float2(*(__half2*)&u0.x), p0b = __half22float2(*(__half2*)&u0.y);
            float2 p1a = __half22float2(*(__half2*)&u1.x), p1b = __half22float2(*(__half2*)&u1.y);
            float2 p2a = __half22float2(*(__half2*)&u2.x), p2b = __half22float2(*(__half2*)&u2.y);
            float2 p3a = __half22float2(*(__half2*)&u3.x), p3b = __half22float2(*(__half2*)&u3.y);
            a0[0] = fmaf(w0, p0a.x, a0[0]); a0[1] = fmaf(w0, p0a.y, a0[1]);
            a0[2] = fmaf(w0, p0b.x, a0[2]); a0[3] = fmaf(w0, p0b.y, a0[3]);
            a1[0] = fmaf(w1, p1a.x, a1[0]); a1[1] = fmaf(w1, p1a.y, a1[1]);
            a1[2] = fmaf(w1, p1b.x, a1[2]); a1[3] = fmaf(w1, p1b.y, a1[3]);
            a2[0] = fmaf(w2, p2a.x, a2[0]); a2[1] = fmaf(w2, p2a.y, a2[1]);
            a2[2] = fmaf(w2, p2b.x, a2[2]); a2[3] = fmaf(w2, p2b.y, a2[3]);
            a3[0] = fmaf(w3, p3a.x, a3[0]); a3[1] = fmaf(w3, p3a.y, a3[1]);
            a3[2] = fmaf(w3, p3b.x, a3[2]); a3[3] = fmaf(w3, p3b.y, a3[3]);
        }
    }
    float dv = dis[v];
    int cv = inv[v];
    float sx0 = 0.f, sx1 = 0.f, sx2 = 0.f, sx3 = 0.f;
    if (cv >= 0) {
        uint2 u = *(const uint2*)(cmp + (long)cv * 128 + lane * 4);
        float2 pa = __half22float2(*(__half2*)&u.x), pb = __half22float2(*(__half2*)&u.y);
        sx0 = pa.x; sx1 = pa.y; sx2 = pb.x; sx3 = pb.y;
    }
    float s2 = 2.f * dv * dv;
    float o0 = fmaf(dv, (a0[0] + a1[0]) + (a2[0] + a3[0]), fmaf(s2, sx0, bias[lane * 4]));
    float o1 = fmaf(dv, (a0[1] + a1[1]) + (a2[1] + a3[1]), fmaf(s2, sx1, bias[lane * 4 + 1]));
    float o2 = fmaf(dv, (a0[2] + a1[2]) + (a2[2] + a3[2]), fmaf(s2, sx2, bias[lane * 4 + 2]));
    float o3 = fmaf(dv, (a0[3] + a1[3]) + (a2[3] + a3[3]), fmaf(s2, sx3, bias[lane * 4 + 3]));
    if (RELU) {
        o0 = fmaxf(o0, 0.f); o1 = fmaxf(o1, 0.f);
        o2 = fmaxf(o2, 0.f); o3 = fmaxf(o3, 0.f);
    }
    __half2 ha = __floats2half2_rn(o0, o1), hb = __floats2half2_rn(o2, o3);
    *(uint2*)(out + (long)v * 128 + lane * 4) = make_uint2(*(unsigned*)&ha, *(unsigned*)&hb);
}

// ------ GCN gather 64ch: 32-lane group per node, 2 ch/lane, live CSR --------
template <bool RELU>
__global__ __launch_bounds__(256) void gcn_gather64_kernel(
    const __half* __restrict__ cmp, const int* __restrict__ inv,
    const int* __restrict__ rp, const int* __restrict__ re,
    const int2* __restrict__ csr, const float* __restrict__ disc,
    const float* __restrict__ dis, const float* __restrict__ bias,
    float* __restrict__ out, int n)
{
    int v = (blockIdx.x * 256 + threadIdx.x) >> 5;
    int lane = threadIdx.x & 31;
    if (v >= n) return;
    int p0 = rp[v], pe = re[v];
    float ax0 = 0.f, ay0 = 0.f, ax1 = 0.f, ay1 = 0.f;
    float ax2 = 0.f, ay2 = 0.f, ax3 = 0.f, ay3 = 0.f;
    for (int base = p0; base < pe; base += 32) {
        int idx = base + lane;
        int cs_l = 0; float w_l = 0.f;
        if (idx < pe) {
            int2 sl = csr[idx];
            cs_l = sl.x;
            w_l = __int_as_float(sl.y) * disc[sl.x];
        }
        int cnt = min(32, pe - base);
        for (int j = 0; j < cnt; j += 4) {
            int c0 = __shfl(cs_l, j, 32),     c1 = __shfl(cs_l, j + 1, 32);
            int c2 = __shfl(cs_l, j + 2, 32), c3 = __shfl(cs_l, j + 3, 32);
            float w0 = __shfl(w_l, j, 32),     w1 = __shfl(w_l, j + 1, 32);
            float w2 = __shfl(w_l, j + 2, 32), w3 = __shfl(w_l, j + 3, 32);
            float2 h0 = __half22float2(*(const __half2*)(cmp + (long)c0 * 64 + lane * 2));
            float2 h1 = __half22float2(*(const __half2*)(cmp + (long)c1 * 64 + lane * 2));
            float2 h2 = __half22float2(*(const __half2*)(cmp + (long)c2 * 64 + lane * 2));
            float2 h3 = __half22float2(*(const __half2*)(cmp + (long)c3 * 64 + lane * 2));
            ax0 = fmaf(w0, h0.x, ax0); ay0 = fmaf(w0, h0.y, ay0);
            ax1 = fmaf(w1, h1.x, ax1); ay1 = fmaf(w1, h1.y, ay1);
            ax2 = fmaf(w2, h2.x, ax2); ay2 = fmaf(w2, h2.y, ay2);
            ax3 = fmaf(w3, h3.x, ax3); ay3 = fmaf(w3, h3.y, ay3);
        }
    }
    float ax = (ax0 + ax1) + (ax2 + ax3);
    float ay = (ay0 + ay1) + (ay2 + ay3);
    float dv = dis[v];
    int cv = inv[v];
    float sx = 0.f, sy = 0.f;
    if (cv >= 0) {
        float2 hv = __half22float2(*(const __half2*)(cmp + (long)cv * 64 + lane * 2));
        sx = hv.x; sy = hv.y;
    }
    float s2 = 2.f * dv * dv;
    float o0 = fmaf(dv, ax, fmaf(s2, sx, bias[lane * 2]));
    float o1 = fmaf(dv, ay, fmaf(s2, sy, bias[lane * 2 + 1]));
    if (RELU) { o0 = fmaxf(o0, 0.f); o1 = fmaxf(o1, 0.f); }
    *(float2*)(out + (long)v * 64 + lane * 2) = make_float2(o0, o1);
}

// ---------------- launch ----------------------------------------------------
extern "C" void kernel_launch(void* const* d_in, const int* in_sizes, int n_in,
                              void* d_out, int out_size, void* d_ws, size_t ws_size,
                              hipStream_t stream)
{
    const float* x    = (const float*)d_in[0];
    const int*   ei2  = (const int*)d_in[1];
    const int*   ei0  = (const int*)d_in[4];
    const int*   ei1  = (const int*)d_in[5];
    const float* ew0  = (const float*)d_in[6];
    const float* ew1  = (const float*)d_in[7];
    const int*   perm0= (const int*)d_in[8];
    const int*   perm1= (const int*)d_in[9];
    const float* W1a  = (const float*)d_in[10];
    const float* b1a  = (const float*)d_in[11];
    const float* W1b  = (const float*)d_in[12];
    const float* b1b  = (const float*)d_in[13];
    const float* g1   = (const float*)d_in[14];
    const float* bt1  = (const float*)d_in[15];
    const float* W2a  = (const float*)d_in[16];
    const float* b2a  = (const float*)d_in[17];
    const float* W2b  = (const float*)d_in[18];
    const float* b2b  = (const float*)d_in[19];
    const float* g2   = (const float*)d_in[20];
    const float* bt2  = (const float*)d_in[21];
    const float* Wg0  = (const float*)d_in[22];
    const float* bg0  = (const float*)d_in[23];
    const float* Wg1  = (const float*)d_in[24];
    const float* bg1  = (const float*)d_in[25];
    float* out = (float*)d_out;

    float* ws  = (float*)d_ws;
    int*   wsi = (int*)d_ws;

    // ---- layout (float-element offsets), total 22,325,000 f = 89.3 MB ----
    int*   rp    = wsi;                     // 175104 -> pad 176000
    int*   re    = wsi + 176000;            // -> 352000
    float* dis   = ws  + 352000;            // 150000 -> 502000
    float* disc1 = ws  + 502000;            // -> 527000
    float* disc0 = ws  + 527000;            // -> 577000
    int*   inv1  = wsi + 577000;            // -> 627000
    int*   inv0  = wsi + 627000;            // -> 727000
    float* s1    = ws  + 727000;            // 64
    float* q1    = ws  + 727064;
    float* s2    = ws  + 727128;            // 128
    float* q2    = ws  + 727256;            // -> 727384
    int*   bsum  = wsi + 727500;            // 300
    int*   G     = wsi + 728000;            // 292752 -> pad 1,025,000
    int2*  bedges= (int2*)(wsi + 1025000);  // 1.75M int2 -> 4,525,000
    int2*  csr   = (int2*)(wsi + 4525000);  // -> 8,025,000
    __half* xh   = (__half*)(wsi + 1025000);// aliases bedges (dead) -> 1,825,000
    __half* t0f  = (__half*)(ws + 8025000); // N2*64 h -> 8,825,000
    __half* BaF  = (__half*)(ws + 8825000); // N2*64 h -> 9,625,000
    __half* t0h  = (__half*)(ws + 9625000); // N2*64 h -> 10,425,000
    __half* t1   = (__half*)(ws + 10425000);// N2*64 h -> 11,225,000
    __half* Ba   = (__half*)(ws + 11225000);// N2*128 h -> 12,825,000
    __half* Bb   = (__half*)(ws + 12825000);// N2*128 h -> 14,425,000
    __half* cmp1 = (__half*)(ws + 14425000);// N2*128 h -> 16,025,000
    __half* out1 = (__half*)(ws + 16025000);// N1*128 h -> 19,225,000
    __half* cmp0 = (__half*)(ws + 19225000);// N1*64 h -> 20,825,000
    int*   tcg   = wsi + 20825000;          // 1.5M -> 22,325,000

    const int* src2 = ei2, *dst2 = ei2 + EE2;
    const int* src1 = ei1, *dst1 = ei1 + EE1;
    const int* src0 = ei0, *dst0 = ei0 + EE0;

    const int NG = NB * NBLK;  // 292752

    // ---- prep ----
    hipMemsetAsync(s1, 0, 384 * 4, stream);
    hipMemsetAsync(inv1, 0xFF, (NN1 + NN0) * 4, stream);
    inv_kernel<<<cdiv(NN2 + NN1, 256), 256, 0, stream>>>(perm1, perm0, inv1, inv0);
    translate_kernel<<<cdiv(EE1 + EE0, 256), 256, 0, stream>>>(src1, src0, inv1, inv0, tcg);
    count_kernel<<<NBLK, 256, 0, stream>>>(dst2, dst1, dst0, G);
    scan_block_kernel<<<cdiv(NG, 1024), 256, 0, stream>>>(G, bsum, NG);
    scan_bsum_kernel<<<1, 512, 0, stream>>>(bsum, cdiv(NG, 1024));
    scan_add_kernel<<<cdiv(NG, 256), 256, 0, stream>>>(G, bsum, NG);
    place_kernel<<<NBLK, 256, 0, stream>>>(
        src2, dst2, dst1, ew1, dst0, ew0, tcg, G, bedges);
    bucket_build_kernel<<<NB, 256, 0, stream>>>(bedges, G, rp, re, csr, dis);
    disc_kernel<<<cdiv(NN2 + NN1, 256), 256, 0, stream>>>(perm1, perm0, dis, disc1, disc0);
    // bedges dead now -> xh into its slot
    tohalf_kernel<<<cdiv(NN2 * 16, 256), 256, 0, stream>>>(x, xh, NN2 * 16);

    // ---- GIN layer 1 ----
    gin_gather_kernel<false><<<cdiv((long)NN2 * 32, 256), 256, 0, stream>>>(
        xh, rp, re, csr, nullptr, nullptr, nullptr, nullptr, t0f, NN2);
    mfma_gemm_kernel<64, 64, true, false, false, __half><<<cdiv(NN2, 64), 256, 0, stream>>>(
        t0f, W1a, b1a, nullptr, nullptr, nullptr, nullptr, nullptr, nullptr, BaF, NN2);
    mfma_gemm_kernel<64, 64, true, false, true, __half><<<cdiv(NN2, 64), 256, 0, stream>>>(
        BaF, W1b, b1b, nullptr, nullptr, nullptr, nullptr, s1, q1, t0h, NN2);

    // ---- GIN layer 2 (BN1 folded into gather epilogue) ----
    gin_gather_kernel<true><<<cdiv((long)NN2 * 32, 256), 256, 0, stream>>>(
        t0h, rp, re, csr, s1, q1, g1, bt1, t1, NN2);
    mfma_gemm_kernel<64, 128, true, false, false, __half><<<cdiv(NN2, 64), 256, 0, stream>>>(
        t1, W2a, b2a, nullptr, nullptr, nullptr, nullptr, nullptr, nullptr, Ba, NN2);
    mfma_gemm_kernel<128, 128, true, false, true, __half><<<cdiv(NN2, 64), 256, 0, stream>>>(
        Ba, W2b, b2b, nullptr, nullptr, nullptr, nullptr, s2, q2, Bb, NN2);

    // ---- GCN level 1: cmp1 = BN2(Bb) @ Wg0 (fp16 MFMA), gather -> out1 -----
    mfma_gemm_kernel<128, 128, false, true, false, __half><<<cdiv(NN2, 64), 256, 0, stream>>>(
        Bb, Wg0, nullptr, s2, q2, g2, bt2, nullptr, nullptr, cmp1, NN2);
    gcn_gather128_kernel<true><<<cdiv((long)NN1 * 32, 256), 256, 0, stream>>>(
        cmp1, inv1, rp + NN2, re + NN2, csr, disc1, dis, bg0, out1, NN1);

    // ---- GCN level 0: cmp0 = out1 @ Wg1 (fp16 MFMA), gather -> d_out -------
    mfma_gemm_kernel<128, 64, false, false, false, __half><<<cdiv(NN1, 64), 256, 0, stream>>>(
        out1, Wg1, nullptr, nullptr, nullptr, nullptr, nullptr, nullptr, nullptr, cmp0, NN1);
    gcn_gather64_kernel<false><<<cdiv((long)NN0 * 32, 256), 256, 0, stream>>>(
        cmp0, inv0, rp + NN2 + NN1, re + NN2 + NN1, csr, disc0, dis + NN1, bg1, out, NN0);
}

// Round 14
// 237.054 us; speedup vs baseline: 1.3815x; 1.1202x over previous
//
#include <hip/hip_runtime.h>
#include <hip/hip_fp16.h>
#include <type_traits>

#define NN2 25000
#define NN1 50000
#define NN0 100000
#define EE2 250000
#define EE1 500000
#define EE0 1000000
#define NTOTC 175000
#define ETOTC 1750000
#define NB 684            // ceil(175104/256) buckets of 256 nodes (vg>>8)
#define CHUNK 2048        // edges per count/place block
#define NBLK 855          // ceil(ETOTC/CHUNK)
#define BN_EPS 1e-5f

static inline int cdiv(long a, long b) { return (int)((a + b - 1) / b); }

typedef _Float16 half8 __attribute__((ext_vector_type(8)));
typedef float f32x4 __attribute__((ext_vector_type(4)));

// ------------- single MFMA GEMM: out = act(bn?(in) @ W + bias) --------------
template <int K, int M, bool RELU, bool BNIN, bool BNOUT, typename OT>
__global__ __launch_bounds__(256) void mfma_gemm_kernel(
    const __half* __restrict__ in, const float* __restrict__ W,
    const float* __restrict__ bias,
    const float* __restrict__ sums, const float* __restrict__ sumsq,
    const float* __restrict__ g, const float* __restrict__ bt,
    float* __restrict__ osum, float* __restrict__ osq,
    OT* __restrict__ out, int n)
{
    constexpr int BM = 64;
    constexpr int LDA = K + 8;
    constexpr int NC = M / 16;
    __shared__ __align__(16) _Float16 Ah[BM * LDA];
    __shared__ __align__(16) _Float16 Wt[M * LDA];
    const int tid = threadIdx.x;
    const int r0 = blockIdx.x * BM;

    for (int idx = tid; idx < K * M; idx += 256) {
        int k = idx / M, m = idx % M;
        Wt[m * LDA + k] = (_Float16)W[idx];
    }
    for (int idx = tid; idx < BM * K; idx += 256) {
        int r = idx / K, k = idx % K;
        int gr = r0 + r;
        float v = (gr < n) ? __half2float(in[(long)gr * K + k]) : 0.f;
        if (BNIN) {
            float mu = sums[k] * (1.f / NN2);
            float rs = rsqrtf(sumsq[k] * (1.f / NN2) - mu * mu + BN_EPS);
            v = g[k] * rs * (v - mu) + bt[k];
        }
        Ah[r * LDA + k] = (_Float16)v;
    }
    __syncthreads();

    const int wid = tid >> 6, lane = tid & 63;
    const int rw = wid * 16;
    const int arow = rw + (lane & 15);
    const int koff = (lane >> 4) * 8;

    f32x4 acc[NC];
    #pragma unroll
    for (int c = 0; c < NC; ++c) acc[c] = f32x4{0.f, 0.f, 0.f, 0.f};
    #pragma unroll
    for (int k0 = 0; k0 < K; k0 += 32) {
        half8 a = *(const half8*)&Ah[arow * LDA + k0 + koff];
        #pragma unroll
        for (int c = 0; c < NC; ++c) {
            half8 b = *(const half8*)&Wt[(c * 16 + (lane & 15)) * LDA + k0 + koff];
            acc[c] = __builtin_amdgcn_mfma_f32_16x16x32_f16(a, b, acc[c], 0, 0, 0);
        }
    }

    float* bs = (float*)Ah;
    if (BNOUT) {
        __syncthreads();
        if (tid < 2 * M) bs[tid] = 0.f;
        __syncthreads();
    }
    const int drow = r0 + rw + 4 * (lane >> 4);
    #pragma unroll
    for (int c = 0; c < NC; ++c) {
        int col = c * 16 + (lane & 15);
        float bv = (bias != nullptr) ? bias[col] : 0.f;
        float sc = 0.f, qc = 0.f;
        #pragma unroll
        for (int j = 0; j < 4; ++j) {
            int r = drow + j;
            if (r < n) {
                float v = acc[c][j] + bv;
                if (RELU) v = fmaxf(v, 0.f);
                if constexpr (std::is_same<OT, __half>::value)
                    out[(long)r * M + col] = __float2half(v);
                else
                    out[(long)r * M + col] = v;
                if (BNOUT) { sc += v; qc += v * v; }
            }
        }
        if (BNOUT) { atomicAdd(&bs[col], sc); atomicAdd(&bs[M + col], qc); }
    }
    if (BNOUT) {
        __syncthreads();
        if (tid < M) { atomicAdd(&osum[tid], bs[tid]); atomicAdd(&osq[tid], bs[M + tid]); }
    }
}

// ------------- fused MLP: out = relu(relu(in@W1+b1)@W2+b2), opt BNOUT -------
template <int K, int M1, int M2, bool BNOUT>
__global__ __launch_bounds__(256) void mlp_gemm_kernel(
    const __half* __restrict__ in,
    const float* __restrict__ W1, const float* __restrict__ b1,
    const float* __restrict__ W2, const float* __restrict__ b2,
    float* __restrict__ osum, float* __restrict__ osq,
    __half* __restrict__ out, int n)
{
    constexpr int BM = 64;
    constexpr int LDA = K + 8;
    constexpr int LDM = M1 + 8;
    constexpr int NC1 = M1 / 16, NC2 = M2 / 16;
    __shared__ __align__(16) _Float16 Ah[BM * LDA];
    __shared__ __align__(16) _Float16 Wt1[M1 * LDA];
    __shared__ __align__(16) _Float16 Wt2[M2 * LDM];
    __shared__ __align__(16) _Float16 mid[BM * LDM];
    const int tid = threadIdx.x;
    const int r0 = blockIdx.x * BM;

    for (int idx = tid; idx < K * M1; idx += 256) {
        int k = idx / M1, m = idx % M1;
        Wt1[m * LDA + k] = (_Float16)W1[idx];
    }
    for (int idx = tid; idx < M1 * M2; idx += 256) {
        int k = idx / M2, m = idx % M2;
        Wt2[m * LDM + k] = (_Float16)W2[idx];
    }
    for (int idx = tid; idx < BM * K; idx += 256) {
        int r = idx / K, k = idx % K;
        int gr = r0 + r;
        Ah[r * LDA + k] = (gr < n) ? (_Float16)in[(long)gr * K + k] : (_Float16)0.f;
    }
    __syncthreads();

    const int wid = tid >> 6, lane = tid & 63;
    const int rw = wid * 16;
    const int arow = rw + (lane & 15);
    const int koff = (lane >> 4) * 8;

    // ---- stage 1 ----
    f32x4 acc1[NC1];
    #pragma unroll
    for (int c = 0; c < NC1; ++c) acc1[c] = f32x4{0.f, 0.f, 0.f, 0.f};
    #pragma unroll
    for (int k0 = 0; k0 < K; k0 += 32) {
        half8 a = *(const half8*)&Ah[arow * LDA + k0 + koff];
        #pragma unroll
        for (int c = 0; c < NC1; ++c) {
            half8 b = *(const half8*)&Wt1[(c * 16 + (lane & 15)) * LDA + k0 + koff];
            acc1[c] = __builtin_amdgcn_mfma_f32_16x16x32_f16(a, b, acc1[c], 0, 0, 0);
        }
    }
    // write mid = relu(acc1 + b1) as fp16
    {
        int rd0 = rw + 4 * (lane >> 4);
        #pragma unroll
        for (int c = 0; c < NC1; ++c) {
            int col = c * 16 + (lane & 15);
            float bv = b1[col];
            #pragma unroll
            for (int j = 0; j < 4; ++j)
                mid[(rd0 + j) * LDM + col] = (_Float16)fmaxf(acc1[c][j] + bv, 0.f);
        }
    }
    float* bs = (float*)Ah;   // Ah dead after stage-1 fragment reads
    if (BNOUT) {
        if (tid < 2 * M2) bs[tid] = 0.f;
    }
    __syncthreads();

    // ---- stage 2 ----
    f32x4 acc2[NC2];
    #pragma unroll
    for (int c = 0; c < NC2; ++c) acc2[c] = f32x4{0.f, 0.f, 0.f, 0.f};
    #pragma unroll
    for (int k0 = 0; k0 < M1; k0 += 32) {
        half8 a = *(const half8*)&mid[arow * LDM + k0 + koff];
        #pragma unroll
        for (int c = 0; c < NC2; ++c) {
            half8 b = *(const half8*)&Wt2[(c * 16 + (lane & 15)) * LDM + k0 + koff];
            acc2[c] = __builtin_amdgcn_mfma_f32_16x16x32_f16(a, b, acc2[c], 0, 0, 0);
        }
    }
    const int drow = r0 + rw + 4 * (lane >> 4);
    #pragma unroll
    for (int c = 0; c < NC2; ++c) {
        int col = c * 16 + (lane & 15);
        float bv = b2[col];
        float sc = 0.f, qc = 0.f;
        #pragma unroll
        for (int j = 0; j < 4; ++j) {
            int r = drow + j;
            if (r < n) {
                float v = fmaxf(acc2[c][j] + bv, 0.f);
                out[(long)r * M2 + col] = __float2half(v);
                if (BNOUT) { sc += v; qc += v * v; }
            }
        }
        if (BNOUT) { atomicAdd(&bs[col], sc); atomicAdd(&bs[M2 + col], qc); }
    }
    if (BNOUT) {
        __syncthreads();
        if (tid < M2) { atomicAdd(&osum[tid], bs[tid]); atomicAdd(&osq[tid], bs[M2 + tid]); }
    }
}

// ---------------- fp32 -> fp16 convert ---------------------------------------
__global__ void tohalf_kernel(const float* __restrict__ in, __half* __restrict__ out, int n4)
{
    int i = blockIdx.x * blockDim.x + threadIdx.x;
    if (i >= n4) return;
    float4 v = ((const float4*)in)[i];
    __half2 a = __floats2half2_rn(v.x, v.y);
    __half2 b = __floats2half2_rn(v.z, v.w);
    ((uint2*)out)[i] = make_uint2(*(unsigned*)&a, *(unsigned*)&b);
}

// ------- fused count (LDS hist of dst buckets) + translate (inv lookup) -----
__global__ __launch_bounds__(256) void count_translate_kernel(
    const int* __restrict__ dst2,
    const int* __restrict__ src1, const int* __restrict__ dst1,
    const int* __restrict__ src0, const int* __restrict__ dst0,
    const int* __restrict__ inv1, const int* __restrict__ inv0,
    int* __restrict__ tcg, int* __restrict__ G)
{
    __shared__ int h[NB];
    int tid = threadIdx.x, blk = blockIdx.x;
    for (int i = tid; i < NB; i += 256) h[i] = 0;
    __syncthreads();
    int e0 = blk * CHUNK, e1 = min(e0 + CHUNK, ETOTC);
    for (int e = e0 + tid; e < e1; e += 256) {
        int vg;
        if (e < EE2) {
            vg = dst2[e];
        } else if (e < EE2 + EE1) {
            int i = e - EE2;
            vg = NN2 + dst1[i];
            tcg[i] = inv1[src1[i]];
        } else {
            int i = e - EE2 - EE1;
            vg = NN2 + NN1 + dst0[i];
            tcg[EE1 + i] = inv0[src0[i]];
        }
        atomicAdd(&h[vg >> 8], 1);
    }
    __syncthreads();
    for (int i = tid; i < NB; i += 256) G[i * NBLK + blk] = h[i];
}

// in-place exclusive scan, 1024 items / block of 256 threads
__global__ __launch_bounds__(256) void scan_block_kernel(int* data, int* bsum, int n)
{
    __shared__ int sh[256];
    int tid = threadIdx.x;
    int base = blockIdx.x * 1024 + tid * 4;
    int v[4];
    #pragma unroll
    for (int i = 0; i < 4; ++i) v[i] = (base + i < n) ? data[base + i] : 0;
    int tot = v[0] + v[1] + v[2] + v[3];
    sh[tid] = tot;
    __syncthreads();
    for (int d = 1; d < 256; d <<= 1) {
        int add = (tid >= d) ? sh[tid - d] : 0;
        __syncthreads();
        sh[tid] += add;
        __syncthreads();
    }
    int run = sh[tid] - tot;
    #pragma unroll
    for (int i = 0; i < 4; ++i) {
        if (base + i < n) data[base + i] = run;
        run += v[i];
    }
    if (tid == 255) bsum[blockIdx.x] = sh[255];
}

__global__ __launch_bounds__(1024) void scan_bsum_kernel(int* bsum, int nb)
{
    __shared__ int sh[1024];
    int tid = threadIdx.x;
    int v = (tid < nb) ? bsum[tid] : 0;
    sh[tid] = v;
    __syncthreads();
    for (int d = 1; d < 1024; d <<= 1) {
        int add = (tid >= d) ? sh[tid - d] : 0;
        __syncthreads();
        sh[tid] += add;
        __syncthreads();
    }
    if (tid < nb) bsum[tid] = sh[tid] - v;
}

// ------- place (streaming; bsum folded); bedges = ((local<<16)|(c+1), ew) ---
__global__ __launch_bounds__(256) void place_kernel(
    const int* __restrict__ src2, const int* __restrict__ dst2,
    const int* __restrict__ dst1, const float* __restrict__ ew1,
    const int* __restrict__ dst0, const float* __restrict__ ew0,
    const int* __restrict__ tcg,
    const int* __restrict__ G, const int* __restrict__ bsum,
    int2* __restrict__ bedges)
{
    __shared__ int cur[NB];
    int tid = threadIdx.x, blk = blockIdx.x;
    for (int i = tid; i < NB; i += 256) {
        int idx = i * NBLK + blk;
        cur[i] = G[idx] + bsum[idx >> 10];
    }
    __syncthreads();
    int e0 = blk * CHUNK, e1 = min(e0 + CHUNK, ETOTC);
    for (int e = e0 + tid; e < e1; e += 256) {
        int vg, c, ewb;
        if (e < EE2) {
            vg = dst2[e]; c = src2[e]; ewb = 0;
        } else if (e < EE2 + EE1) {
            int i = e - EE2;
            vg = NN2 + dst1[i]; c = tcg[i]; ewb = __float_as_int(ew1[i]);
        } else {
            int i = e - EE2 - EE1;
            vg = NN2 + NN1 + dst0[i]; c = tcg[EE1 + i]; ewb = __float_as_int(ew0[i]);
        }
        int b = vg >> 8, local = vg & 255;
        int pos = atomicAdd(&cur[b], 1);
        bedges[pos] = make_int2((local << 16) | (c + 1), ewb);
    }
}

// ------- per-bucket (256 nodes) live-only CSR + rp/re + dis (bsum folded) ---
__global__ __launch_bounds__(256) void bucket_build_kernel(
    const int2* __restrict__ bedges, const int* __restrict__ G,
    const int* __restrict__ bsum,
    int* __restrict__ rp, int* __restrict__ re,
    int2* __restrict__ csr, float* __restrict__ dis)
{
    __shared__ int cnt[256];
    __shared__ float wdeg[256];
    __shared__ int excl[256];
    __shared__ int tsum[256];
    int b = blockIdx.x, tid = threadIdx.x;
    int i0 = b * NBLK;
    int s0 = G[i0] + bsum[i0 >> 10];
    int s1;
    if (b == NB - 1) s1 = ETOTC;
    else { int i1 = (b + 1) * NBLK; s1 = G[i1] + bsum[i1 >> 10]; }
    cnt[tid] = 0; wdeg[tid] = 0.f;
    __syncthreads();
    for (int i = s0 + tid; i < s1; i += 256) {
        int2 t = bedges[i];
        int local = t.x >> 16;
        atomicAdd(&wdeg[local], __int_as_float(t.y));
        if (t.x & 0xFFFF) atomicAdd(&cnt[local], 1);
    }
    __syncthreads();
    int v = cnt[tid];
    tsum[tid] = v;
    __syncthreads();
    for (int d = 1; d < 256; d <<= 1) {
        int add = (tid >= d) ? tsum[tid - d] : 0;
        __syncthreads();
        tsum[tid] += add;
        __syncthreads();
    }
    excl[tid] = tsum[tid] - v;
    {
        int vg = (b << 8) + tid;
        if (vg < NTOTC) {
            int r0_ = s0 + excl[tid];
            rp[vg] = r0_;
            re[vg] = r0_ + v;
            if (vg >= NN2) dis[vg - NN2] = rsqrtf(wdeg[tid] + 2.0f);
        }
    }
    cnt[tid] = 0;
    __syncthreads();
    for (int i = s0 + tid; i < s1; i += 256) {
        int2 t = bedges[i];
        int cx = t.x & 0xFFFF;
        if (cx) {
            int local = t.x >> 16;
            int pos = s0 + excl[local] + atomicAdd(&cnt[local], 1);
            csr[pos] = make_int2(cx - 1, t.y);
        }
    }
}

// ------- inverse perms + zero bn stats ---------------------------------------
__global__ void inv_kernel(const int* __restrict__ perm1, const int* __restrict__ perm0,
                           int* __restrict__ inv1, int* __restrict__ inv0,
                           float* __restrict__ bnz)
{
    int i = blockIdx.x * blockDim.x + threadIdx.x;
    if (i < 384) bnz[i] = 0.f;
    if (i < NN2) inv1[perm1[i]] = i;
    else if (i < NN2 + NN1) inv0[perm0[i - NN2]] = i - NN2;
}

// ---------------- compact-indexed dis tables --------------------------------
__global__ void disc_kernel(const int* __restrict__ perm1, const int* __restrict__ perm0,
                            const float* __restrict__ dis,
                            float* __restrict__ disc1, float* __restrict__ disc0)
{
    int i = blockIdx.x * blockDim.x + threadIdx.x;
    if (i < NN2) disc1[i] = dis[perm1[i]];
    else if (i < NN2 + NN1) disc0[i - NN2] = dis[NN1 + perm0[i - NN2]];
}

// --------- GIN gather: 32-lane group per node (2 nodes/wave), fp16 ----------
template <bool BN>
__global__ __launch_bounds__(256) void gin_gather_kernel(
    const __half* __restrict__ x, const int* __restrict__ rp, const int* __restrict__ re,
    const int2* __restrict__ csr,
    const float* __restrict__ sums, const float* __restrict__ sumsq,
    const float* __restrict__ g, const float* __restrict__ bt,
    __half* __restrict__ out, int n)
{
    int v = (blockIdx.x * 256 + threadIdx.x) >> 5;
    int lane = threadIdx.x & 31;
    if (v >= n) return;
    int p0 = rp[v], pe = re[v];
    float2 sv = __half22float2(*(const __half2*)(x + (long)v * 64 + lane * 2));
    float ax0 = sv.x, ay0 = sv.y;
    float ax1 = 0.f, ay1 = 0.f, ax2 = 0.f, ay2 = 0.f, ax3 = 0.f, ay3 = 0.f;
    for (int base = p0; base < pe; base += 32) {
        int idx = base + lane;
        int s_l = 0; float m_l = 0.f;
        if (idx < pe) { s_l = csr[idx].x; m_l = 1.f; }
        int cnt = min(32, pe - base);
        for (int j = 0; j < cnt; j += 4) {
            int s0 = __shfl(s_l, j, 32),     s1 = __shfl(s_l, j + 1, 32);
            int s2 = __shfl(s_l, j + 2, 32), s3 = __shfl(s_l, j + 3, 32);
            float m0 = __shfl(m_l, j, 32),     m1 = __shfl(m_l, j + 1, 32);
            float m2 = __shfl(m_l, j + 2, 32), m3 = __shfl(m_l, j + 3, 32);
            float2 h0 = __half22float2(*(const __half2*)(x + (long)s0 * 64 + lane * 2));
            float2 h1 = __half22float2(*(const __half2*)(x + (long)s1 * 64 + lane * 2));
            float2 h2 = __half22float2(*(const __half2*)(x + (long)s2 * 64 + lane * 2));
            float2 h3 = __half22float2(*(const __half2*)(x + (long)s3 * 64 + lane * 2));
            ax0 = fmaf(m0, h0.x, ax0); ay0 = fmaf(m0, h0.y, ay0);
            ax1 = fmaf(m1, h1.x, ax1); ay1 = fmaf(m1, h1.y, ay1);
            ax2 = fmaf(m2, h2.x, ax2); ay2 = fmaf(m2, h2.y, ay2);
            ax3 = fmaf(m3, h3.x, ax3); ay3 = fmaf(m3, h3.y, ay3);
        }
    }
    float accx = (ax0 + ax1) + (ax2 + ax3);
    float accy = (ay0 + ay1) + (ay2 + ay3);
    if (BN) {
        int deg = pe - p0;
        int c0 = lane * 2, c1 = lane * 2 + 1;
        float mu0 = sums[c0] * (1.f / NN2), mu1 = sums[c1] * (1.f / NN2);
        float rs0 = rsqrtf(sumsq[c0] * (1.f / NN2) - mu0 * mu0 + BN_EPS);
        float rs1 = rsqrtf(sumsq[c1] * (1.f / NN2) - mu1 * mu1 + BN_EPS);
        float a0 = g[c0] * rs0, a1 = g[c1] * rs1;
        accx = a0 * accx + (float)(deg + 1) * (bt[c0] - a0 * mu0);
        accy = a1 * accy + (float)(deg + 1) * (bt[c1] - a1 * mu1);
    }
    *(__half2*)(out + (long)v * 64 + lane * 2) = __floats2half2_rn(accx, accy);
}

// ------ GCN gather 128ch: 32-lane group per node, 4 ch/lane -----------------
template <bool RELU>
__global__ __launch_bounds__(256) void gcn_gather128_kernel(
    const __half* __restrict__ cmp, const int* __restrict__ inv,
    const int* __restrict__ rp, const int* __restrict__ re,
    const int2* __restrict__ csr, const float* __restrict__ disc,
    const float* __restrict__ dis, const float* __restrict__ bias,
    __half* __restrict__ out, int n)
{
    int v = (blockIdx.x * 256 + threadIdx.x) >> 5;
    int lane = threadIdx.x & 31;
    if (v >= n) return;
    int p0 = rp[v], pe = re[v];
    f32x4 a0 = {0,0,0,0}, a1 = {0,0,0,0}, a2 = {0,0,0,0}, a3 = {0,0,0,0};
    for (int base = p0; base < pe; base += 32) {
        int idx = base + lane;
        int cs_l = 0; float w_l = 0.f;
        if (idx < pe) {
            int2 sl = csr[idx];
            cs_l = sl.x;
            w_l = __int_as_float(sl.y) * disc[sl.x];
        }
        int cnt = min(32, pe - base);
        for (int j = 0; j < cnt; j += 4) {
            int c0 = __shfl(cs_l, j, 32),     c1 = __shfl(cs_l, j + 1, 32);
            int c2 = __shfl(cs_l, j + 2, 32), c3 = __shfl(cs_l, j + 3, 32);
            float w0 = __shfl(w_l, j, 32),     w1 = __shfl(w_l, j + 1, 32);
            float w2 = __shfl(w_l, j + 2, 32), w3 = __shfl(w_l, j + 3, 32);
            uint2 u0 = *(const uint2*)(cmp + (long)c0 * 128 + lane * 4);
            uint2 u1 = *(const uint2*)(cmp + (long)c1 * 128 + lane * 4);
            uint2 u2 = *(const uint2*)(cmp + (long)c2 * 128 + lane * 4);
            uint2 u3 = *(const uint2*)(cmp + (long)c3 * 128 + lane * 4);
            float2 p0a = __half22float2(*(__half2*)&u0.x), p0b = __half22float2(*(__half2*)&u0.y);
            float2 p1a = __half22float2(*(__half2*)&u1.x), p1b = __half22float2(*(__half2*)&u1.y);
            float2 p2a = __half22float2(*(__half2*)&u2.x), p2b = __half22float2(*(__half2*)&u2.y);
            float2 p3a = __half22float2(*(__half2*)&u3.x), p3b = __half22float2(*(__half2*)&u3.y);
            a0[0] = fmaf(w0, p0a.x, a0[0]); a0[1] = fmaf(w0, p0a.y, a0[1]);
            a0[2] = fmaf(w0, p0b.x, a0[2]); a0[3] = fmaf(w0, p0b.y, a0[3]);
            a1[0] = fmaf(w1, p1a.x, a1[0]); a1[1] = fmaf(w1, p1a.y, a1[1]);
            a1[2] = fmaf(w1, p1b.x, a1[2]); a1[3] = fmaf(w1, p1b.y, a1[3]);
            a2[0] = fmaf(w2, p2a.x, a2[0]); a2[1] = fmaf(w2, p2a.y, a2[1]);
            a2[2] = fmaf(w2, p2b.x, a2[2]); a2[3] = fmaf(w2, p2b.y, a2[3]);
            a3[0] = fmaf(w3, p3a.x, a3[0]); a3[1] = fmaf(w3, p3a.y, a3[1]);
            a3[2] = fmaf(w3, p3b.x, a3[2]); a3[3] = fmaf(w3, p3b.y, a3[3]);
        }
    }
    float dv = dis[v];
    int cv = inv[v];
    float sx0 = 0.f, sx1 = 0.f, sx2 = 0.f, sx3 = 0.f;
    if (cv >= 0) {
        uint2 u = *(const uint2*)(cmp + (long)cv * 128 + lane * 4);
        float2 pa = __half22float2(*(__half2*)&u.x), pb = __half22float2(*(__half2*)&u.y);
        sx0 = pa.x; sx1 = pa.y; sx2 = pb.x; sx3 = pb.y;
    }
    float s2 = 2.f * dv * dv;
    float o0 = fmaf(dv, (a0[0] + a1[0]) + (a2[0] + a3[0]), fmaf(s2, sx0, bias[lane * 4]));
    float o1 = fmaf(dv, (a0[1] + a1[1]) + (a2[1] + a3[1]), fmaf(s2, sx1, bias[lane * 4 + 1]));
    float o2 = fmaf(dv, (a0[2] + a1[2]) + (a2[2] + a3[2]), fmaf(s2, sx2, bias[lane * 4 + 2]));
    float o3 = fmaf(dv, (a0[3] + a1[3]) + (a2[3] + a3[3]), fmaf(s2, sx3, bias[lane * 4 + 3]));
    if (RELU) {
        o0 = fmaxf(o0, 0.f); o1 = fmaxf(o1, 0.f);
        o2 = fmaxf(o2, 0.f); o3 = fmaxf(o3, 0.f);
    }
    __half2 ha = __floats2half2_rn(o0, o1), hb = __floats2half2_rn(o2, o3);
    *(uint2*)(out + (long)v * 128 + lane * 4) = make_uint2(*(unsigned*)&ha, *(unsigned*)&hb);
}

// ------ GCN gather 64ch: 32-lane group per node, 2 ch/lane ------------------
template <bool RELU>
__global__ __launch_bounds__(256) void gcn_gather64_kernel(
    const __half* __restrict__ cmp, const int* __restrict__ inv,
    const int* __restrict__ rp, const int* __restrict__ re,
    const int2* __restrict__ csr, const float* __restrict__ disc,
    const float* __restrict__ dis, const float* __restrict__ bias,
    float* __restrict__ out, int n)
{
    int v = (blockIdx.x * 256 + threadIdx.x) >> 5;
    int lane = threadIdx.x & 31;
    if (v >= n) return;
    int p0 = rp[v], pe = re[v];
    float ax0 = 0.f, ay0 = 0.f, ax1 = 0.f, ay1 = 0.f;
    float ax2 = 0.f, ay2 = 0.f, ax3 = 0.f, ay3 = 0.f;
    for (int base = p0; base < pe; base += 32) {
        int idx = base + lane;
        int cs_l = 0; float w_l = 0.f;
        if (idx < pe) {
            int2 sl = csr[idx];
            cs_l = sl.x;
            w_l = __int_as_float(sl.y) * disc[sl.x];
        }
        int cnt = min(32, pe - base);
        for (int j = 0; j < cnt; j += 4) {
            int c0 = __shfl(cs_l, j, 32),     c1 = __shfl(cs_l, j + 1, 32);
            int c2 = __shfl(cs_l, j + 2, 32), c3 = __shfl(cs_l, j + 3, 32);
            float w0 = __shfl(w_l, j, 32),     w1 = __shfl(w_l, j + 1, 32);
            float w2 = __shfl(w_l, j + 2, 32), w3 = __shfl(w_l, j + 3, 32);
            float2 h0 = __half22float2(*(const __half2*)(cmp + (long)c0 * 64 + lane * 2));
            float2 h1 = __half22float2(*(const __half2*)(cmp + (long)c1 * 64 + lane * 2));
            float2 h2 = __half22float2(*(const __half2*)(cmp + (long)c2 * 64 + lane * 2));
            float2 h3 = __half22float2(*(const __half2*)(cmp + (long)c3 * 64 + lane * 2));
            ax0 = fmaf(w0, h0.x, ax0); ay0 = fmaf(w0, h0.y, ay0);
            ax1 = fmaf(w1, h1.x, ax1); ay1 = fmaf(w1, h1.y, ay1);
            ax2 = fmaf(w2, h2.x, ax2); ay2 = fmaf(w2, h2.y, ay2);
            ax3 = fmaf(w3, h3.x, ax3); ay3 = fmaf(w3, h3.y, ay3);
        }
    }
    float ax = (ax0 + ax1) + (ax2 + ax3);
    float ay = (ay0 + ay1) + (ay2 + ay3);
    float dv = dis[v];
    int cv = inv[v];
    float sx = 0.f, sy = 0.f;
    if (cv >= 0) {
        float2 hv = __half22float2(*(const __half2*)(cmp + (long)cv * 64 + lane * 2));
        sx = hv.x; sy = hv.y;
    }
    float s2 = 2.f * dv * dv;
    float o0 = fmaf(dv, ax, fmaf(s2, sx, bias[lane * 2]));
    float o1 = fmaf(dv, ay, fmaf(s2, sy, bias[lane * 2 + 1]));
    if (RELU) { o0 = fmaxf(o0, 0.f); o1 = fmaxf(o1, 0.f); }
    *(float2*)(out + (long)v * 64 + lane * 2) = make_float2(o0, o1);
}

// ---------------- launch ----------------------------------------------------
extern "C" void kernel_launch(void* const* d_in, const int* in_sizes, int n_in,
                              void* d_out, int out_size, void* d_ws, size_t ws_size,
                              hipStream_t stream)
{
    const float* x    = (const float*)d_in[0];
    const int*   ei2  = (const int*)d_in[1];
    const int*   ei0  = (const int*)d_in[4];
    const int*   ei1  = (const int*)d_in[5];
    const float* ew0  = (const float*)d_in[6];
    const float* ew1  = (const float*)d_in[7];
    const int*   perm0= (const int*)d_in[8];
    const int*   perm1= (const int*)d_in[9];
    const float* W1a  = (const float*)d_in[10];
    const float* b1a  = (const float*)d_in[11];
    const float* W1b  = (const float*)d_in[12];
    const float* b1b  = (const float*)d_in[13];
    const float* g1   = (const float*)d_in[14];
    const float* bt1  = (const float*)d_in[15];
    const float* W2a  = (const float*)d_in[16];
    const float* b2a  = (const float*)d_in[17];
    const float* W2b  = (const float*)d_in[18];
    const float* b2b  = (const float*)d_in[19];
    const float* g2   = (const float*)d_in[20];
    const float* bt2  = (const float*)d_in[21];
    const float* Wg0  = (const float*)d_in[22];
    const float* bg0  = (const float*)d_in[23];
    const float* Wg1  = (const float*)d_in[24];
    const float* bg1  = (const float*)d_in[25];
    float* out = (float*)d_out;

    float* ws  = (float*)d_ws;
    int*   wsi = (int*)d_ws;

    // ---- layout (float-element offsets), total ~22.6M f = 90.5 MB (ws=256MB)
    int*   rp    = wsi;                     // 175104 -> 176000
    int*   re    = wsi + 176000;            // -> 352000
    float* dis   = ws  + 352000;            // -> 502000
    float* disc1 = ws  + 502000;            // -> 527000
    float* disc0 = ws  + 527000;            // -> 577000
    int*   inv1  = wsi + 577000;            // -> 627000
    int*   inv0  = wsi + 627000;            // -> 727000
    float* s1    = ws  + 727000;            // s1(64) q1(64) s2(128) q2(128) = 384
    float* q1    = ws  + 727064;
    float* s2    = ws  + 727128;
    float* q2    = ws  + 727256;            // -> 727384
    int*   bsum  = wsi + 727500;            // 1024 -> 728600
    int*   G     = wsi + 729000;            // NB*NBLK = 584820 -> 1,315,000
    int2*  bedges= (int2*)(wsi + 1315000);  // 1.75M int2 -> 4,815,000
    int2*  csr   = (int2*)(wsi + 4815000);  // -> 8,315,000
    __half* xh   = (__half*)(wsi + 1315000);// aliases bedges (dead) -> 2,115,000
    __half* t0f  = (__half*)(ws + 8315000); // N2*64 h -> 9,115,000
    __half* t0h  = (__half*)(ws + 9115000); // N2*64 h -> 9,915,000
    __half* t1   = (__half*)(ws + 9915000); // N2*64 h -> 10,715,000
    __half* Bb   = (__half*)(ws + 10715000);// N2*128 h -> 12,315,000
    __half* cmp1 = (__half*)(ws + 12315000);// N2*128 h -> 13,915,000
    __half* out1 = (__half*)(ws + 13915000);// N1*128 h -> 17,115,000
    __half* cmp0 = (__half*)(ws + 17115000);// N1*64 h -> 18,715,000
    int*   tcg   = wsi + 18715000;          // 1.5M -> 20,215,000

    const int* src2 = ei2, *dst2 = ei2 + EE2;
    const int* src1 = ei1, *dst1 = ei1 + EE1;
    const int* src0 = ei0, *dst0 = ei0 + EE0;

    const int NG = NB * NBLK;  // 584820

    // ---- prep ----
    hipMemsetAsync(inv1, 0xFF, (NN1 + NN0) * 4, stream);
    inv_kernel<<<cdiv(NN2 + NN1, 256), 256, 0, stream>>>(perm1, perm0, inv1, inv0, s1);
    count_translate_kernel<<<NBLK, 256, 0, stream>>>(
        dst2, src1, dst1, src0, dst0, inv1, inv0, tcg, G);
    scan_block_kernel<<<cdiv(NG, 1024), 256, 0, stream>>>(G, bsum, NG);
    scan_bsum_kernel<<<1, 1024, 0, stream>>>(bsum, cdiv(NG, 1024));
    place_kernel<<<NBLK, 256, 0, stream>>>(
        src2, dst2, dst1, ew1, dst0, ew0, tcg, G, bsum, bedges);
    bucket_build_kernel<<<NB, 256, 0, stream>>>(bedges, G, bsum, rp, re, csr, dis);
    disc_kernel<<<cdiv(NN2 + NN1, 256), 256, 0, stream>>>(perm1, perm0, dis, disc1, disc0);
    tohalf_kernel<<<cdiv(NN2 * 16, 256), 256, 0, stream>>>(x, xh, NN2 * 16);

    // ---- GIN layer 1: gather -> fused MLP (64->64->64) + BN1 stats ----
    gin_gather_kernel<false><<<cdiv((long)NN2 * 32, 256), 256, 0, stream>>>(
        xh, rp, re, csr, nullptr, nullptr, nullptr, nullptr, t0f, NN2);
    mlp_gemm_kernel<64, 64, 64, true><<<cdiv(NN2, 64), 256, 0, stream>>>(
        t0f, W1a, b1a, W1b, b1b, s1, q1, t0h, NN2);

    // ---- GIN layer 2: gather (BN1 folded) -> fused MLP (64->128->128) ------
    gin_gather_kernel<true><<<cdiv((long)NN2 * 32, 256), 256, 0, stream>>>(
        t0h, rp, re, csr, s1, q1, g1, bt1, t1, NN2);
    mlp_gemm_kernel<64, 128, 128, true><<<cdiv(NN2, 64), 256, 0, stream>>>(
        t1, W2a, b2a, W2b, b2b, s2, q2, Bb, NN2);

    // ---- GCN level 1: cmp1 = BN2(Bb) @ Wg0 (MFMA), gather -> out1 ----------
    mfma_gemm_kernel<128, 128, false, true, false, __half><<<cdiv(NN2, 64), 256, 0, stream>>>(
        Bb, Wg0, nullptr, s2, q2, g2, bt2, nullptr, nullptr, cmp1, NN2);
    gcn_gather128_kernel<true><<<cdiv((long)NN1 * 32, 256), 256, 0, stream>>>(
        cmp1, inv1, rp + NN2, re + NN2, csr, disc1, dis, bg0, out1, NN1);

    // ---- GCN level 0: cmp0 = out1 @ Wg1 (MFMA), gather -> d_out ------------
    mfma_gemm_kernel<128, 64, false, false, false, __half><<<cdiv(NN1, 64), 256, 0, stream>>>(
        out1, Wg1, nullptr, nullptr, nullptr, nullptr, nullptr, nullptr, nullptr, cmp0, NN1);
    gcn_gather64_kernel<false><<<cdiv((long)NN0 * 32, 256), 256, 0, stream>>>(
        cmp0, inv0, rp + NN2 + NN1, re + NN2 + NN1, csr, disc0, dis + NN1, bg1, out, NN0);
}

// Round 15
// 234.960 us; speedup vs baseline: 1.3938x; 1.0089x over previous
//
#include <hip/hip_runtime.h>
#include <hip/hip_fp16.h>
#include <type_traits>

#define NN2 25000
#define NN1 50000
#define NN0 100000
#define EE2 250000
#define EE1 500000
#define EE0 1000000
#define NTOTC 175000
#define ETOTC 1750000
#define NB 684            // ceil(175104/256) buckets of 256 nodes (vg>>8)
#define CHUNK 2048        // edges per count/place block
#define NBLK 855          // ceil(ETOTC/CHUNK)
#define BN_EPS 1e-5f

static inline int cdiv(long a, long b) { return (int)((a + b - 1) / b); }

typedef _Float16 half8 __attribute__((ext_vector_type(8)));
typedef float f32x4 __attribute__((ext_vector_type(4)));

// ------------- single MFMA GEMM: out = act(bn?(in) @ W + bias) --------------
template <int K, int M, bool RELU, bool BNIN, bool BNOUT, typename OT>
__global__ __launch_bounds__(256) void mfma_gemm_kernel(
    const __half* __restrict__ in, const float* __restrict__ W,
    const float* __restrict__ bias,
    const float* __restrict__ sums, const float* __restrict__ sumsq,
    const float* __restrict__ g, const float* __restrict__ bt,
    float* __restrict__ osum, float* __restrict__ osq,
    OT* __restrict__ out, int n)
{
    constexpr int BM = 64;
    constexpr int LDA = K + 8;
    constexpr int NC = M / 16;
    __shared__ __align__(16) _Float16 Ah[BM * LDA];
    __shared__ __align__(16) _Float16 Wt[M * LDA];
    const int tid = threadIdx.x;
    const int r0 = blockIdx.x * BM;

    for (int idx = tid; idx < K * M; idx += 256) {
        int k = idx / M, m = idx % M;
        Wt[m * LDA + k] = (_Float16)W[idx];
    }
    for (int idx = tid; idx < BM * K; idx += 256) {
        int r = idx / K, k = idx % K;
        int gr = r0 + r;
        float v = (gr < n) ? __half2float(in[(long)gr * K + k]) : 0.f;
        if (BNIN) {
            float mu = sums[k] * (1.f / NN2);
            float rs = rsqrtf(sumsq[k] * (1.f / NN2) - mu * mu + BN_EPS);
            v = g[k] * rs * (v - mu) + bt[k];
        }
        Ah[r * LDA + k] = (_Float16)v;
    }
    __syncthreads();

    const int wid = tid >> 6, lane = tid & 63;
    const int rw = wid * 16;
    const int arow = rw + (lane & 15);
    const int koff = (lane >> 4) * 8;

    f32x4 acc[NC];
    #pragma unroll
    for (int c = 0; c < NC; ++c) acc[c] = f32x4{0.f, 0.f, 0.f, 0.f};
    #pragma unroll
    for (int k0 = 0; k0 < K; k0 += 32) {
        half8 a = *(const half8*)&Ah[arow * LDA + k0 + koff];
        #pragma unroll
        for (int c = 0; c < NC; ++c) {
            half8 b = *(const half8*)&Wt[(c * 16 + (lane & 15)) * LDA + k0 + koff];
            acc[c] = __builtin_amdgcn_mfma_f32_16x16x32_f16(a, b, acc[c], 0, 0, 0);
        }
    }

    float* bs = (float*)Ah;
    if (BNOUT) {
        __syncthreads();
        if (tid < 2 * M) bs[tid] = 0.f;
        __syncthreads();
    }
    const int drow = r0 + rw + 4 * (lane >> 4);
    #pragma unroll
    for (int c = 0; c < NC; ++c) {
        int col = c * 16 + (lane & 15);
        float bv = (bias != nullptr) ? bias[col] : 0.f;
        float sc = 0.f, qc = 0.f;
        #pragma unroll
        for (int j = 0; j < 4; ++j) {
            int r = drow + j;
            if (r < n) {
                float v = acc[c][j] + bv;
                if (RELU) v = fmaxf(v, 0.f);
                if constexpr (std::is_same<OT, __half>::value)
                    out[(long)r * M + col] = __float2half(v);
                else
                    out[(long)r * M + col] = v;
                if (BNOUT) { sc += v; qc += v * v; }
            }
        }
        if (BNOUT) { atomicAdd(&bs[col], sc); atomicAdd(&bs[M + col], qc); }
    }
    if (BNOUT) {
        __syncthreads();
        if (tid < M) { atomicAdd(&osum[tid], bs[tid]); atomicAdd(&osq[tid], bs[M + tid]); }
    }
}

// ------------- fused MLP: out = relu(relu(in@W1+b1)@W2+b2), opt BNOUT -------
template <int K, int M1, int M2, bool BNOUT>
__global__ __launch_bounds__(256) void mlp_gemm_kernel(
    const __half* __restrict__ in,
    const float* __restrict__ W1, const float* __restrict__ b1,
    const float* __restrict__ W2, const float* __restrict__ b2,
    float* __restrict__ osum, float* __restrict__ osq,
    __half* __restrict__ out, int n)
{
    constexpr int BM = 64;
    constexpr int LDA = K + 8;
    constexpr int LDM = M1 + 8;
    constexpr int NC1 = M1 / 16, NC2 = M2 / 16;
    __shared__ __align__(16) _Float16 Ah[BM * LDA];
    __shared__ __align__(16) _Float16 Wt1[M1 * LDA];
    __shared__ __align__(16) _Float16 Wt2[M2 * LDM];
    __shared__ __align__(16) _Float16 mid[BM * LDM];
    const int tid = threadIdx.x;
    const int r0 = blockIdx.x * BM;

    for (int idx = tid; idx < K * M1; idx += 256) {
        int k = idx / M1, m = idx % M1;
        Wt1[m * LDA + k] = (_Float16)W1[idx];
    }
    for (int idx = tid; idx < M1 * M2; idx += 256) {
        int k = idx / M2, m = idx % M2;
        Wt2[m * LDM + k] = (_Float16)W2[idx];
    }
    for (int idx = tid; idx < BM * K; idx += 256) {
        int r = idx / K, k = idx % K;
        int gr = r0 + r;
        Ah[r * LDA + k] = (gr < n) ? (_Float16)in[(long)gr * K + k] : (_Float16)0.f;
    }
    __syncthreads();

    const int wid = tid >> 6, lane = tid & 63;
    const int rw = wid * 16;
    const int arow = rw + (lane & 15);
    const int koff = (lane >> 4) * 8;

    f32x4 acc1[NC1];
    #pragma unroll
    for (int c = 0; c < NC1; ++c) acc1[c] = f32x4{0.f, 0.f, 0.f, 0.f};
    #pragma unroll
    for (int k0 = 0; k0 < K; k0 += 32) {
        half8 a = *(const half8*)&Ah[arow * LDA + k0 + koff];
        #pragma unroll
        for (int c = 0; c < NC1; ++c) {
            half8 b = *(const half8*)&Wt1[(c * 16 + (lane & 15)) * LDA + k0 + koff];
            acc1[c] = __builtin_amdgcn_mfma_f32_16x16x32_f16(a, b, acc1[c], 0, 0, 0);
        }
    }
    {
        int rd0 = rw + 4 * (lane >> 4);
        #pragma unroll
        for (int c = 0; c < NC1; ++c) {
            int col = c * 16 + (lane & 15);
            float bv = b1[col];
            #pragma unroll
            for (int j = 0; j < 4; ++j)
                mid[(rd0 + j) * LDM + col] = (_Float16)fmaxf(acc1[c][j] + bv, 0.f);
        }
    }
    float* bs = (float*)Ah;
    if (BNOUT) {
        if (tid < 2 * M2) bs[tid] = 0.f;
    }
    __syncthreads();

    f32x4 acc2[NC2];
    #pragma unroll
    for (int c = 0; c < NC2; ++c) acc2[c] = f32x4{0.f, 0.f, 0.f, 0.f};
    #pragma unroll
    for (int k0 = 0; k0 < M1; k0 += 32) {
        half8 a = *(const half8*)&mid[arow * LDM + k0 + koff];
        #pragma unroll
        for (int c = 0; c < NC2; ++c) {
            half8 b = *(const half8*)&Wt2[(c * 16 + (lane & 15)) * LDM + k0 + koff];
            acc2[c] = __builtin_amdgcn_mfma_f32_16x16x32_f16(a, b, acc2[c], 0, 0, 0);
        }
    }
    const int drow = r0 + rw + 4 * (lane >> 4);
    #pragma unroll
    for (int c = 0; c < NC2; ++c) {
        int col = c * 16 + (lane & 15);
        float bv = b2[col];
        float sc = 0.f, qc = 0.f;
        #pragma unroll
        for (int j = 0; j < 4; ++j) {
            int r = drow + j;
            if (r < n) {
                float v = fmaxf(acc2[c][j] + bv, 0.f);
                out[(long)r * M2 + col] = __float2half(v);
                if (BNOUT) { sc += v; qc += v * v; }
            }
        }
        if (BNOUT) { atomicAdd(&bs[col], sc); atomicAdd(&bs[M2 + col], qc); }
    }
    if (BNOUT) {
        __syncthreads();
        if (tid < M2) { atomicAdd(&osum[tid], bs[tid]); atomicAdd(&osq[tid], bs[M2 + tid]); }
    }
}

// ------- inverse perms + zero bn stats + x->fp16 convert (fused) ------------
__global__ void inv_tohalf_kernel(const int* __restrict__ perm1, const int* __restrict__ perm0,
                                  int* __restrict__ inv1, int* __restrict__ inv0,
                                  float* __restrict__ bnz,
                                  const float* __restrict__ x, __half* __restrict__ xh)
{
    int i = blockIdx.x * blockDim.x + threadIdx.x;
    if (i < 384) bnz[i] = 0.f;
    if (i < NN2) inv1[perm1[i]] = i;
    else if (i < NN2 + NN1) inv0[perm0[i - NN2]] = i - NN2;
    if (i < NN2 * 16) {
        float4 v = ((const float4*)x)[i];
        __half2 a = __floats2half2_rn(v.x, v.y);
        __half2 b = __floats2half2_rn(v.z, v.w);
        ((uint2*)xh)[i] = make_uint2(*(unsigned*)&a, *(unsigned*)&b);
    }
}

// ------- fused count (LDS hist of dst buckets) + translate (inv lookup) -----
__global__ __launch_bounds__(256) void count_translate_kernel(
    const int* __restrict__ dst2,
    const int* __restrict__ src1, const int* __restrict__ dst1,
    const int* __restrict__ src0, const int* __restrict__ dst0,
    const int* __restrict__ inv1, const int* __restrict__ inv0,
    int* __restrict__ tcg, int* __restrict__ G)
{
    __shared__ int h[NB];
    int tid = threadIdx.x, blk = blockIdx.x;
    for (int i = tid; i < NB; i += 256) h[i] = 0;
    __syncthreads();
    int e0 = blk * CHUNK, e1 = min(e0 + CHUNK, ETOTC);
    for (int e = e0 + tid; e < e1; e += 256) {
        int vg;
        if (e < EE2) {
            vg = dst2[e];
        } else if (e < EE2 + EE1) {
            int i = e - EE2;
            vg = NN2 + dst1[i];
            tcg[i] = inv1[src1[i]];
        } else {
            int i = e - EE2 - EE1;
            vg = NN2 + NN1 + dst0[i];
            tcg[EE1 + i] = inv0[src0[i]];
        }
        atomicAdd(&h[vg >> 8], 1);
    }
    __syncthreads();
    for (int i = tid; i < NB; i += 256) G[i * NBLK + blk] = h[i];
}

// in-place exclusive scan, 1024 items / block of 256 threads
__global__ __launch_bounds__(256) void scan_block_kernel(int* data, int* bsum, int n)
{
    __shared__ int sh[256];
    int tid = threadIdx.x;
    int base = blockIdx.x * 1024 + tid * 4;
    int v[4];
    #pragma unroll
    for (int i = 0; i < 4; ++i) v[i] = (base + i < n) ? data[base + i] : 0;
    int tot = v[0] + v[1] + v[2] + v[3];
    sh[tid] = tot;
    __syncthreads();
    for (int d = 1; d < 256; d <<= 1) {
        int add = (tid >= d) ? sh[tid - d] : 0;
        __syncthreads();
        sh[tid] += add;
        __syncthreads();
    }
    int run = sh[tid] - tot;
    #pragma unroll
    for (int i = 0; i < 4; ++i) {
        if (base + i < n) data[base + i] = run;
        run += v[i];
    }
    if (tid == 255) bsum[blockIdx.x] = sh[255];
}

__global__ __launch_bounds__(1024) void scan_bsum_kernel(int* bsum, int nb)
{
    __shared__ int sh[1024];
    int tid = threadIdx.x;
    int v = (tid < nb) ? bsum[tid] : 0;
    sh[tid] = v;
    __syncthreads();
    for (int d = 1; d < 1024; d <<= 1) {
        int add = (tid >= d) ? sh[tid - d] : 0;
        __syncthreads();
        sh[tid] += add;
        __syncthreads();
    }
    if (tid < nb) bsum[tid] = sh[tid] - v;
}

// ------- place (streaming; bsum folded); bedges = ((local<<16)|(c+1), ew) ---
__global__ __launch_bounds__(256) void place_kernel(
    const int* __restrict__ src2, const int* __restrict__ dst2,
    const int* __restrict__ dst1, const float* __restrict__ ew1,
    const int* __restrict__ dst0, const float* __restrict__ ew0,
    const int* __restrict__ tcg,
    const int* __restrict__ G, const int* __restrict__ bsum,
    int2* __restrict__ bedges)
{
    __shared__ int cur[NB];
    int tid = threadIdx.x, blk = blockIdx.x;
    for (int i = tid; i < NB; i += 256) {
        int idx = i * NBLK + blk;
        cur[i] = G[idx] + bsum[idx >> 10];
    }
    __syncthreads();
    int e0 = blk * CHUNK, e1 = min(e0 + CHUNK, ETOTC);
    for (int e = e0 + tid; e < e1; e += 256) {
        int vg, c, ewb;
        if (e < EE2) {
            vg = dst2[e]; c = src2[e]; ewb = 0;
        } else if (e < EE2 + EE1) {
            int i = e - EE2;
            vg = NN2 + dst1[i]; c = tcg[i]; ewb = __float_as_int(ew1[i]);
        } else {
            int i = e - EE2 - EE1;
            vg = NN2 + NN1 + dst0[i]; c = tcg[EE1 + i]; ewb = __float_as_int(ew0[i]);
        }
        int b = vg >> 8, local = vg & 255;
        int pos = atomicAdd(&cur[b], 1);
        bedges[pos] = make_int2((local << 16) | (c + 1), ewb);
    }
}

// ------- per-bucket (256 nodes) live-only CSR + rp/re + dis (bsum folded) ---
__global__ __launch_bounds__(256) void bucket_build_kernel(
    const int2* __restrict__ bedges, const int* __restrict__ G,
    const int* __restrict__ bsum,
    int* __restrict__ rp, int* __restrict__ re,
    int2* __restrict__ csr, float* __restrict__ dis)
{
    __shared__ int cnt[256];
    __shared__ float wdeg[256];
    __shared__ int excl[256];
    __shared__ int tsum[256];
    int b = blockIdx.x, tid = threadIdx.x;
    int i0 = b * NBLK;
    int s0 = G[i0] + bsum[i0 >> 10];
    int s1;
    if (b == NB - 1) s1 = ETOTC;
    else { int i1 = (b + 1) * NBLK; s1 = G[i1] + bsum[i1 >> 10]; }
    cnt[tid] = 0; wdeg[tid] = 0.f;
    __syncthreads();
    for (int i = s0 + tid; i < s1; i += 256) {
        int2 t = bedges[i];
        int local = t.x >> 16;
        atomicAdd(&wdeg[local], __int_as_float(t.y));
        if (t.x & 0xFFFF) atomicAdd(&cnt[local], 1);
    }
    __syncthreads();
    int v = cnt[tid];
    tsum[tid] = v;
    __syncthreads();
    for (int d = 1; d < 256; d <<= 1) {
        int add = (tid >= d) ? tsum[tid - d] : 0;
        __syncthreads();
        tsum[tid] += add;
        __syncthreads();
    }
    excl[tid] = tsum[tid] - v;
    {
        int vg = (b << 8) + tid;
        if (vg < NTOTC) {
            int r0_ = s0 + excl[tid];
            rp[vg] = r0_;
            re[vg] = r0_ + v;
            if (vg >= NN2) dis[vg - NN2] = rsqrtf(wdeg[tid] + 2.0f);
        }
    }
    cnt[tid] = 0;
    __syncthreads();
    for (int i = s0 + tid; i < s1; i += 256) {
        int2 t = bedges[i];
        int cx = t.x & 0xFFFF;
        if (cx) {
            int local = t.x >> 16;
            int pos = s0 + excl[local] + atomicAdd(&cnt[local], 1);
            csr[pos] = make_int2(cx - 1, t.y);
        }
    }
}

// ---------------- compact-indexed dis tables --------------------------------
__global__ void disc_kernel(const int* __restrict__ perm1, const int* __restrict__ perm0,
                            const float* __restrict__ dis,
                            float* __restrict__ disc1, float* __restrict__ disc0)
{
    int i = blockIdx.x * blockDim.x + threadIdx.x;
    if (i < NN2) disc1[i] = dis[perm1[i]];
    else if (i < NN2 + NN1) disc0[i - NN2] = dis[NN1 + perm0[i - NN2]];
}

// --------- GIN gather: 32-lane group per node, 8-deep ILP, fp16 -------------
template <bool BN>
__global__ __launch_bounds__(256) void gin_gather_kernel(
    const __half* __restrict__ x, const int* __restrict__ rp, const int* __restrict__ re,
    const int2* __restrict__ csr,
    const float* __restrict__ sums, const float* __restrict__ sumsq,
    const float* __restrict__ g, const float* __restrict__ bt,
    __half* __restrict__ out, int n)
{
    int v = (blockIdx.x * 256 + threadIdx.x) >> 5;
    int lane = threadIdx.x & 31;
    if (v >= n) return;
    int p0 = rp[v], pe = re[v];
    float2 sv = __half22float2(*(const __half2*)(x + (long)v * 64 + lane * 2));
    float ax[8], ay[8];
    #pragma unroll
    for (int u = 0; u < 8; ++u) { ax[u] = 0.f; ay[u] = 0.f; }
    ax[0] = sv.x; ay[0] = sv.y;
    for (int base = p0; base < pe; base += 32) {
        int idx = base + lane;
        int s_l = 0; float m_l = 0.f;
        if (idx < pe) { s_l = csr[idx].x; m_l = 1.f; }
        int cnt = min(32, pe - base);
        for (int j = 0; j < cnt; j += 8) {
            int ss[8]; float mm[8];
            #pragma unroll
            for (int u = 0; u < 8; ++u) {
                ss[u] = __shfl(s_l, j + u, 32);
                mm[u] = __shfl(m_l, j + u, 32);
            }
            float2 hh[8];
            #pragma unroll
            for (int u = 0; u < 8; ++u)
                hh[u] = __half22float2(*(const __half2*)(x + (long)ss[u] * 64 + lane * 2));
            #pragma unroll
            for (int u = 0; u < 8; ++u) {
                ax[u] = fmaf(mm[u], hh[u].x, ax[u]);
                ay[u] = fmaf(mm[u], hh[u].y, ay[u]);
            }
        }
    }
    float accx = ((ax[0] + ax[1]) + (ax[2] + ax[3])) + ((ax[4] + ax[5]) + (ax[6] + ax[7]));
    float accy = ((ay[0] + ay[1]) + (ay[2] + ay[3])) + ((ay[4] + ay[5]) + (ay[6] + ay[7]));
    if (BN) {
        int deg = pe - p0;
        int c0 = lane * 2, c1 = lane * 2 + 1;
        float mu0 = sums[c0] * (1.f / NN2), mu1 = sums[c1] * (1.f / NN2);
        float rs0 = rsqrtf(sumsq[c0] * (1.f / NN2) - mu0 * mu0 + BN_EPS);
        float rs1 = rsqrtf(sumsq[c1] * (1.f / NN2) - mu1 * mu1 + BN_EPS);
        float a0 = g[c0] * rs0, a1 = g[c1] * rs1;
        accx = a0 * accx + (float)(deg + 1) * (bt[c0] - a0 * mu0);
        accy = a1 * accy + (float)(deg + 1) * (bt[c1] - a1 * mu1);
    }
    *(__half2*)(out + (long)v * 64 + lane * 2) = __floats2half2_rn(accx, accy);
}

// ------ GCN gather 128ch: 32-lane group per node, 8-deep ILP ----------------
template <bool RELU>
__global__ __launch_bounds__(256) void gcn_gather128_kernel(
    const __half* __restrict__ cmp, const int* __restrict__ inv,
    const int* __restrict__ rp, const int* __restrict__ re,
    const int2* __restrict__ csr, const float* __restrict__ disc,
    const float* __restrict__ dis, const float* __restrict__ bias,
    __half* __restrict__ out, int n)
{
    int v = (blockIdx.x * 256 + threadIdx.x) >> 5;
    int lane = threadIdx.x & 31;
    if (v >= n) return;
    int p0 = rp[v], pe = re[v];
    f32x4 acc[8];
    #pragma unroll
    for (int u = 0; u < 8; ++u) acc[u] = f32x4{0.f, 0.f, 0.f, 0.f};
    for (int base = p0; base < pe; base += 32) {
        int idx = base + lane;
        int cs_l = 0; float w_l = 0.f;
        if (idx < pe) {
            int2 sl = csr[idx];
            cs_l = sl.x;
            w_l = __int_as_float(sl.y) * disc[sl.x];
        }
        int cnt = min(32, pe - base);
        for (int j = 0; j < cnt; j += 8) {
            int cc[8]; float ww[8];
            #pragma unroll
            for (int u = 0; u < 8; ++u) {
                cc[u] = __shfl(cs_l, j + u, 32);
                ww[u] = __shfl(w_l, j + u, 32);
            }
            uint2 uu[8];
            #pragma unroll
            for (int u = 0; u < 8; ++u)
                uu[u] = *(const uint2*)(cmp + (long)cc[u] * 128 + lane * 4);
            #pragma unroll
            for (int u = 0; u < 8; ++u) {
                float2 pa = __half22float2(*(__half2*)&uu[u].x);
                float2 pb = __half22float2(*(__half2*)&uu[u].y);
                acc[u][0] = fmaf(ww[u], pa.x, acc[u][0]);
                acc[u][1] = fmaf(ww[u], pa.y, acc[u][1]);
                acc[u][2] = fmaf(ww[u], pb.x, acc[u][2]);
                acc[u][3] = fmaf(ww[u], pb.y, acc[u][3]);
            }
        }
    }
    f32x4 tot = ((acc[0] + acc[1]) + (acc[2] + acc[3])) + ((acc[4] + acc[5]) + (acc[6] + acc[7]));
    float dv = dis[v];
    int cv = inv[v];
    float sx0 = 0.f, sx1 = 0.f, sx2 = 0.f, sx3 = 0.f;
    if (cv >= 0) {
        uint2 u = *(const uint2*)(cmp + (long)cv * 128 + lane * 4);
        float2 pa = __half22float2(*(__half2*)&u.x), pb = __half22float2(*(__half2*)&u.y);
        sx0 = pa.x; sx1 = pa.y; sx2 = pb.x; sx3 = pb.y;
    }
    float s2 = 2.f * dv * dv;
    float o0 = fmaf(dv, tot[0], fmaf(s2, sx0, bias[lane * 4]));
    float o1 = fmaf(dv, tot[1], fmaf(s2, sx1, bias[lane * 4 + 1]));
    float o2 = fmaf(dv, tot[2], fmaf(s2, sx2, bias[lane * 4 + 2]));
    float o3 = fmaf(dv, tot[3], fmaf(s2, sx3, bias[lane * 4 + 3]));
    if (RELU) {
        o0 = fmaxf(o0, 0.f); o1 = fmaxf(o1, 0.f);
        o2 = fmaxf(o2, 0.f); o3 = fmaxf(o3, 0.f);
    }
    __half2 ha = __floats2half2_rn(o0, o1), hb = __floats2half2_rn(o2, o3);
    *(uint2*)(out + (long)v * 128 + lane * 4) = make_uint2(*(unsigned*)&ha, *(unsigned*)&hb);
}

// ------ GCN gather 64ch: 32-lane group per node, 8-deep ILP -----------------
template <bool RELU>
__global__ __launch_bounds__(256) void gcn_gather64_kernel(
    const __half* __restrict__ cmp, const int* __restrict__ inv,
    const int* __restrict__ rp, const int* __restrict__ re,
    const int2* __restrict__ csr, const float* __restrict__ disc,
    const float* __restrict__ dis, const float* __restrict__ bias,
    float* __restrict__ out, int n)
{
    int v = (blockIdx.x * 256 + threadIdx.x) >> 5;
    int lane = threadIdx.x & 31;
    if (v >= n) return;
    int p0 = rp[v], pe = re[v];
    float ax[8], ay[8];
    #pragma unroll
    for (int u = 0; u < 8; ++u) { ax[u] = 0.f; ay[u] = 0.f; }
    for (int base = p0; base < pe; base += 32) {
        int idx = base + lane;
        int cs_l = 0; float w_l = 0.f;
        if (idx < pe) {
            int2 sl = csr[idx];
            cs_l = sl.x;
            w_l = __int_as_float(sl.y) * disc[sl.x];
        }
        int cnt = min(32, pe - base);
        for (int j = 0; j < cnt; j += 8) {
            int cc[8]; float ww[8];
            #pragma unroll
            for (int u = 0; u < 8; ++u) {
                cc[u] = __shfl(cs_l, j + u, 32);
                ww[u] = __shfl(w_l, j + u, 32);
            }
            float2 hh[8];
            #pragma unroll
            for (int u = 0; u < 8; ++u)
                hh[u] = __half22float2(*(const __half2*)(cmp + (long)cc[u] * 64 + lane * 2));
            #pragma unroll
            for (int u = 0; u < 8; ++u) {
                ax[u] = fmaf(ww[u], hh[u].x, ax[u]);
                ay[u] = fmaf(ww[u], hh[u].y, ay[u]);
            }
        }
    }
    float axs = ((ax[0] + ax[1]) + (ax[2] + ax[3])) + ((ax[4] + ax[5]) + (ax[6] + ax[7]));
    float ays = ((ay[0] + ay[1]) + (ay[2] + ay[3])) + ((ay[4] + ay[5]) + (ay[6] + ay[7]));
    float dv = dis[v];
    int cv = inv[v];
    float sx = 0.f, sy = 0.f;
    if (cv >= 0) {
        float2 hv = __half22float2(*(const __half2*)(cmp + (long)cv * 64 + lane * 2));
        sx = hv.x; sy = hv.y;
    }
    float s2 = 2.f * dv * dv;
    float o0 = fmaf(dv, axs, fmaf(s2, sx, bias[lane * 2]));
    float o1 = fmaf(dv, ays, fmaf(s2, sy, bias[lane * 2 + 1]));
    if (RELU) { o0 = fmaxf(o0, 0.f); o1 = fmaxf(o1, 0.f); }
    *(float2*)(out + (long)v * 64 + lane * 2) = make_float2(o0, o1);
}

// ---------------- launch ----------------------------------------------------
extern "C" void kernel_launch(void* const* d_in, const int* in_sizes, int n_in,
                              void* d_out, int out_size, void* d_ws, size_t ws_size,
                              hipStream_t stream)
{
    const float* x    = (const float*)d_in[0];
    const int*   ei2  = (const int*)d_in[1];
    const int*   ei0  = (const int*)d_in[4];
    const int*   ei1  = (const int*)d_in[5];
    const float* ew0  = (const float*)d_in[6];
    const float* ew1  = (const float*)d_in[7];
    const int*   perm0= (const int*)d_in[8];
    const int*   perm1= (const int*)d_in[9];
    const float* W1a  = (const float*)d_in[10];
    const float* b1a  = (const float*)d_in[11];
    const float* W1b  = (const float*)d_in[12];
    const float* b1b  = (const float*)d_in[13];
    const float* g1   = (const float*)d_in[14];
    const float* bt1  = (const float*)d_in[15];
    const float* W2a  = (const float*)d_in[16];
    const float* b2a  = (const float*)d_in[17];
    const float* W2b  = (const float*)d_in[18];
    const float* b2b  = (const float*)d_in[19];
    const float* g2   = (const float*)d_in[20];
    const float* bt2  = (const float*)d_in[21];
    const float* Wg0  = (const float*)d_in[22];
    const float* bg0  = (const float*)d_in[23];
    const float* Wg1  = (const float*)d_in[24];
    const float* bg1  = (const float*)d_in[25];
    float* out = (float*)d_out;

    float* ws  = (float*)d_ws;
    int*   wsi = (int*)d_ws;

    // ---- layout (float-element offsets); ws = 256 MB, using ~84 MB ----
    int*   rp    = wsi;                     // 175104 -> 176000
    int*   re    = wsi + 176000;            // -> 352000
    float* dis   = ws  + 352000;            // -> 502000
    float* disc1 = ws  + 502000;            // -> 527000
    float* disc0 = ws  + 527000;            // -> 577000
    int*   inv1  = wsi + 577000;            // -> 627000
    int*   inv0  = wsi + 627000;            // -> 727000
    float* s1    = ws  + 727000;            // s1(64) q1(64) s2(128) q2(128)
    float* q1    = ws  + 727064;
    float* s2    = ws  + 727128;
    float* q2    = ws  + 727256;            // -> 727384
    int*   bsum  = wsi + 727500;            // 1024 -> 728600
    int*   G     = wsi + 729000;            // NB*NBLK = 584820 -> 1,315,000
    int2*  bedges= (int2*)(wsi + 1315000);  // 1.75M int2 -> 4,815,000
    int2*  csr   = (int2*)(wsi + 4815000);  // -> 8,315,000
    __half* t0f  = (__half*)(ws + 8315000); // N2*64 h -> 9,115,000
    __half* t0h  = (__half*)(ws + 9115000); // N2*64 h -> 9,915,000
    __half* t1   = (__half*)(ws + 9915000); // N2*64 h -> 10,715,000
    __half* Bb   = (__half*)(ws + 10715000);// N2*128 h -> 12,315,000
    __half* cmp1 = (__half*)(ws + 12315000);// N2*128 h -> 13,915,000
    __half* out1 = (__half*)(ws + 13915000);// N1*128 h -> 17,115,000
    __half* cmp0 = (__half*)(ws + 17115000);// N1*64 h -> 18,715,000
    int*   tcg   = wsi + 18715000;          // 1.5M -> 20,215,000
    __half* xh   = (__half*)(ws + 20215000);// N2*64 h (dedicated) -> 21,015,000

    const int* src2 = ei2, *dst2 = ei2 + EE2;
    const int* src1 = ei1, *dst1 = ei1 + EE1;
    const int* src0 = ei0, *dst0 = ei0 + EE0;

    const int NG = NB * NBLK;  // 584820

    // ---- prep ----
    hipMemsetAsync(inv1, 0xFF, (NN1 + NN0) * 4, stream);
    inv_tohalf_kernel<<<cdiv(NN2 * 16, 256), 256, 0, stream>>>(
        perm1, perm0, inv1, inv0, s1, x, xh);
    count_translate_kernel<<<NBLK, 256, 0, stream>>>(
        dst2, src1, dst1, src0, dst0, inv1, inv0, tcg, G);
    scan_block_kernel<<<cdiv(NG, 1024), 256, 0, stream>>>(G, bsum, NG);
    scan_bsum_kernel<<<1, 1024, 0, stream>>>(bsum, cdiv(NG, 1024));
    place_kernel<<<NBLK, 256, 0, stream>>>(
        src2, dst2, dst1, ew1, dst0, ew0, tcg, G, bsum, bedges);
    bucket_build_kernel<<<NB, 256, 0, stream>>>(bedges, G, bsum, rp, re, csr, dis);
    disc_kernel<<<cdiv(NN2 + NN1, 256), 256, 0, stream>>>(perm1, perm0, dis, disc1, disc0);

    // ---- GIN layer 1: gather -> fused MLP (64->64->64) + BN1 stats ----
    gin_gather_kernel<false><<<cdiv((long)NN2 * 32, 256), 256, 0, stream>>>(
        xh, rp, re, csr, nullptr, nullptr, nullptr, nullptr, t0f, NN2);
    mlp_gemm_kernel<64, 64, 64, true><<<cdiv(NN2, 64), 256, 0, stream>>>(
        t0f, W1a, b1a, W1b, b1b, s1, q1, t0h, NN2);

    // ---- GIN layer 2: gather (BN1 folded) -> fused MLP (64->128->128) ------
    gin_gather_kernel<true><<<cdiv((long)NN2 * 32, 256), 256, 0, stream>>>(
        t0h, rp, re, csr, s1, q1, g1, bt1, t1, NN2);
    mlp_gemm_kernel<64, 128, 128, true><<<cdiv(NN2, 64), 256, 0, stream>>>(
        t1, W2a, b2a, W2b, b2b, s2, q2, Bb, NN2);

    // ---- GCN level 1: cmp1 = BN2(Bb) @ Wg0 (MFMA), gather -> out1 ----------
    mfma_gemm_kernel<128, 128, false, true, false, __half><<<cdiv(NN2, 64), 256, 0, stream>>>(
        Bb, Wg0, nullptr, s2, q2, g2, bt2, nullptr, nullptr, cmp1, NN2);
    gcn_gather128_kernel<true><<<cdiv((long)NN1 * 32, 256), 256, 0, stream>>>(
        cmp1, inv1, rp + NN2, re + NN2, csr, disc1, dis, bg0, out1, NN1);

    // ---- GCN level 0: cmp0 = out1 @ Wg1 (MFMA), gather -> d_out ------------
    mfma_gemm_kernel<128, 64, false, false, false, __half><<<cdiv(NN1, 64), 256, 0, stream>>>(
        out1, Wg1, nullptr, nullptr, nullptr, nullptr, nullptr, nullptr, nullptr, cmp0, NN1);
    gcn_gather64_kernel<false><<<cdiv((long)NN0 * 32, 256), 256, 0, stream>>>(
        cmp0, inv0, rp + NN2 + NN1, re + NN2 + NN1, csr, disc0, dis + NN1, bg1, out, NN0);
}